// Round 4
// baseline (757.476 us; speedup 1.0000x reference)
//
#include <hip/hip_runtime.h>
#include <math.h>

#define HD   128
#define EFD  16
#define KP   288     // layer-1 K padded: [h_src 0..127 | h_dst 128..255 | a 256..271 | rad 272 | pad..287]
#define MT   64      // edges / nodes per block
#define LPF  296     // LDS pitch (ushort) for f tile
#define LPA  264
#define LPC  136

#define W1SZ (128 * KP)
#define W2SZ (128 * 128)
#define O_WE1 (W1SZ)
#define O_WC2 (2 * W1SZ)
#define O_WE2 (2 * W1SZ + W2SZ)
#define O_WN1 (2 * W1SZ + 2 * W2SZ)
#define O_WN2 (2 * W1SZ + 2 * W2SZ + 128 * 256)
#define WS_ELEMS (O_WN2 + W2SZ)          // 155648 ushorts

// ws byte layout
#define B_H16   ((size_t)0)              // 32768*128*2      = 8,388,608
#define B_WPAN  ((size_t)8388608)        // WS_ELEMS*2       =   311,296
#define B_CNT   ((size_t)8699904)        // 32768*4          =   131,072
#define B_OFS   ((size_t)8830976)        // 32768*4          =   131,072
#define B_SRCP  ((size_t)8962048)        // 524288*4         = 2,097,152
#define B_DSTP  ((size_t)11059200)       // 524288*4         = 2,097,152
#define B_A16   ((size_t)13156352)       // 524288*16*2      = 16,777,216  (end ~29.9 MB)

typedef __attribute__((ext_vector_type(8))) short short8;
typedef __attribute__((ext_vector_type(4))) float f32x4;

__device__ __forceinline__ unsigned short f2bf(float x) {
    union { float f; unsigned u; } v; v.f = x;
    unsigned r = v.u + 0x7fffu + ((v.u >> 16) & 1u);
    return (unsigned short)(r >> 16);
}
__device__ __forceinline__ float bf2f(unsigned short u) {
    union { unsigned u; float f; } v; v.u = ((unsigned)u) << 16;
    return v.f;
}
__device__ __forceinline__ float silu_f(float x) { return x / (1.f + __expf(-x)); }

// ---------------------------------------------------------------------------
// h (fp32, N x 128) -> bf16 table
// ---------------------------------------------------------------------------
__global__ __launch_bounds__(256) void conv_h(const float* __restrict__ h,
                                              unsigned short* __restrict__ h16)
{
    const int i = blockIdx.x * 256 + threadIdx.x;       // float4 index
    const float4 v = ((const float4*)h)[i];
    union { unsigned short us[4]; uint2 u2; } p;
    p.us[0] = f2bf(v.x); p.us[1] = f2bf(v.y);
    p.us[2] = f2bf(v.z); p.us[3] = f2bf(v.w);
    ((uint2*)h16)[i] = p.u2;
}

// ---------------------------------------------------------------------------
// Weight prep: fp32 [K][128] -> bf16 transposed [128][Kpad] panels
// Layer-1 K-order remap: newk<256 -> newk ; 256..271 -> a rows (orig 257..272);
// 272 -> radial row (orig 256); >272 -> 0
// ---------------------------------------------------------------------------
__global__ __launch_bounds__(256) void prep_weights(
    const float* __restrict__ Wc1, const float* __restrict__ We1,
    const float* __restrict__ Wc2, const float* __restrict__ We2,
    const float* __restrict__ Wn1, const float* __restrict__ Wn2,
    unsigned short* __restrict__ ws)
{
    int idx = blockIdx.x * 256 + threadIdx.x;
    if (idx < W1SZ) {
        int c = idx / KP, k = idx % KP;
        float v = 0.f;
        if (k < 256) v = Wc1[k * HD + c];
        else if (k < 272) v = Wc1[(k + 1) * HD + c];
        else if (k == 272) v = Wc1[256 * HD + c];
        ws[idx] = f2bf(v);
        return;
    }
    idx -= W1SZ;
    if (idx < W1SZ) {
        int c = idx / KP, k = idx % KP;
        float v = 0.f;
        if (k < 256) v = We1[k * HD + c];
        else if (k < 272) v = We1[(k + 1) * HD + c];
        else if (k == 272) v = We1[256 * HD + c];
        ws[O_WE1 + idx] = f2bf(v);
        return;
    }
    idx -= W1SZ;
    if (idx < W2SZ) { int c = idx / HD, k = idx % HD; ws[O_WC2 + idx] = f2bf(Wc2[k * HD + c]); return; }
    idx -= W2SZ;
    if (idx < W2SZ) { int c = idx / HD, k = idx % HD; ws[O_WE2 + idx] = f2bf(We2[k * HD + c]); return; }
    idx -= W2SZ;
    if (idx < 128 * 256) { int c = idx / 256, k = idx % 256; ws[O_WN1 + idx] = f2bf(Wn1[k * HD + c]); return; }
    idx -= 128 * 256;
    if (idx < W2SZ) { int c = idx / HD, k = idx % HD; ws[O_WN2 + idx] = f2bf(Wn2[k * HD + c]); }
}

// ---------------------------------------------------------------------------
// Counting sort by dst: histogram -> exclusive scan -> scatter permute
// ---------------------------------------------------------------------------
__global__ __launch_bounds__(256) void hist_kernel(const int* __restrict__ dst,
                                                   unsigned* __restrict__ cnt, int E)
{
    const int i = blockIdx.x * 256 + threadIdx.x;
    if (i < E) atomicAdd(&cnt[dst[i]], 1u);
}

__global__ __launch_bounds__(1024) void scan32k(const unsigned* __restrict__ cnt,
                                                unsigned* __restrict__ ofs)
{
    __shared__ unsigned wsum[16];
    __shared__ unsigned carry_s;
    const int tid = threadIdx.x, lane = tid & 63, w = tid >> 6;
    if (tid == 0) carry_s = 0;
    __syncthreads();
    for (int c = 0; c < 32; ++c) {
        const unsigned x = cnt[c * 1024 + tid];
        unsigned v = x;
        #pragma unroll
        for (int off = 1; off < 64; off <<= 1) {
            unsigned t = __shfl_up(v, off);
            if (lane >= off) v += t;
        }
        if (lane == 63) wsum[w] = v;
        __syncthreads();
        if (tid < 16) {
            unsigned s = wsum[tid];
            #pragma unroll
            for (int off = 1; off < 16; off <<= 1) {
                unsigned t = __shfl_up(s, off);
                if (tid >= off) s += t;
            }
            wsum[tid] = s;
        }
        __syncthreads();
        const unsigned carry = carry_s;
        const unsigned woff = (w == 0) ? 0u : wsum[w - 1];
        ofs[c * 1024 + tid] = carry + woff + v - x;
        __syncthreads();
        if (tid == 0) carry_s = carry + wsum[15];
        __syncthreads();
    }
}

__global__ __launch_bounds__(256) void scatter_perm(
    const int* __restrict__ src, const int* __restrict__ dst,
    const float* __restrict__ a, unsigned* __restrict__ ofs,
    int* __restrict__ srcp, int* __restrict__ dstp,
    unsigned short* __restrict__ a16p, int E)
{
    const int i = blockIdx.x * 256 + threadIdx.x;
    if (i >= E) return;
    const int d = dst[i];
    const unsigned pos = atomicAdd(&ofs[d], 1u);
    srcp[pos] = src[i];
    dstp[pos] = d;
    const float* ar = a + (size_t)i * EFD;
    union { unsigned short us[8]; short8 v; } p0, p1;
    #pragma unroll
    for (int t = 0; t < 8; ++t) { p0.us[t] = f2bf(ar[t]); p1.us[t] = f2bf(ar[8 + t]); }
    short8* dstv = (short8*)(a16p + (size_t)pos * EFD);
    dstv[0] = p0.v; dstv[1] = p1.v;
}

// ---------------------------------------------------------------------------
// Edge kernel (MFMA, dst-sorted tiles, segmented-sum scatter)
// ---------------------------------------------------------------------------
__global__ __launch_bounds__(256) void edge_kernel(
    const int* __restrict__ srcp, const int* __restrict__ dstp,
    const unsigned short* __restrict__ a16p,
    const float* __restrict__ coords, const unsigned short* __restrict__ h16,
    const float* __restrict__ bc1, const float* __restrict__ bc2,
    const float* __restrict__ Wc3,
    const float* __restrict__ be1, const float* __restrict__ be2,
    const float* __restrict__ Watt, const float* __restrict__ batt,
    const unsigned short* __restrict__ wpan,
    float* __restrict__ out_h, float* __restrict__ out_x)
{
    __shared__ __align__(16) unsigned short fsh[MT][LPF];
    __shared__ __align__(16) unsigned short csh[MT][LPC];
    __shared__ float diff_s[MT][3];
    __shared__ float rinv_s[MT];
    __shared__ float sc_s[MT];
    __shared__ int   src_s[MT], dst_s[MT];
    __shared__ short run_start[MT + 1];
    __shared__ int   nruns_s;

    const int tid = threadIdx.x;
    const int e0  = blockIdx.x * MT;

    if (tid < MT) {
        const int s = srcp[e0 + tid], d = dstp[e0 + tid];
        src_s[tid] = s; dst_s[tid] = d;
        const float dx = coords[(size_t)s*3+0] - coords[(size_t)d*3+0];
        const float dy = coords[(size_t)s*3+1] - coords[(size_t)d*3+1];
        const float dz = coords[(size_t)s*3+2] - coords[(size_t)d*3+2];
        diff_s[tid][0] = dx; diff_s[tid][1] = dy; diff_s[tid][2] = dz;
        const float rad = dx*dx + dy*dy + dz*dz;
        rinv_s[tid] = 1.f / (sqrtf(rad + 1e-5f) + 1.f);
        fsh[tid][272] = f2bf(rad);
        #pragma unroll
        for (int c = 273; c < KP; ++c) fsh[tid][c] = 0;
    }
    __syncthreads();

    if (tid == 0) {          // build same-dst runs (sorted tile)
        int nr = 0, prev = -1;
        for (int e = 0; e < MT; ++e) {
            if (dst_s[e] != prev) { run_start[nr++] = (short)e; prev = dst_s[e]; }
        }
        run_start[nr] = MT;
        nruns_s = nr;
    }

    // gather h16[src] | h16[dst] rows (16B chunks, dst rows L2-hot via sort)
    #pragma unroll
    for (int it = 0; it < 8; ++it) {
        const int cid = it * 256 + tid;              // 2048 chunks of 16B
        const int e = cid >> 5, q = cid & 31;
        if (q < 16)
            *(short8*)&fsh[e][q * 8] =
                *(const short8*)(h16 + (size_t)src_s[e] * HD + q * 8);
        else
            *(short8*)&fsh[e][128 + (q - 16) * 8] =
                *(const short8*)(h16 + (size_t)dst_s[e] * HD + (q - 16) * 8);
    }
    {   // a tile (pre-permuted bf16): cols 256..271
        const int e = tid >> 2, g = tid & 3;
        *(uint2*)&fsh[e][256 + g * 4] =
            *(const uint2*)(a16p + (size_t)(e0 + e) * EFD + g * 4);
    }
    __syncthreads();

    const int lane = tid & 63;
    const int w    = tid >> 6;
    const int er0  = w * 16;
    const int col  = lane & 15;
    const int kg   = lane >> 4;

    const unsigned short* Wc1t = wpan;
    const unsigned short* We1t = wpan + O_WE1;
    const unsigned short* Wc2t = wpan + O_WC2;
    const unsigned short* We2t = wpan + O_WE2;

    const f32x4 zero = {0.f, 0.f, 0.f, 0.f};
    f32x4 acc[8];

    // ================= coord-MLP =================
    #pragma unroll
    for (int n = 0; n < 8; ++n) acc[n] = zero;
    #pragma unroll
    for (int kc = 0; kc < 9; ++kc) {
        const short8 af = *(const short8*)&fsh[er0 + col][kc * 32 + kg * 8];
        #pragma unroll
        for (int n = 0; n < 8; ++n) {
            const short8 bf = *(const short8*)&Wc1t[(size_t)(n*16 + col) * KP + kc * 32 + kg * 8];
            acc[n] = __builtin_amdgcn_mfma_f32_16x16x32_bf16(af, bf, acc[n], 0, 0, 0);
        }
    }
    #pragma unroll
    for (int n = 0; n < 8; ++n) {
        const float b = bc1[n*16 + col];
        #pragma unroll
        for (int i = 0; i < 4; ++i)
            csh[er0 + kg*4 + i][n*16 + col] = f2bf(silu_f(acc[n][i] + b));
    }
    #pragma unroll
    for (int n = 0; n < 8; ++n) acc[n] = zero;
    #pragma unroll
    for (int kc = 0; kc < 4; ++kc) {
        const short8 af = *(const short8*)&csh[er0 + col][kc * 32 + kg * 8];
        #pragma unroll
        for (int n = 0; n < 8; ++n) {
            const short8 bf = *(const short8*)&Wc2t[(size_t)(n*16 + col) * HD + kc * 32 + kg * 8];
            acc[n] = __builtin_amdgcn_mfma_f32_16x16x32_bf16(af, bf, acc[n], 0, 0, 0);
        }
    }
    {   // scale -> sc_s (per edge); scatter deferred to seg-sum
        float part[4] = {0.f, 0.f, 0.f, 0.f};
        #pragma unroll
        for (int n = 0; n < 8; ++n) {
            const float b  = bc2[n*16 + col];
            const float w3 = Wc3[n*16 + col];
            #pragma unroll
            for (int i = 0; i < 4; ++i) part[i] += silu_f(acc[n][i] + b) * w3;
        }
        #pragma unroll
        for (int m = 1; m < 16; m <<= 1) {
            #pragma unroll
            for (int i = 0; i < 4; ++i) part[i] += __shfl_xor(part[i], m);
        }
        if (col == 0) {
            #pragma unroll
            for (int i = 0; i < 4; ++i) sc_s[er0 + kg*4 + i] = part[i];
        }
    }

    // ================= edge-MLP =================
    #pragma unroll
    for (int n = 0; n < 8; ++n) acc[n] = zero;
    #pragma unroll
    for (int kc = 0; kc < 9; ++kc) {
        const short8 af = *(const short8*)&fsh[er0 + col][kc * 32 + kg * 8];
        #pragma unroll
        for (int n = 0; n < 8; ++n) {
            const short8 bf = *(const short8*)&We1t[(size_t)(n*16 + col) * KP + kc * 32 + kg * 8];
            acc[n] = __builtin_amdgcn_mfma_f32_16x16x32_bf16(af, bf, acc[n], 0, 0, 0);
        }
    }
    #pragma unroll
    for (int n = 0; n < 8; ++n) {
        const float b = be1[n*16 + col];
        #pragma unroll
        for (int i = 0; i < 4; ++i)
            csh[er0 + kg*4 + i][n*16 + col] = f2bf(silu_f(acc[n][i] + b));
    }
    #pragma unroll
    for (int n = 0; n < 8; ++n) acc[n] = zero;
    #pragma unroll
    for (int kc = 0; kc < 4; ++kc) {
        const short8 af = *(const short8*)&csh[er0 + col][kc * 32 + kg * 8];
        #pragma unroll
        for (int n = 0; n < 8; ++n) {
            const short8 bf = *(const short8*)&We2t[(size_t)(n*16 + col) * HD + kc * 32 + kg * 8];
            acc[n] = __builtin_amdgcn_mfma_f32_16x16x32_bf16(af, bf, acc[n], 0, 0, 0);
        }
    }
    {   // att-gate; write gated msg (bf16) into csh cols 0..127
        float msg[8][4];
        float pa[4] = {0.f, 0.f, 0.f, 0.f};
        #pragma unroll
        for (int n = 0; n < 8; ++n) {
            const float b  = be2[n*16 + col];
            const float wa = Watt[n*16 + col];
            #pragma unroll
            for (int i = 0; i < 4; ++i) {
                const float v = silu_f(acc[n][i] + b);
                msg[n][i] = v;
                pa[i] += v * wa;
            }
        }
        #pragma unroll
        for (int m = 1; m < 16; m <<= 1) {
            #pragma unroll
            for (int i = 0; i < 4; ++i) pa[i] += __shfl_xor(pa[i], m);
        }
        const float bt = batt[0];
        #pragma unroll
        for (int i = 0; i < 4; ++i) {
            const float at = 1.f / (1.f + __expf(-(pa[i] + bt)));
            #pragma unroll
            for (int n = 0; n < 8; ++n)
                csh[er0 + kg*4 + i][n*16 + col] = f2bf(at * msg[n][i]);
        }
    }
    __syncthreads();

    // ---- segmented sum over same-dst runs: 1 atomic per (run, col) ----
    {
        const int nr  = nruns_s;
        const int colx = tid & 127;
        for (int r = tid >> 7; r < nr; r += 2) {
            const int s0 = run_start[r], s1 = run_start[r + 1];
            float sum = 0.f;
            for (int e = s0; e < s1; ++e) sum += bf2f(csh[e][colx]);
            const int drow = dst_s[s0];
            atomicAdd(&out_h[(size_t)drow * HD + colx], sum);
            if (colx < 3) {
                float sx = 0.f;
                for (int e = s0; e < s1; ++e)
                    sx += sc_s[e] * diff_s[e][colx] * rinv_s[e];
                atomicAdd(&out_x[(size_t)drow * 3 + colx], sx);
            }
        }
    }
}

// ---------------------------------------------------------------------------
// Node kernel (MFMA): h_out = h + silu([h,h_agg]@Wn1+bn1)@Wn2+bn2
// ---------------------------------------------------------------------------
__global__ __launch_bounds__(256) void node_kernel(
    const float* __restrict__ h, const float* __restrict__ coords,
    const float* __restrict__ bn1, const float* __restrict__ bn2,
    const unsigned short* __restrict__ wpan,
    float* __restrict__ out_h, float* __restrict__ out_x)
{
    __shared__ __align__(16) unsigned short ash[MT][LPA];
    __shared__ __align__(16) unsigned short csh[MT][LPC];

    const int tid = threadIdx.x;
    const int n0  = blockIdx.x * MT;

    #pragma unroll
    for (int it = 0; it < 16; ++it) {
        const int idx = it * 256 + tid;
        const int e = idx >> 6, q = idx & 63;
        const float* base = (q < 32)
            ? h     + (size_t)(n0 + e) * HD + q * 4
            : out_h + (size_t)(n0 + e) * HD + (q - 32) * 4;
        const float4 v = *(const float4*)base;
        union { unsigned short us[4]; uint2 u2; } p;
        p.us[0] = f2bf(v.x); p.us[1] = f2bf(v.y);
        p.us[2] = f2bf(v.z); p.us[3] = f2bf(v.w);
        *(uint2*)&ash[e][q * 4] = p.u2;
    }
    __syncthreads();

    if (tid < MT * 3) {
        const int n = tid / 3, d = tid % 3;
        const size_t gi = (size_t)(n0 + n) * 3 + d;
        out_x[gi] += coords[gi];
    }

    const int lane = tid & 63;
    const int w    = tid >> 6;
    const int er0  = w * 16;
    const int col  = lane & 15;
    const int kg   = lane >> 4;

    const unsigned short* Wn1t = wpan + O_WN1;
    const unsigned short* Wn2t = wpan + O_WN2;

    const f32x4 zero = {0.f, 0.f, 0.f, 0.f};
    f32x4 acc[8];

    #pragma unroll
    for (int n = 0; n < 8; ++n) acc[n] = zero;
    #pragma unroll
    for (int kc = 0; kc < 8; ++kc) {
        const short8 af = *(const short8*)&ash[er0 + col][kc * 32 + kg * 8];
        #pragma unroll
        for (int n = 0; n < 8; ++n) {
            const short8 bf = *(const short8*)&Wn1t[(size_t)(n*16 + col) * 256 + kc * 32 + kg * 8];
            acc[n] = __builtin_amdgcn_mfma_f32_16x16x32_bf16(af, bf, acc[n], 0, 0, 0);
        }
    }
    #pragma unroll
    for (int n = 0; n < 8; ++n) {
        const float b = bn1[n*16 + col];
        #pragma unroll
        for (int i = 0; i < 4; ++i)
            csh[er0 + kg*4 + i][n*16 + col] = f2bf(silu_f(acc[n][i] + b));
    }
    #pragma unroll
    for (int n = 0; n < 8; ++n) acc[n] = zero;
    #pragma unroll
    for (int kc = 0; kc < 4; ++kc) {
        const short8 af = *(const short8*)&csh[er0 + col][kc * 32 + kg * 8];
        #pragma unroll
        for (int n = 0; n < 8; ++n) {
            const short8 bf = *(const short8*)&Wn2t[(size_t)(n*16 + col) * HD + kc * 32 + kg * 8];
            acc[n] = __builtin_amdgcn_mfma_f32_16x16x32_bf16(af, bf, acc[n], 0, 0, 0);
        }
    }
    #pragma unroll
    for (int i = 0; i < 4; ++i) {
        const int node = n0 + er0 + kg*4 + i;
        const float* hr  = h     + (size_t)node * HD;
        float*       orow = out_h + (size_t)node * HD;
        #pragma unroll
        for (int n = 0; n < 8; ++n) {
            const int f = n*16 + col;
            orow[f] = hr[f] + acc[n][i] + bn2[f];
        }
    }
}

extern "C" void kernel_launch(void* const* d_in, const int* in_sizes, int n_in,
                              void* d_out, int out_size, void* d_ws, size_t ws_size,
                              hipStream_t stream)
{
    const int*   src    = (const int*)  d_in[0];
    const int*   dst    = (const int*)  d_in[1];
    const float* h      = (const float*)d_in[2];
    const float* coords = (const float*)d_in[3];
    const float* a      = (const float*)d_in[4];
    const float* Wc1    = (const float*)d_in[5];
    const float* bc1    = (const float*)d_in[6];
    const float* Wc2    = (const float*)d_in[7];
    const float* bc2    = (const float*)d_in[8];
    const float* Wc3    = (const float*)d_in[9];
    const float* We1    = (const float*)d_in[10];
    const float* be1    = (const float*)d_in[11];
    const float* We2    = (const float*)d_in[12];
    const float* be2    = (const float*)d_in[13];
    const float* Watt   = (const float*)d_in[14];
    const float* batt   = (const float*)d_in[15];
    const float* Wn1    = (const float*)d_in[16];
    const float* bn1    = (const float*)d_in[17];
    const float* Wn2    = (const float*)d_in[18];
    const float* bn2    = (const float*)d_in[19];

    const int E = in_sizes[0];
    const int N = in_sizes[2] / HD;

    float* out_h = (float*)d_out;
    float* out_x = out_h + (size_t)N * HD;

    char* wsb = (char*)d_ws;
    unsigned short* h16  = (unsigned short*)(wsb + B_H16);
    unsigned short* wpan = (unsigned short*)(wsb + B_WPAN);
    unsigned*       cnt  = (unsigned*)      (wsb + B_CNT);
    unsigned*       ofs  = (unsigned*)      (wsb + B_OFS);
    int*            srcp = (int*)           (wsb + B_SRCP);
    int*            dstp = (int*)           (wsb + B_DSTP);
    unsigned short* a16p = (unsigned short*)(wsb + B_A16);

    hipMemsetAsync(d_out, 0, (size_t)out_size * sizeof(float), stream);
    hipMemsetAsync(cnt, 0, (size_t)N * sizeof(unsigned), stream);

    conv_h<<<dim3((N * HD / 4) / 256), dim3(256), 0, stream>>>(h, h16);
    prep_weights<<<dim3(WS_ELEMS / 256), dim3(256), 0, stream>>>(
        Wc1, We1, Wc2, We2, Wn1, Wn2, wpan);

    hist_kernel<<<dim3((E + 255) / 256), dim3(256), 0, stream>>>(dst, cnt, E);
    scan32k<<<dim3(1), dim3(1024), 0, stream>>>(cnt, ofs);
    scatter_perm<<<dim3((E + 255) / 256), dim3(256), 0, stream>>>(
        src, dst, a, ofs, srcp, dstp, a16p, E);

    edge_kernel<<<dim3(E / MT), dim3(256), 0, stream>>>(
        srcp, dstp, a16p, coords, h16,
        bc1, bc2, Wc3, be1, be2, Watt, batt,
        wpan, out_h, out_x);

    node_kernel<<<dim3(N / MT), dim3(256), 0, stream>>>(
        h, coords, bn1, bn2, wpan, out_h, out_x);
}

// Round 5
// 553.107 us; speedup vs baseline: 1.3695x; 1.3695x over previous
//
#include <hip/hip_runtime.h>
#include <math.h>

#define HD   128
#define EFD  16
#define KP   288     // layer-1 K padded: [h_src 0..255(src|dst) | a 256..271 | rad 272 | pad..287]
#define MT   64      // edges / nodes per block
#define LPF  296     // LDS pitch (ushort) for f tile (592B: stride 148 dwords -> 2-way max on b128 reads)
#define LPA  264
#define LPC  136

#define W1SZ (128 * KP)      // 36864 ushorts per layer-1 panel
#define W2SZ (128 * 128)     // 16384
#define O_WE1 (W1SZ)
#define O_WC2 (2 * W1SZ)
#define O_WE2 (2 * W1SZ + W2SZ)
#define O_WN1 (2 * W1SZ + 2 * W2SZ)
#define O_WN2 (2 * W1SZ + 2 * W2SZ + 128 * 256)
#define WS_ELEMS (O_WN2 + W2SZ)          // 155648 ushorts

// ws byte layout
#define B_H16   ((size_t)0)              // 32768*128*2      = 8,388,608
#define B_WPAN  ((size_t)8388608)        // WS_ELEMS*2       =   311,296
#define B_CNT   ((size_t)8699904)        // 32768*4
#define B_OFS   ((size_t)8830976)        // 32768*4
#define B_SRCP  ((size_t)8962048)        // 524288*4
#define B_DSTP  ((size_t)11059200)       // 524288*4
#define B_A16   ((size_t)13156352)       // 524288*16*2 (end ~29.9 MB)

typedef __attribute__((ext_vector_type(8))) short short8;
typedef __attribute__((ext_vector_type(4))) float f32x4;

__device__ __forceinline__ unsigned short f2bf(float x) {
    union { float f; unsigned u; } v; v.f = x;
    unsigned r = v.u + 0x7fffu + ((v.u >> 16) & 1u);
    return (unsigned short)(r >> 16);
}
__device__ __forceinline__ float bf2f(unsigned short u) {
    union { unsigned u; float f; } v; v.u = ((unsigned)u) << 16;
    return v.f;
}
__device__ __forceinline__ float silu_f(float x) { return x / (1.f + __expf(-x)); }

// ---------------------------------------------------------------------------
// h (fp32, N x 128) -> bf16 table
// ---------------------------------------------------------------------------
__global__ __launch_bounds__(256) void conv_h(const float* __restrict__ h,
                                              unsigned short* __restrict__ h16)
{
    const int i = blockIdx.x * 256 + threadIdx.x;
    const float4 v = ((const float4*)h)[i];
    union { unsigned short us[4]; uint2 u2; } p;
    p.us[0] = f2bf(v.x); p.us[1] = f2bf(v.y);
    p.us[2] = f2bf(v.z); p.us[3] = f2bf(v.w);
    ((uint2*)h16)[i] = p.u2;
}

// ---------------------------------------------------------------------------
// Weight prep: fragment-ordered bf16 panels.
// Fragment (n,kc) = 64 lanes x 16B contiguous; lane (kg=lane>>4, col=lane&15)
// holds W[k = kc*32 + kg*8 + j][c = n*16 + col], j=0..7.
// Wave B-load = base + (n*KC+kc)*1024 + lane*16  -> fully coalesced 1KB.
// Layer-1 K remap: k<256 -> k ; 256..271 -> a rows (orig 257..272);
//                  272 -> radial row (orig 256); 273..287 -> 0
// ---------------------------------------------------------------------------
__device__ __forceinline__ void frag_l1(int idx, const float* __restrict__ W,
                                        unsigned short* __restrict__ out)
{
    const int j = idx & 7, lane = (idx >> 3) & 63, blk = idx >> 9;
    const int kc = blk % 9, n = blk / 9;
    const int k = kc * 32 + (lane >> 4) * 8 + j;
    const int c = n * 16 + (lane & 15);
    float v = 0.f;
    if (k < 256) v = W[k * HD + c];
    else if (k < 272) v = W[(k + 1) * HD + c];
    else if (k == 272) v = W[256 * HD + c];
    out[idx] = f2bf(v);
}
__device__ __forceinline__ void frag_sq(int idx, const float* __restrict__ W,
                                        int nkc, unsigned short* __restrict__ out)
{
    const int j = idx & 7, lane = (idx >> 3) & 63, blk = idx >> 9;
    const int kc = blk % nkc, n = blk / nkc;
    const int k = kc * 32 + (lane >> 4) * 8 + j;
    const int c = n * 16 + (lane & 15);
    out[idx] = f2bf(W[k * HD + c]);
}

__global__ __launch_bounds__(256) void prep_weights(
    const float* __restrict__ Wc1, const float* __restrict__ We1,
    const float* __restrict__ Wc2, const float* __restrict__ We2,
    const float* __restrict__ Wn1, const float* __restrict__ Wn2,
    unsigned short* __restrict__ ws)
{
    int idx = blockIdx.x * 256 + threadIdx.x;
    if (idx < W1SZ)            { frag_l1(idx, Wc1, ws);                 return; }
    idx -= W1SZ;
    if (idx < W1SZ)            { frag_l1(idx, We1, ws + O_WE1);         return; }
    idx -= W1SZ;
    if (idx < W2SZ)            { frag_sq(idx, Wc2, 4, ws + O_WC2);      return; }
    idx -= W2SZ;
    if (idx < W2SZ)            { frag_sq(idx, We2, 4, ws + O_WE2);      return; }
    idx -= W2SZ;
    if (idx < 128 * 256)       { frag_sq(idx, Wn1, 8, ws + O_WN1);      return; }
    idx -= 128 * 256;
    if (idx < W2SZ)            { frag_sq(idx, Wn2, 4, ws + O_WN2); }
}

// ---------------------------------------------------------------------------
// Counting sort by dst
// ---------------------------------------------------------------------------
__global__ __launch_bounds__(256) void hist_kernel(const int* __restrict__ dst,
                                                   unsigned* __restrict__ cnt, int E)
{
    const int i = blockIdx.x * 256 + threadIdx.x;
    if (i < E) atomicAdd(&cnt[dst[i]], 1u);
}

__global__ __launch_bounds__(1024) void scan32k(const unsigned* __restrict__ cnt,
                                                unsigned* __restrict__ ofs)
{
    __shared__ unsigned wsum[16];
    __shared__ unsigned carry_s;
    const int tid = threadIdx.x, lane = tid & 63, w = tid >> 6;
    if (tid == 0) carry_s = 0;
    __syncthreads();
    for (int c = 0; c < 32; ++c) {
        const unsigned x = cnt[c * 1024 + tid];
        unsigned v = x;
        #pragma unroll
        for (int off = 1; off < 64; off <<= 1) {
            unsigned t = __shfl_up(v, off);
            if (lane >= off) v += t;
        }
        if (lane == 63) wsum[w] = v;
        __syncthreads();
        if (tid < 16) {
            unsigned s = wsum[tid];
            #pragma unroll
            for (int off = 1; off < 16; off <<= 1) {
                unsigned t = __shfl_up(s, off);
                if (tid >= off) s += t;
            }
            wsum[tid] = s;
        }
        __syncthreads();
        const unsigned carry = carry_s;
        const unsigned woff = (w == 0) ? 0u : wsum[w - 1];
        ofs[c * 1024 + tid] = carry + woff + v - x;
        __syncthreads();
        if (tid == 0) carry_s = carry + wsum[15];
        __syncthreads();
    }
}

__global__ __launch_bounds__(256) void scatter_perm(
    const int* __restrict__ src, const int* __restrict__ dst,
    const float* __restrict__ a, unsigned* __restrict__ ofs,
    int* __restrict__ srcp, int* __restrict__ dstp,
    unsigned short* __restrict__ a16p, int E)
{
    const int i = blockIdx.x * 256 + threadIdx.x;
    if (i >= E) return;
    const int d = dst[i];
    const unsigned pos = atomicAdd(&ofs[d], 1u);
    srcp[pos] = src[i];
    dstp[pos] = d;
    const float* ar = a + (size_t)i * EFD;
    union { unsigned short us[8]; short8 v; } p0, p1;
    #pragma unroll
    for (int t = 0; t < 8; ++t) { p0.us[t] = f2bf(ar[t]); p1.us[t] = f2bf(ar[8 + t]); }
    short8* dstv = (short8*)(a16p + (size_t)pos * EFD);
    dstv[0] = p0.v; dstv[1] = p1.v;
}

// ---------------------------------------------------------------------------
// Edge kernel (MFMA, dst-sorted tiles, fragment-ordered B, segmented scatter)
// ---------------------------------------------------------------------------
__global__ __launch_bounds__(256) void edge_kernel(
    const int* __restrict__ srcp, const int* __restrict__ dstp,
    const unsigned short* __restrict__ a16p,
    const float* __restrict__ coords, const unsigned short* __restrict__ h16,
    const float* __restrict__ bc1, const float* __restrict__ bc2,
    const float* __restrict__ Wc3,
    const float* __restrict__ be1, const float* __restrict__ be2,
    const float* __restrict__ Watt, const float* __restrict__ batt,
    const unsigned short* __restrict__ wpan,
    float* __restrict__ out_h, float* __restrict__ out_x)
{
    __shared__ __align__(16) unsigned short fsh[MT][LPF];
    __shared__ __align__(16) unsigned short csh[MT][LPC];
    __shared__ float diff_s[MT][3];
    __shared__ float rinv_s[MT];
    __shared__ float sc_s[MT];
    __shared__ int   src_s[MT], dst_s[MT];
    __shared__ short run_start[MT + 1];
    __shared__ int   nruns_s;
    __shared__ unsigned long long runmask_s;

    const int tid = threadIdx.x;
    const int e0  = blockIdx.x * MT;

    if (tid < MT) {
        const int s = srcp[e0 + tid], d = dstp[e0 + tid];
        src_s[tid] = s; dst_s[tid] = d;
        const float dx = coords[(size_t)s*3+0] - coords[(size_t)d*3+0];
        const float dy = coords[(size_t)s*3+1] - coords[(size_t)d*3+1];
        const float dz = coords[(size_t)s*3+2] - coords[(size_t)d*3+2];
        diff_s[tid][0] = dx; diff_s[tid][1] = dy; diff_s[tid][2] = dz;
        const float rad = dx*dx + dy*dy + dz*dz;
        rinv_s[tid] = 1.f / (sqrtf(rad + 1e-5f) + 1.f);
        fsh[tid][272] = f2bf(rad);
        #pragma unroll
        for (int c = 273; c < KP; ++c) fsh[tid][c] = 0;
    }
    __syncthreads();

    // run boundaries via wave-0 ballot (dst-sorted tile)
    if (tid < 64) {
        const bool st = (tid == 0) || (dst_s[tid] != dst_s[tid - 1]);
        const unsigned long long m = __ballot(st);
        if (tid == 0) runmask_s = m;
    }

    // gather h16[src] | h16[dst] rows (16B/lane, 256B segments)
    #pragma unroll
    for (int it = 0; it < 8; ++it) {
        const int cid = it * 256 + tid;
        const int e = cid >> 5, q = cid & 31;
        if (q < 16)
            *(short8*)&fsh[e][q * 8] =
                *(const short8*)(h16 + (size_t)src_s[e] * HD + q * 8);
        else
            *(short8*)&fsh[e][128 + (q - 16) * 8] =
                *(const short8*)(h16 + (size_t)dst_s[e] * HD + (q - 16) * 8);
    }
    {   // a tile: cols 256..271
        const int e = tid >> 2, g = tid & 3;
        *(uint2*)&fsh[e][256 + g * 4] =
            *(const uint2*)(a16p + (size_t)(e0 + e) * EFD + g * 4);
    }
    if (tid == 0) {
        unsigned long long m = runmask_s;
        int nr = 0;
        while (m) { run_start[nr++] = (short)__builtin_ctzll(m); m &= m - 1; }
        run_start[nr] = MT;
        nruns_s = nr;
    }
    __syncthreads();

    const int lane = tid & 63;
    const int w    = tid >> 6;
    const int er0  = w * 16;
    const int col  = lane & 15;
    const int kg   = lane >> 4;

    // fragment-ordered panel bases, per-lane 16B slot
    const unsigned short* Wc1p = wpan            + lane * 8;
    const unsigned short* We1p = wpan + O_WE1    + lane * 8;
    const unsigned short* Wc2p = wpan + O_WC2    + lane * 8;
    const unsigned short* We2p = wpan + O_WE2    + lane * 8;

    const f32x4 zero = {0.f, 0.f, 0.f, 0.f};
    f32x4 acc[8];

    // ================= coord-MLP =================
    #pragma unroll
    for (int n = 0; n < 8; ++n) acc[n] = zero;
    #pragma unroll
    for (int kc = 0; kc < 9; ++kc) {
        const short8 af = *(const short8*)&fsh[er0 + col][kc * 32 + kg * 8];
        #pragma unroll
        for (int n = 0; n < 8; ++n) {
            const short8 bf = *(const short8*)&Wc1p[(n * 9 + kc) << 9];
            acc[n] = __builtin_amdgcn_mfma_f32_16x16x32_bf16(af, bf, acc[n], 0, 0, 0);
        }
    }
    #pragma unroll
    for (int n = 0; n < 8; ++n) {
        const float b = bc1[n*16 + col];
        #pragma unroll
        for (int i = 0; i < 4; ++i)
            csh[er0 + kg*4 + i][n*16 + col] = f2bf(silu_f(acc[n][i] + b));
    }
    #pragma unroll
    for (int n = 0; n < 8; ++n) acc[n] = zero;
    #pragma unroll
    for (int kc = 0; kc < 4; ++kc) {
        const short8 af = *(const short8*)&csh[er0 + col][kc * 32 + kg * 8];
        #pragma unroll
        for (int n = 0; n < 8; ++n) {
            const short8 bf = *(const short8*)&Wc2p[(n * 4 + kc) << 9];
            acc[n] = __builtin_amdgcn_mfma_f32_16x16x32_bf16(af, bf, acc[n], 0, 0, 0);
        }
    }
    {   // scale -> sc_s
        float part[4] = {0.f, 0.f, 0.f, 0.f};
        #pragma unroll
        for (int n = 0; n < 8; ++n) {
            const float b  = bc2[n*16 + col];
            const float w3 = Wc3[n*16 + col];
            #pragma unroll
            for (int i = 0; i < 4; ++i) part[i] += silu_f(acc[n][i] + b) * w3;
        }
        #pragma unroll
        for (int m = 1; m < 16; m <<= 1) {
            #pragma unroll
            for (int i = 0; i < 4; ++i) part[i] += __shfl_xor(part[i], m);
        }
        if (col == 0) {
            #pragma unroll
            for (int i = 0; i < 4; ++i) sc_s[er0 + kg*4 + i] = part[i];
        }
    }

    // ================= edge-MLP =================
    #pragma unroll
    for (int n = 0; n < 8; ++n) acc[n] = zero;
    #pragma unroll
    for (int kc = 0; kc < 9; ++kc) {
        const short8 af = *(const short8*)&fsh[er0 + col][kc * 32 + kg * 8];
        #pragma unroll
        for (int n = 0; n < 8; ++n) {
            const short8 bf = *(const short8*)&We1p[(n * 9 + kc) << 9];
            acc[n] = __builtin_amdgcn_mfma_f32_16x16x32_bf16(af, bf, acc[n], 0, 0, 0);
        }
    }
    #pragma unroll
    for (int n = 0; n < 8; ++n) {
        const float b = be1[n*16 + col];
        #pragma unroll
        for (int i = 0; i < 4; ++i)
            csh[er0 + kg*4 + i][n*16 + col] = f2bf(silu_f(acc[n][i] + b));
    }
    #pragma unroll
    for (int n = 0; n < 8; ++n) acc[n] = zero;
    #pragma unroll
    for (int kc = 0; kc < 4; ++kc) {
        const short8 af = *(const short8*)&csh[er0 + col][kc * 32 + kg * 8];
        #pragma unroll
        for (int n = 0; n < 8; ++n) {
            const short8 bf = *(const short8*)&We2p[(n * 4 + kc) << 9];
            acc[n] = __builtin_amdgcn_mfma_f32_16x16x32_bf16(af, bf, acc[n], 0, 0, 0);
        }
    }
    {   // att-gate; gated msg (bf16) -> csh
        float msg[8][4];
        float pa[4] = {0.f, 0.f, 0.f, 0.f};
        #pragma unroll
        for (int n = 0; n < 8; ++n) {
            const float b  = be2[n*16 + col];
            const float wa = Watt[n*16 + col];
            #pragma unroll
            for (int i = 0; i < 4; ++i) {
                const float v = silu_f(acc[n][i] + b);
                msg[n][i] = v;
                pa[i] += v * wa;
            }
        }
        #pragma unroll
        for (int m = 1; m < 16; m <<= 1) {
            #pragma unroll
            for (int i = 0; i < 4; ++i) pa[i] += __shfl_xor(pa[i], m);
        }
        const float bt = batt[0];
        #pragma unroll
        for (int i = 0; i < 4; ++i) {
            const float at = 1.f / (1.f + __expf(-(pa[i] + bt)));
            #pragma unroll
            for (int n = 0; n < 8; ++n)
                csh[er0 + kg*4 + i][n*16 + col] = f2bf(at * msg[n][i]);
        }
    }
    __syncthreads();

    // ---- segmented sum over same-dst runs: 1 atomic per (run, col) ----
    {
        const int nr   = nruns_s;
        const int colx = tid & 127;
        for (int r = tid >> 7; r < nr; r += 2) {
            const int s0 = run_start[r], s1 = run_start[r + 1];
            float sum = 0.f;
            for (int e = s0; e < s1; ++e) sum += bf2f(csh[e][colx]);
            const int drow = dst_s[s0];
            atomicAdd(&out_h[(size_t)drow * HD + colx], sum);
            if (colx < 3) {
                float sx = 0.f;
                for (int e = s0; e < s1; ++e)
                    sx += sc_s[e] * diff_s[e][colx] * rinv_s[e];
                atomicAdd(&out_x[(size_t)drow * 3 + colx], sx);
            }
        }
    }
}

// ---------------------------------------------------------------------------
// Node kernel (MFMA, fragment-ordered B)
// ---------------------------------------------------------------------------
__global__ __launch_bounds__(256) void node_kernel(
    const float* __restrict__ h, const float* __restrict__ coords,
    const float* __restrict__ bn1, const float* __restrict__ bn2,
    const unsigned short* __restrict__ wpan,
    float* __restrict__ out_h, float* __restrict__ out_x)
{
    __shared__ __align__(16) unsigned short ash[MT][LPA];
    __shared__ __align__(16) unsigned short csh[MT][LPC];

    const int tid = threadIdx.x;
    const int n0  = blockIdx.x * MT;

    #pragma unroll
    for (int it = 0; it < 16; ++it) {
        const int idx = it * 256 + tid;
        const int e = idx >> 6, q = idx & 63;
        const float* base = (q < 32)
            ? h     + (size_t)(n0 + e) * HD + q * 4
            : out_h + (size_t)(n0 + e) * HD + (q - 32) * 4;
        const float4 v = *(const float4*)base;
        union { unsigned short us[4]; uint2 u2; } p;
        p.us[0] = f2bf(v.x); p.us[1] = f2bf(v.y);
        p.us[2] = f2bf(v.z); p.us[3] = f2bf(v.w);
        *(uint2*)&ash[e][q * 4] = p.u2;
    }
    __syncthreads();

    if (tid < MT * 3) {
        const int n = tid / 3, d = tid % 3;
        const size_t gi = (size_t)(n0 + n) * 3 + d;
        out_x[gi] += coords[gi];
    }

    const int lane = tid & 63;
    const int w    = tid >> 6;
    const int er0  = w * 16;
    const int col  = lane & 15;
    const int kg   = lane >> 4;

    const unsigned short* Wn1p = wpan + O_WN1 + lane * 8;
    const unsigned short* Wn2p = wpan + O_WN2 + lane * 8;

    const f32x4 zero = {0.f, 0.f, 0.f, 0.f};
    f32x4 acc[8];

    #pragma unroll
    for (int n = 0; n < 8; ++n) acc[n] = zero;
    #pragma unroll
    for (int kc = 0; kc < 8; ++kc) {
        const short8 af = *(const short8*)&ash[er0 + col][kc * 32 + kg * 8];
        #pragma unroll
        for (int n = 0; n < 8; ++n) {
            const short8 bf = *(const short8*)&Wn1p[(n * 8 + kc) << 9];
            acc[n] = __builtin_amdgcn_mfma_f32_16x16x32_bf16(af, bf, acc[n], 0, 0, 0);
        }
    }
    #pragma unroll
    for (int n = 0; n < 8; ++n) {
        const float b = bn1[n*16 + col];
        #pragma unroll
        for (int i = 0; i < 4; ++i)
            csh[er0 + kg*4 + i][n*16 + col] = f2bf(silu_f(acc[n][i] + b));
    }
    #pragma unroll
    for (int n = 0; n < 8; ++n) acc[n] = zero;
    #pragma unroll
    for (int kc = 0; kc < 4; ++kc) {
        const short8 af = *(const short8*)&csh[er0 + col][kc * 32 + kg * 8];
        #pragma unroll
        for (int n = 0; n < 8; ++n) {
            const short8 bf = *(const short8*)&Wn2p[(n * 4 + kc) << 9];
            acc[n] = __builtin_amdgcn_mfma_f32_16x16x32_bf16(af, bf, acc[n], 0, 0, 0);
        }
    }
    #pragma unroll
    for (int i = 0; i < 4; ++i) {
        const int node = n0 + er0 + kg*4 + i;
        const float* hr   = h     + (size_t)node * HD;
        float*       orow = out_h + (size_t)node * HD;
        #pragma unroll
        for (int n = 0; n < 8; ++n) {
            const int f = n*16 + col;
            orow[f] = hr[f] + acc[n][i] + bn2[f];
        }
    }
}

extern "C" void kernel_launch(void* const* d_in, const int* in_sizes, int n_in,
                              void* d_out, int out_size, void* d_ws, size_t ws_size,
                              hipStream_t stream)
{
    const int*   src    = (const int*)  d_in[0];
    const int*   dst    = (const int*)  d_in[1];
    const float* h      = (const float*)d_in[2];
    const float* coords = (const float*)d_in[3];
    const float* a      = (const float*)d_in[4];
    const float* Wc1    = (const float*)d_in[5];
    const float* bc1    = (const float*)d_in[6];
    const float* Wc2    = (const float*)d_in[7];
    const float* bc2    = (const float*)d_in[8];
    const float* Wc3    = (const float*)d_in[9];
    const float* We1    = (const float*)d_in[10];
    const float* be1    = (const float*)d_in[11];
    const float* We2    = (const float*)d_in[12];
    const float* be2    = (const float*)d_in[13];
    const float* Watt   = (const float*)d_in[14];
    const float* batt   = (const float*)d_in[15];
    const float* Wn1    = (const float*)d_in[16];
    const float* bn1    = (const float*)d_in[17];
    const float* Wn2    = (const float*)d_in[18];
    const float* bn2    = (const float*)d_in[19];

    const int E = in_sizes[0];
    const int N = in_sizes[2] / HD;

    float* out_h = (float*)d_out;
    float* out_x = out_h + (size_t)N * HD;

    char* wsb = (char*)d_ws;
    unsigned short* h16  = (unsigned short*)(wsb + B_H16);
    unsigned short* wpan = (unsigned short*)(wsb + B_WPAN);
    unsigned*       cnt  = (unsigned*)      (wsb + B_CNT);
    unsigned*       ofs  = (unsigned*)      (wsb + B_OFS);
    int*            srcp = (int*)           (wsb + B_SRCP);
    int*            dstp = (int*)           (wsb + B_DSTP);
    unsigned short* a16p = (unsigned short*)(wsb + B_A16);

    hipMemsetAsync(d_out, 0, (size_t)out_size * sizeof(float), stream);
    hipMemsetAsync(cnt, 0, (size_t)N * sizeof(unsigned), stream);

    conv_h<<<dim3((N * HD / 4) / 256), dim3(256), 0, stream>>>(h, h16);
    prep_weights<<<dim3(WS_ELEMS / 256), dim3(256), 0, stream>>>(
        Wc1, We1, Wc2, We2, Wn1, Wn2, wpan);

    hist_kernel<<<dim3((E + 255) / 256), dim3(256), 0, stream>>>(dst, cnt, E);
    scan32k<<<dim3(1), dim3(1024), 0, stream>>>(cnt, ofs);
    scatter_perm<<<dim3((E + 255) / 256), dim3(256), 0, stream>>>(
        src, dst, a, ofs, srcp, dstp, a16p, E);

    edge_kernel<<<dim3(E / MT), dim3(256), 0, stream>>>(
        srcp, dstp, a16p, coords, h16,
        bc1, bc2, Wc3, be1, be2, Watt, batt,
        wpan, out_h, out_x);

    node_kernel<<<dim3(N / MT), dim3(256), 0, stream>>>(
        h, coords, bn1, bn2, wpan, out_h, out_x);
}

// Round 6
// 428.352 us; speedup vs baseline: 1.7683x; 1.2912x over previous
//
#include <hip/hip_runtime.h>
#include <math.h>

#define HD   128
#define EFD  16
#define KP   288     // layer-1 K padded: [h_src|h_dst 0..255 | a 256..271 | rad 272 | pad..287]
#define MT   64      // edges / nodes per block
#define LPF  296     // LDS pitch (ushort) for f tile (592B, 16B-aligned rows)
#define LPA  264
#define LPC  136

#define W1SZ (128 * KP)
#define W2SZ (128 * 128)
#define O_WE1 (W1SZ)
#define O_WC2 (2 * W1SZ)
#define O_WE2 (2 * W1SZ + W2SZ)
#define O_WN1 (2 * W1SZ + 2 * W2SZ)
#define O_WN2 (2 * W1SZ + 2 * W2SZ + 128 * 256)
#define WS_ELEMS (O_WN2 + W2SZ)          // 155648 ushorts

// ws byte layout
#define B_H16   ((size_t)0)
#define B_WPAN  ((size_t)8388608)
#define B_CNT   ((size_t)8699904)
#define B_OFS   ((size_t)8830976)
#define B_SRCP  ((size_t)8962048)
#define B_DSTP  ((size_t)11059200)
#define B_A16   ((size_t)13156352)

typedef __attribute__((ext_vector_type(8))) short short8;
typedef __attribute__((ext_vector_type(4))) float f32x4;

__device__ __forceinline__ unsigned short f2bf(float x) {
    union { float f; unsigned u; } v; v.f = x;
    unsigned r = v.u + 0x7fffu + ((v.u >> 16) & 1u);
    return (unsigned short)(r >> 16);
}
__device__ __forceinline__ float bf2f(unsigned short u) {
    union { unsigned u; float f; } v; v.u = ((unsigned)u) << 16;
    return v.f;
}
// fast activation: 1 trans + 1 rcp instead of exact-division chain
__device__ __forceinline__ float sigm_f(float x) {
    return __builtin_amdgcn_rcpf(1.f + __expf(-x));
}
__device__ __forceinline__ float silu_f(float x) { return x * sigm_f(x); }

// ---------------------------------------------------------------------------
__global__ __launch_bounds__(256) void conv_h(const float* __restrict__ h,
                                              unsigned short* __restrict__ h16)
{
    const int i = blockIdx.x * 256 + threadIdx.x;
    const float4 v = ((const float4*)h)[i];
    union { unsigned short us[4]; uint2 u2; } p;
    p.us[0] = f2bf(v.x); p.us[1] = f2bf(v.y);
    p.us[2] = f2bf(v.z); p.us[3] = f2bf(v.w);
    ((uint2*)h16)[i] = p.u2;
}

// ---------------------------------------------------------------------------
// Fragment-ordered bf16 weight panels (unchanged layout from round 5)
// ---------------------------------------------------------------------------
__device__ __forceinline__ void frag_l1(int idx, const float* __restrict__ W,
                                        unsigned short* __restrict__ out)
{
    const int j = idx & 7, lane = (idx >> 3) & 63, blk = idx >> 9;
    const int kc = blk % 9, n = blk / 9;
    const int k = kc * 32 + (lane >> 4) * 8 + j;
    const int c = n * 16 + (lane & 15);
    float v = 0.f;
    if (k < 256) v = W[k * HD + c];
    else if (k < 272) v = W[(k + 1) * HD + c];
    else if (k == 272) v = W[256 * HD + c];
    out[idx] = f2bf(v);
}
__device__ __forceinline__ void frag_sq(int idx, const float* __restrict__ W,
                                        int nkc, unsigned short* __restrict__ out)
{
    const int j = idx & 7, lane = (idx >> 3) & 63, blk = idx >> 9;
    const int kc = blk % nkc, n = blk / nkc;
    const int k = kc * 32 + (lane >> 4) * 8 + j;
    const int c = n * 16 + (lane & 15);
    out[idx] = f2bf(W[k * HD + c]);
}

__global__ __launch_bounds__(256) void prep_weights(
    const float* __restrict__ Wc1, const float* __restrict__ We1,
    const float* __restrict__ Wc2, const float* __restrict__ We2,
    const float* __restrict__ Wn1, const float* __restrict__ Wn2,
    unsigned short* __restrict__ ws)
{
    int idx = blockIdx.x * 256 + threadIdx.x;
    if (idx < W1SZ)            { frag_l1(idx, Wc1, ws);                 return; }
    idx -= W1SZ;
    if (idx < W1SZ)            { frag_l1(idx, We1, ws + O_WE1);         return; }
    idx -= W1SZ;
    if (idx < W2SZ)            { frag_sq(idx, Wc2, 4, ws + O_WC2);      return; }
    idx -= W2SZ;
    if (idx < W2SZ)            { frag_sq(idx, We2, 4, ws + O_WE2);      return; }
    idx -= W2SZ;
    if (idx < 128 * 256)       { frag_sq(idx, Wn1, 8, ws + O_WN1);      return; }
    idx -= 128 * 256;
    if (idx < W2SZ)            { frag_sq(idx, Wn2, 4, ws + O_WN2); }
}

// ---------------------------------------------------------------------------
// Counting sort by dst
// ---------------------------------------------------------------------------
__global__ __launch_bounds__(256) void hist_kernel(const int* __restrict__ dst,
                                                   unsigned* __restrict__ cnt, int E)
{
    const int i = blockIdx.x * 256 + threadIdx.x;
    if (i < E) atomicAdd(&cnt[dst[i]], 1u);
}

__global__ __launch_bounds__(1024) void scan32k(const unsigned* __restrict__ cnt,
                                                unsigned* __restrict__ ofs)
{
    __shared__ unsigned wsum[16];
    __shared__ unsigned carry_s;
    const int tid = threadIdx.x, lane = tid & 63, w = tid >> 6;
    if (tid == 0) carry_s = 0;
    __syncthreads();
    for (int c = 0; c < 32; ++c) {
        const unsigned x = cnt[c * 1024 + tid];
        unsigned v = x;
        #pragma unroll
        for (int off = 1; off < 64; off <<= 1) {
            unsigned t = __shfl_up(v, off);
            if (lane >= off) v += t;
        }
        if (lane == 63) wsum[w] = v;
        __syncthreads();
        if (tid < 16) {
            unsigned s = wsum[tid];
            #pragma unroll
            for (int off = 1; off < 16; off <<= 1) {
                unsigned t = __shfl_up(s, off);
                if (tid >= off) s += t;
            }
            wsum[tid] = s;
        }
        __syncthreads();
        const unsigned carry = carry_s;
        const unsigned woff = (w == 0) ? 0u : wsum[w - 1];
        ofs[c * 1024 + tid] = carry + woff + v - x;
        __syncthreads();
        if (tid == 0) carry_s = carry + wsum[15];
        __syncthreads();
    }
}

__global__ __launch_bounds__(256) void scatter_perm(
    const int* __restrict__ src, const int* __restrict__ dst,
    const float* __restrict__ a, unsigned* __restrict__ ofs,
    int* __restrict__ srcp, int* __restrict__ dstp,
    unsigned short* __restrict__ a16p, int E)
{
    const int i = blockIdx.x * 256 + threadIdx.x;
    if (i >= E) return;
    const int d = dst[i];
    const unsigned pos = atomicAdd(&ofs[d], 1u);
    srcp[pos] = src[i];
    dstp[pos] = d;
    const float* ar = a + (size_t)i * EFD;
    union { unsigned short us[8]; short8 v; } p0, p1;
    #pragma unroll
    for (int t = 0; t < 8; ++t) { p0.us[t] = f2bf(ar[t]); p1.us[t] = f2bf(ar[8 + t]); }
    short8* dstv = (short8*)(a16p + (size_t)pos * EFD);
    dstv[0] = p0.v; dstv[1] = p1.v;
}

// ---------------------------------------------------------------------------
// Edge kernel: 4 waves; wave (eh,nh) = 32 edges x 64 cols. Each B-fragment
// load feeds TWO A-fragments -> L2 weight traffic halved vs round 5.
// ---------------------------------------------------------------------------
__global__ __launch_bounds__(256) void edge_kernel(
    const int* __restrict__ srcp, const int* __restrict__ dstp,
    const unsigned short* __restrict__ a16p,
    const float* __restrict__ coords, const unsigned short* __restrict__ h16,
    const float* __restrict__ bc1, const float* __restrict__ bc2,
    const float* __restrict__ Wc3,
    const float* __restrict__ be1, const float* __restrict__ be2,
    const float* __restrict__ Watt, const float* __restrict__ batt,
    const unsigned short* __restrict__ wpan,
    float* __restrict__ out_h, float* __restrict__ out_x)
{
    __shared__ __align__(16) unsigned short fsh[MT][LPF];
    __shared__ __align__(16) unsigned short csh[MT][LPC];
    __shared__ float diff_s[MT][3];
    __shared__ float rinv_s[MT];
    __shared__ float sc_part[2][MT];
    __shared__ float pa_part[2][MT];
    __shared__ float att_s[MT];
    __shared__ int   src_s[MT], dst_s[MT];
    __shared__ short run_start[MT + 1];
    __shared__ int   nruns_s;
    __shared__ unsigned long long runmask_s;

    const int tid = threadIdx.x;
    const int e0  = blockIdx.x * MT;

    if (tid < MT) {
        const int s = srcp[e0 + tid], d = dstp[e0 + tid];
        src_s[tid] = s; dst_s[tid] = d;
        const float dx = coords[(size_t)s*3+0] - coords[(size_t)d*3+0];
        const float dy = coords[(size_t)s*3+1] - coords[(size_t)d*3+1];
        const float dz = coords[(size_t)s*3+2] - coords[(size_t)d*3+2];
        diff_s[tid][0] = dx; diff_s[tid][1] = dy; diff_s[tid][2] = dz;
        const float rad = dx*dx + dy*dy + dz*dz;
        rinv_s[tid] = __builtin_amdgcn_rcpf(sqrtf(rad + 1e-5f) + 1.f);
        fsh[tid][272] = f2bf(rad);
        #pragma unroll
        for (int c = 273; c < KP; ++c) fsh[tid][c] = 0;
    }
    __syncthreads();

    if (tid < 64) {
        const bool st = (tid == 0) || (dst_s[tid] != dst_s[tid - 1]);
        const unsigned long long m = __ballot(st);
        if (tid == 0) runmask_s = m;
    }

    #pragma unroll
    for (int it = 0; it < 8; ++it) {
        const int cid = it * 256 + tid;
        const int e = cid >> 5, q = cid & 31;
        if (q < 16)
            *(short8*)&fsh[e][q * 8] =
                *(const short8*)(h16 + (size_t)src_s[e] * HD + q * 8);
        else
            *(short8*)&fsh[e][128 + (q - 16) * 8] =
                *(const short8*)(h16 + (size_t)dst_s[e] * HD + (q - 16) * 8);
    }
    {
        const int e = tid >> 2, g = tid & 3;
        *(uint2*)&fsh[e][256 + g * 4] =
            *(const uint2*)(a16p + (size_t)(e0 + e) * EFD + g * 4);
    }
    if (tid == 0) {
        unsigned long long m = runmask_s;
        int nr = 0;
        while (m) { run_start[nr++] = (short)__builtin_ctzll(m); m &= m - 1; }
        run_start[nr] = MT;
        nruns_s = nr;
    }
    __syncthreads();                                     // B0

    const int lane = tid & 63;
    const int w    = tid >> 6;
    const int eh   = w >> 1;          // edge-half (0,1): rows eh*32..+31
    const int nh   = w & 1;           // col-half  (0,1): cols nh*64..+63
    const int er0  = eh * 32;
    const int col  = lane & 15;
    const int kg   = lane >> 4;

    const unsigned short* Wc1p = wpan            + lane * 8;
    const unsigned short* We1p = wpan + O_WE1    + lane * 8;
    const unsigned short* Wc2p = wpan + O_WC2    + lane * 8;
    const unsigned short* We2p = wpan + O_WE2    + lane * 8;

    const f32x4 zero = {0.f, 0.f, 0.f, 0.f};
    f32x4 acc[2][4];

    // ================= coord-MLP layer 1 =================
    #pragma unroll
    for (int fr = 0; fr < 2; ++fr)
        #pragma unroll
        for (int n = 0; n < 4; ++n) acc[fr][n] = zero;
    #pragma unroll
    for (int kc = 0; kc < 9; ++kc) {
        const short8 af0 = *(const short8*)&fsh[er0      + col][kc * 32 + kg * 8];
        const short8 af1 = *(const short8*)&fsh[er0 + 16 + col][kc * 32 + kg * 8];
        #pragma unroll
        for (int n = 0; n < 4; ++n) {
            const int ng = nh * 4 + n;
            const short8 bf = *(const short8*)&Wc1p[(ng * 9 + kc) << 9];
            acc[0][n] = __builtin_amdgcn_mfma_f32_16x16x32_bf16(af0, bf, acc[0][n], 0, 0, 0);
            acc[1][n] = __builtin_amdgcn_mfma_f32_16x16x32_bf16(af1, bf, acc[1][n], 0, 0, 0);
        }
    }
    #pragma unroll
    for (int n = 0; n < 4; ++n) {
        const int ng = nh * 4 + n;
        const float b = bc1[ng*16 + col];
        #pragma unroll
        for (int fr = 0; fr < 2; ++fr)
            #pragma unroll
            for (int i = 0; i < 4; ++i)
                csh[er0 + fr*16 + kg*4 + i][ng*16 + col] = f2bf(silu_f(acc[fr][n][i] + b));
    }
    __syncthreads();                                     // B1: c1 complete

    // ================= coord-MLP layer 2 + scale =================
    #pragma unroll
    for (int fr = 0; fr < 2; ++fr)
        #pragma unroll
        for (int n = 0; n < 4; ++n) acc[fr][n] = zero;
    #pragma unroll
    for (int kc = 0; kc < 4; ++kc) {
        const short8 af0 = *(const short8*)&csh[er0      + col][kc * 32 + kg * 8];
        const short8 af1 = *(const short8*)&csh[er0 + 16 + col][kc * 32 + kg * 8];
        #pragma unroll
        for (int n = 0; n < 4; ++n) {
            const int ng = nh * 4 + n;
            const short8 bf = *(const short8*)&Wc2p[(ng * 4 + kc) << 9];
            acc[0][n] = __builtin_amdgcn_mfma_f32_16x16x32_bf16(af0, bf, acc[0][n], 0, 0, 0);
            acc[1][n] = __builtin_amdgcn_mfma_f32_16x16x32_bf16(af1, bf, acc[1][n], 0, 0, 0);
        }
    }
    {
        float part[2][4] = {{0.f,0.f,0.f,0.f},{0.f,0.f,0.f,0.f}};
        #pragma unroll
        for (int n = 0; n < 4; ++n) {
            const int ng = nh * 4 + n;
            const float b  = bc2[ng*16 + col];
            const float w3 = Wc3[ng*16 + col];
            #pragma unroll
            for (int fr = 0; fr < 2; ++fr)
                #pragma unroll
                for (int i = 0; i < 4; ++i) part[fr][i] += silu_f(acc[fr][n][i] + b) * w3;
        }
        #pragma unroll
        for (int m = 1; m < 16; m <<= 1)
            #pragma unroll
            for (int fr = 0; fr < 2; ++fr)
                #pragma unroll
                for (int i = 0; i < 4; ++i) part[fr][i] += __shfl_xor(part[fr][i], m);
        if (col == 0) {
            #pragma unroll
            for (int fr = 0; fr < 2; ++fr)
                #pragma unroll
                for (int i = 0; i < 4; ++i)
                    sc_part[nh][er0 + fr*16 + kg*4 + i] = part[fr][i];
        }
    }
    __syncthreads();                                     // B2: coord csh reads done

    // ================= edge-MLP layer 1 =================
    #pragma unroll
    for (int fr = 0; fr < 2; ++fr)
        #pragma unroll
        for (int n = 0; n < 4; ++n) acc[fr][n] = zero;
    #pragma unroll
    for (int kc = 0; kc < 9; ++kc) {
        const short8 af0 = *(const short8*)&fsh[er0      + col][kc * 32 + kg * 8];
        const short8 af1 = *(const short8*)&fsh[er0 + 16 + col][kc * 32 + kg * 8];
        #pragma unroll
        for (int n = 0; n < 4; ++n) {
            const int ng = nh * 4 + n;
            const short8 bf = *(const short8*)&We1p[(ng * 9 + kc) << 9];
            acc[0][n] = __builtin_amdgcn_mfma_f32_16x16x32_bf16(af0, bf, acc[0][n], 0, 0, 0);
            acc[1][n] = __builtin_amdgcn_mfma_f32_16x16x32_bf16(af1, bf, acc[1][n], 0, 0, 0);
        }
    }
    #pragma unroll
    for (int n = 0; n < 4; ++n) {
        const int ng = nh * 4 + n;
        const float b = be1[ng*16 + col];
        #pragma unroll
        for (int fr = 0; fr < 2; ++fr)
            #pragma unroll
            for (int i = 0; i < 4; ++i)
                csh[er0 + fr*16 + kg*4 + i][ng*16 + col] = f2bf(silu_f(acc[fr][n][i] + b));
    }
    __syncthreads();                                     // B3: e1 complete

    // ================= edge-MLP layer 2 =================
    #pragma unroll
    for (int fr = 0; fr < 2; ++fr)
        #pragma unroll
        for (int n = 0; n < 4; ++n) acc[fr][n] = zero;
    #pragma unroll
    for (int kc = 0; kc < 4; ++kc) {
        const short8 af0 = *(const short8*)&csh[er0      + col][kc * 32 + kg * 8];
        const short8 af1 = *(const short8*)&csh[er0 + 16 + col][kc * 32 + kg * 8];
        #pragma unroll
        for (int n = 0; n < 4; ++n) {
            const int ng = nh * 4 + n;
            const short8 bf = *(const short8*)&We2p[(ng * 4 + kc) << 9];
            acc[0][n] = __builtin_amdgcn_mfma_f32_16x16x32_bf16(af0, bf, acc[0][n], 0, 0, 0);
            acc[1][n] = __builtin_amdgcn_mfma_f32_16x16x32_bf16(af1, bf, acc[1][n], 0, 0, 0);
        }
    }
    __syncthreads();                                     // B4: e2 csh reads done

    {   // epilogue: ungated msg (bf16) -> csh ; att partial -> pa_part
        float pa[2][4] = {{0.f,0.f,0.f,0.f},{0.f,0.f,0.f,0.f}};
        #pragma unroll
        for (int n = 0; n < 4; ++n) {
            const int ng = nh * 4 + n;
            const float b  = be2[ng*16 + col];
            const float wa = Watt[ng*16 + col];
            #pragma unroll
            for (int fr = 0; fr < 2; ++fr)
                #pragma unroll
                for (int i = 0; i < 4; ++i) {
                    const float v = silu_f(acc[fr][n][i] + b);
                    csh[er0 + fr*16 + kg*4 + i][ng*16 + col] = f2bf(v);
                    pa[fr][i] += v * wa;
                }
        }
        #pragma unroll
        for (int m = 1; m < 16; m <<= 1)
            #pragma unroll
            for (int fr = 0; fr < 2; ++fr)
                #pragma unroll
                for (int i = 0; i < 4; ++i) pa[fr][i] += __shfl_xor(pa[fr][i], m);
        if (col == 0) {
            #pragma unroll
            for (int fr = 0; fr < 2; ++fr)
                #pragma unroll
                for (int i = 0; i < 4; ++i)
                    pa_part[nh][er0 + fr*16 + kg*4 + i] = pa[fr][i];
        }
    }
    __syncthreads();                                     // B5: msg + pa complete

    if (tid < MT)
        att_s[tid] = sigm_f(pa_part[0][tid] + pa_part[1][tid] + batt[0]);
    __syncthreads();                                     // B6

    // ---- segmented sum over same-dst runs: 1 atomic per (run, col) ----
    {
        const int nr   = nruns_s;
        const int colx = tid & 127;
        for (int r = tid >> 7; r < nr; r += 2) {
            const int s0 = run_start[r], s1 = run_start[r + 1];
            float sum = 0.f;
            for (int e = s0; e < s1; ++e) sum += bf2f(csh[e][colx]) * att_s[e];
            const int drow = dst_s[s0];
            atomicAdd(&out_h[(size_t)drow * HD + colx], sum);
            if (colx < 3) {
                float sx = 0.f;
                for (int e = s0; e < s1; ++e)
                    sx += (sc_part[0][e] + sc_part[1][e]) * diff_s[e][colx] * rinv_s[e];
                atomicAdd(&out_x[(size_t)drow * 3 + colx], sx);
            }
        }
    }
}

// ---------------------------------------------------------------------------
// Node kernel (MFMA, fragment-ordered B)
// ---------------------------------------------------------------------------
__global__ __launch_bounds__(256) void node_kernel(
    const float* __restrict__ h, const float* __restrict__ coords,
    const float* __restrict__ bn1, const float* __restrict__ bn2,
    const unsigned short* __restrict__ wpan,
    float* __restrict__ out_h, float* __restrict__ out_x)
{
    __shared__ __align__(16) unsigned short ash[MT][LPA];
    __shared__ __align__(16) unsigned short csh[MT][LPC];

    const int tid = threadIdx.x;
    const int n0  = blockIdx.x * MT;

    #pragma unroll
    for (int it = 0; it < 16; ++it) {
        const int idx = it * 256 + tid;
        const int e = idx >> 6, q = idx & 63;
        const float* base = (q < 32)
            ? h     + (size_t)(n0 + e) * HD + q * 4
            : out_h + (size_t)(n0 + e) * HD + (q - 32) * 4;
        const float4 v = *(const float4*)base;
        union { unsigned short us[4]; uint2 u2; } p;
        p.us[0] = f2bf(v.x); p.us[1] = f2bf(v.y);
        p.us[2] = f2bf(v.z); p.us[3] = f2bf(v.w);
        *(uint2*)&ash[e][q * 4] = p.u2;
    }
    __syncthreads();

    if (tid < MT * 3) {
        const int n = tid / 3, d = tid % 3;
        const size_t gi = (size_t)(n0 + n) * 3 + d;
        out_x[gi] += coords[gi];
    }

    const int lane = tid & 63;
    const int w    = tid >> 6;
    const int er0  = w * 16;
    const int col  = lane & 15;
    const int kg   = lane >> 4;

    const unsigned short* Wn1p = wpan + O_WN1 + lane * 8;
    const unsigned short* Wn2p = wpan + O_WN2 + lane * 8;

    const f32x4 zero = {0.f, 0.f, 0.f, 0.f};
    f32x4 acc[8];

    #pragma unroll
    for (int n = 0; n < 8; ++n) acc[n] = zero;
    #pragma unroll
    for (int kc = 0; kc < 8; ++kc) {
        const short8 af = *(const short8*)&ash[er0 + col][kc * 32 + kg * 8];
        #pragma unroll
        for (int n = 0; n < 8; ++n) {
            const short8 bf = *(const short8*)&Wn1p[(n * 8 + kc) << 9];
            acc[n] = __builtin_amdgcn_mfma_f32_16x16x32_bf16(af, bf, acc[n], 0, 0, 0);
        }
    }
    #pragma unroll
    for (int n = 0; n < 8; ++n) {
        const float b = bn1[n*16 + col];
        #pragma unroll
        for (int i = 0; i < 4; ++i)
            csh[er0 + kg*4 + i][n*16 + col] = f2bf(silu_f(acc[n][i] + b));
    }
    #pragma unroll
    for (int n = 0; n < 8; ++n) acc[n] = zero;
    #pragma unroll
    for (int kc = 0; kc < 4; ++kc) {
        const short8 af = *(const short8*)&csh[er0 + col][kc * 32 + kg * 8];
        #pragma unroll
        for (int n = 0; n < 8; ++n) {
            const short8 bf = *(const short8*)&Wn2p[(n * 4 + kc) << 9];
            acc[n] = __builtin_amdgcn_mfma_f32_16x16x32_bf16(af, bf, acc[n], 0, 0, 0);
        }
    }
    #pragma unroll
    for (int i = 0; i < 4; ++i) {
        const int node = n0 + er0 + kg*4 + i;
        const float* hr   = h     + (size_t)node * HD;
        float*       orow = out_h + (size_t)node * HD;
        #pragma unroll
        for (int n = 0; n < 8; ++n) {
            const int f = n*16 + col;
            orow[f] = hr[f] + acc[n][i] + bn2[f];
        }
    }
}

extern "C" void kernel_launch(void* const* d_in, const int* in_sizes, int n_in,
                              void* d_out, int out_size, void* d_ws, size_t ws_size,
                              hipStream_t stream)
{
    const int*   src    = (const int*)  d_in[0];
    const int*   dst    = (const int*)  d_in[1];
    const float* h      = (const float*)d_in[2];
    const float* coords = (const float*)d_in[3];
    const float* a      = (const float*)d_in[4];
    const float* Wc1    = (const float*)d_in[5];
    const float* bc1    = (const float*)d_in[6];
    const float* Wc2    = (const float*)d_in[7];
    const float* bc2    = (const float*)d_in[8];
    const float* Wc3    = (const float*)d_in[9];
    const float* We1    = (const float*)d_in[10];
    const float* be1    = (const float*)d_in[11];
    const float* We2    = (const float*)d_in[12];
    const float* be2    = (const float*)d_in[13];
    const float* Watt   = (const float*)d_in[14];
    const float* batt   = (const float*)d_in[15];
    const float* Wn1    = (const float*)d_in[16];
    const float* bn1    = (const float*)d_in[17];
    const float* Wn2    = (const float*)d_in[18];
    const float* bn2    = (const float*)d_in[19];

    const int E = in_sizes[0];
    const int N = in_sizes[2] / HD;

    float* out_h = (float*)d_out;
    float* out_x = out_h + (size_t)N * HD;

    char* wsb = (char*)d_ws;
    unsigned short* h16  = (unsigned short*)(wsb + B_H16);
    unsigned short* wpan = (unsigned short*)(wsb + B_WPAN);
    unsigned*       cnt  = (unsigned*)      (wsb + B_CNT);
    unsigned*       ofs  = (unsigned*)      (wsb + B_OFS);
    int*            srcp = (int*)           (wsb + B_SRCP);
    int*            dstp = (int*)           (wsb + B_DSTP);
    unsigned short* a16p = (unsigned short*)(wsb + B_A16);

    hipMemsetAsync(d_out, 0, (size_t)out_size * sizeof(float), stream);
    hipMemsetAsync(cnt, 0, (size_t)N * sizeof(unsigned), stream);

    conv_h<<<dim3((N * HD / 4) / 256), dim3(256), 0, stream>>>(h, h16);
    prep_weights<<<dim3(WS_ELEMS / 256), dim3(256), 0, stream>>>(
        Wc1, We1, Wc2, We2, Wn1, Wn2, wpan);

    hist_kernel<<<dim3((E + 255) / 256), dim3(256), 0, stream>>>(dst, cnt, E);
    scan32k<<<dim3(1), dim3(1024), 0, stream>>>(cnt, ofs);
    scatter_perm<<<dim3((E + 255) / 256), dim3(256), 0, stream>>>(
        src, dst, a, ofs, srcp, dstp, a16p, E);

    edge_kernel<<<dim3(E / MT), dim3(256), 0, stream>>>(
        srcp, dstp, a16p, coords, h16,
        bc1, bc2, Wc3, be1, be2, Watt, batt,
        wpan, out_h, out_x);

    node_kernel<<<dim3(N / MT), dim3(256), 0, stream>>>(
        h, coords, bn1, bn2, wpan, out_h, out_x);
}

// Round 7
// 402.683 us; speedup vs baseline: 1.8811x; 1.0637x over previous
//
#include <hip/hip_runtime.h>
#include <math.h>

#define HD   128
#define EFD  16
#define MT   64      // edges / nodes per block
#define LPA  264
#define LPC  136     // LDS pitch (ushort) for layer-1 out tiles

#define W1SZ (128 * 288)     // layer-1 panel: 128 cols x KP(288) fragment-ordered
#define W2SZ (128 * 128)
#define O_WE1 (W1SZ)
#define O_WC2 (2 * W1SZ)
#define O_WE2 (2 * W1SZ + W2SZ)
#define O_WN1 (2 * W1SZ + 2 * W2SZ)
#define O_WN2 (2 * W1SZ + 2 * W2SZ + 128 * 256)
#define WS_ELEMS (O_WN2 + W2SZ)

// ws byte layout
#define B_H16   ((size_t)0)
#define B_WPAN  ((size_t)8388608)
#define B_CNT   ((size_t)8699904)
#define B_OFS   ((size_t)8830976)
#define B_SRCP  ((size_t)8962048)
#define B_DSTP  ((size_t)11059200)
#define B_A16   ((size_t)13156352)

typedef __attribute__((ext_vector_type(8))) short short8;
typedef __attribute__((ext_vector_type(4))) float f32x4;

__device__ __forceinline__ unsigned short f2bf(float x) {
    union { float f; unsigned u; } v; v.f = x;
    unsigned r = v.u + 0x7fffu + ((v.u >> 16) & 1u);
    return (unsigned short)(r >> 16);
}
__device__ __forceinline__ float bf2f(unsigned short u) {
    union { unsigned u; float f; } v; v.u = ((unsigned)u) << 16;
    return v.f;
}
__device__ __forceinline__ float sigm_f(float x) {
    return __builtin_amdgcn_rcpf(1.f + __expf(-x));
}
__device__ __forceinline__ float silu_f(float x) { return x * sigm_f(x); }

// ---------------------------------------------------------------------------
__global__ __launch_bounds__(256) void conv_h(const float* __restrict__ h,
                                              unsigned short* __restrict__ h16)
{
    const int i = blockIdx.x * 256 + threadIdx.x;
    const float4 v = ((const float4*)h)[i];
    union { unsigned short us[4]; uint2 u2; } p;
    p.us[0] = f2bf(v.x); p.us[1] = f2bf(v.y);
    p.us[2] = f2bf(v.z); p.us[3] = f2bf(v.w);
    ((uint2*)h16)[i] = p.u2;
}

// ---------------------------------------------------------------------------
// Fragment-ordered bf16 weight panels (layout unchanged from round 5/6)
// ---------------------------------------------------------------------------
__device__ __forceinline__ void frag_l1(int idx, const float* __restrict__ W,
                                        unsigned short* __restrict__ out)
{
    const int j = idx & 7, lane = (idx >> 3) & 63, blk = idx >> 9;
    const int kc = blk % 9, n = blk / 9;
    const int k = kc * 32 + (lane >> 4) * 8 + j;
    const int c = n * 16 + (lane & 15);
    float v = 0.f;
    if (k < 256) v = W[k * HD + c];
    else if (k < 272) v = W[(k + 1) * HD + c];
    else if (k == 272) v = W[256 * HD + c];
    out[idx] = f2bf(v);
}
__device__ __forceinline__ void frag_sq(int idx, const float* __restrict__ W,
                                        int nkc, unsigned short* __restrict__ out)
{
    const int j = idx & 7, lane = (idx >> 3) & 63, blk = idx >> 9;
    const int kc = blk % nkc, n = blk / nkc;
    const int k = kc * 32 + (lane >> 4) * 8 + j;
    const int c = n * 16 + (lane & 15);
    out[idx] = f2bf(W[k * HD + c]);
}

__global__ __launch_bounds__(256) void prep_weights(
    const float* __restrict__ Wc1, const float* __restrict__ We1,
    const float* __restrict__ Wc2, const float* __restrict__ We2,
    const float* __restrict__ Wn1, const float* __restrict__ Wn2,
    unsigned short* __restrict__ ws)
{
    int idx = blockIdx.x * 256 + threadIdx.x;
    if (idx < W1SZ)            { frag_l1(idx, Wc1, ws);                 return; }
    idx -= W1SZ;
    if (idx < W1SZ)            { frag_l1(idx, We1, ws + O_WE1);         return; }
    idx -= W1SZ;
    if (idx < W2SZ)            { frag_sq(idx, Wc2, 4, ws + O_WC2);      return; }
    idx -= W2SZ;
    if (idx < W2SZ)            { frag_sq(idx, We2, 4, ws + O_WE2);      return; }
    idx -= W2SZ;
    if (idx < 128 * 256)       { frag_sq(idx, Wn1, 8, ws + O_WN1);      return; }
    idx -= 128 * 256;
    if (idx < W2SZ)            { frag_sq(idx, Wn2, 4, ws + O_WN2); }
}

// ---------------------------------------------------------------------------
// Counting sort by dst
// ---------------------------------------------------------------------------
__global__ __launch_bounds__(256) void hist_kernel(const int* __restrict__ dst,
                                                   unsigned* __restrict__ cnt, int E)
{
    const int i = blockIdx.x * 256 + threadIdx.x;
    if (i < E) atomicAdd(&cnt[dst[i]], 1u);
}

__global__ __launch_bounds__(1024) void scan32k(const unsigned* __restrict__ cnt,
                                                unsigned* __restrict__ ofs)
{
    __shared__ unsigned wsum[16];
    __shared__ unsigned carry_s;
    const int tid = threadIdx.x, lane = tid & 63, w = tid >> 6;
    if (tid == 0) carry_s = 0;
    __syncthreads();
    for (int c = 0; c < 32; ++c) {
        const unsigned x = cnt[c * 1024 + tid];
        unsigned v = x;
        #pragma unroll
        for (int off = 1; off < 64; off <<= 1) {
            unsigned t = __shfl_up(v, off);
            if (lane >= off) v += t;
        }
        if (lane == 63) wsum[w] = v;
        __syncthreads();
        if (tid < 16) {
            unsigned s = wsum[tid];
            #pragma unroll
            for (int off = 1; off < 16; off <<= 1) {
                unsigned t = __shfl_up(s, off);
                if (tid >= off) s += t;
            }
            wsum[tid] = s;
        }
        __syncthreads();
        const unsigned carry = carry_s;
        const unsigned woff = (w == 0) ? 0u : wsum[w - 1];
        ofs[c * 1024 + tid] = carry + woff + v - x;
        __syncthreads();
        if (tid == 0) carry_s = carry + wsum[15];
        __syncthreads();
    }
}

__global__ __launch_bounds__(256) void scatter_perm(
    const int* __restrict__ src, const int* __restrict__ dst,
    const float* __restrict__ a, unsigned* __restrict__ ofs,
    int* __restrict__ srcp, int* __restrict__ dstp,
    unsigned short* __restrict__ a16p, int E)
{
    const int i = blockIdx.x * 256 + threadIdx.x;
    if (i >= E) return;
    const int d = dst[i];
    const unsigned pos = atomicAdd(&ofs[d], 1u);
    srcp[pos] = src[i];
    dstp[pos] = d;
    const float* ar = a + (size_t)i * EFD;
    union { unsigned short us[8]; short8 v; } p0, p1;
    #pragma unroll
    for (int t = 0; t < 8; ++t) { p0.us[t] = f2bf(ar[t]); p1.us[t] = f2bf(ar[8 + t]); }
    short8* dstv = (short8*)(a16p + (size_t)pos * EFD);
    dstv[0] = p0.v; dstv[1] = p1.v;
}

// ---------------------------------------------------------------------------
// Edge kernel: no f-tile in LDS — A-fragments gathered direct from global
// (h16 rows, 16B chunks). coord+edge MLPs fused per phase (shared A).
// 4 waves: wave (eh,nh) = 32 edges x 64 cols. LDS ~38KB -> 4 blocks/CU.
// ---------------------------------------------------------------------------
__global__ __launch_bounds__(256, 4) void edge_kernel(
    const int* __restrict__ srcp, const int* __restrict__ dstp,
    const unsigned short* __restrict__ a16p,
    const float* __restrict__ coords, const unsigned short* __restrict__ h16,
    const float* __restrict__ bc1, const float* __restrict__ bc2,
    const float* __restrict__ Wc3,
    const float* __restrict__ be1, const float* __restrict__ be2,
    const float* __restrict__ Watt, const float* __restrict__ batt,
    const unsigned short* __restrict__ wpan,
    float* __restrict__ out_h, float* __restrict__ out_x)
{
    __shared__ __align__(16) unsigned short csh_c[MT][LPC];  // c1 out
    __shared__ __align__(16) unsigned short csh_e[MT][LPC];  // e1 out, then msg
    __shared__ float diff_s[MT][3];
    __shared__ float rinv_s[MT];
    __shared__ float rad_s[MT];
    __shared__ float sc_part[2][MT];
    __shared__ float pa_part[2][MT];
    __shared__ float att_s[MT];
    __shared__ int   src_s[MT], dst_s[MT];
    __shared__ short run_start[MT + 1];
    __shared__ int   nruns_s;

    const int tid = threadIdx.x;
    const int e0  = blockIdx.x * MT;

    if (tid < MT) {
        const int s = srcp[e0 + tid], d = dstp[e0 + tid];
        src_s[tid] = s; dst_s[tid] = d;
        const float dx = coords[(size_t)s*3+0] - coords[(size_t)d*3+0];
        const float dy = coords[(size_t)s*3+1] - coords[(size_t)d*3+1];
        const float dz = coords[(size_t)s*3+2] - coords[(size_t)d*3+2];
        diff_s[tid][0] = dx; diff_s[tid][1] = dy; diff_s[tid][2] = dz;
        const float rad = dx*dx + dy*dy + dz*dz;
        rad_s[tid]  = rad;
        rinv_s[tid] = __builtin_amdgcn_rcpf(sqrtf(rad + 1e-5f) + 1.f);
    }
    __syncthreads();                                     // Ba: indices visible

    // wave 0: run boundaries (visible to segsum via later barriers)
    if (tid < 64) {
        const bool st = (tid == 0) || (dst_s[tid] != dst_s[tid - 1]);
        unsigned long long m = __ballot(st);
        if (tid == 0) {
            int nr = 0;
            while (m) { run_start[nr++] = (short)__builtin_ctzll(m); m &= m - 1; }
            run_start[nr] = MT;
            nruns_s = nr;
        }
    }

    const int lane = tid & 63;
    const int w    = tid >> 6;
    const int eh   = w >> 1;          // edge-half: rows eh*32..+31
    const int nh   = w & 1;           // col-half:  cols nh*64..+63
    const int er0  = eh * 32;
    const int col  = lane & 15;
    const int kg   = lane >> 4;
    const int r0   = er0 + col;
    const int r1   = er0 + 16 + col;

    const unsigned short* Wc1p = wpan            + lane * 8;
    const unsigned short* We1p = wpan + O_WE1    + lane * 8;
    const unsigned short* Wc2p = wpan + O_WC2    + lane * 8;
    const unsigned short* We2p = wpan + O_WE2    + lane * 8;

    // per-lane A-gather bases
    const unsigned short* hs0 = h16 + (size_t)src_s[r0] * HD;
    const unsigned short* hs1 = h16 + (size_t)src_s[r1] * HD;
    const unsigned short* hd0 = h16 + (size_t)dst_s[r0] * HD;
    const unsigned short* hd1 = h16 + (size_t)dst_s[r1] * HD;

    const f32x4 zero = {0.f, 0.f, 0.f, 0.f};
    const short8 zf  = {0,0,0,0,0,0,0,0};
    f32x4 ac[2][4], ae[2][4];

    // ================= layer 1 (coord + edge fused) =================
    #pragma unroll
    for (int fr = 0; fr < 2; ++fr)
        #pragma unroll
        for (int n = 0; n < 4; ++n) { ac[fr][n] = zero; ae[fr][n] = zero; }

    #pragma unroll
    for (int kc = 0; kc < 9; ++kc) {
        short8 af0, af1;
        if (kc < 4) {
            af0 = *(const short8*)(hs0 + kc * 32 + kg * 8);
            af1 = *(const short8*)(hs1 + kc * 32 + kg * 8);
        } else if (kc < 8) {
            af0 = *(const short8*)(hd0 + (kc - 4) * 32 + kg * 8);
            af1 = *(const short8*)(hd1 + (kc - 4) * 32 + kg * 8);
        } else {
            if (kg < 2) {
                af0 = *(const short8*)(a16p + (size_t)(e0 + r0) * EFD + kg * 8);
                af1 = *(const short8*)(a16p + (size_t)(e0 + r1) * EFD + kg * 8);
            } else if (kg == 2) {
                af0 = zf; af1 = zf;
                af0[0] = (short)f2bf(rad_s[r0]);
                af1[0] = (short)f2bf(rad_s[r1]);
            } else {
                af0 = zf; af1 = zf;
            }
        }
        #pragma unroll
        for (int n = 0; n < 4; ++n) {
            const int ng = nh * 4 + n;
            const short8 bc = *(const short8*)&Wc1p[(ng * 9 + kc) << 9];
            ac[0][n] = __builtin_amdgcn_mfma_f32_16x16x32_bf16(af0, bc, ac[0][n], 0, 0, 0);
            ac[1][n] = __builtin_amdgcn_mfma_f32_16x16x32_bf16(af1, bc, ac[1][n], 0, 0, 0);
            const short8 be = *(const short8*)&We1p[(ng * 9 + kc) << 9];
            ae[0][n] = __builtin_amdgcn_mfma_f32_16x16x32_bf16(af0, be, ae[0][n], 0, 0, 0);
            ae[1][n] = __builtin_amdgcn_mfma_f32_16x16x32_bf16(af1, be, ae[1][n], 0, 0, 0);
        }
    }
    #pragma unroll
    for (int n = 0; n < 4; ++n) {
        const int ng = nh * 4 + n;
        const float b1c = bc1[ng*16 + col];
        const float b1e = be1[ng*16 + col];
        #pragma unroll
        for (int fr = 0; fr < 2; ++fr)
            #pragma unroll
            for (int i = 0; i < 4; ++i) {
                const int rr = er0 + fr*16 + kg*4 + i;
                csh_c[rr][ng*16 + col] = f2bf(silu_f(ac[fr][n][i] + b1c));
                csh_e[rr][ng*16 + col] = f2bf(silu_f(ae[fr][n][i] + b1e));
            }
    }
    __syncthreads();                                     // B1: l1 outputs visible

    // ================= layer 2 (coord + edge fused) =================
    #pragma unroll
    for (int fr = 0; fr < 2; ++fr)
        #pragma unroll
        for (int n = 0; n < 4; ++n) { ac[fr][n] = zero; ae[fr][n] = zero; }

    #pragma unroll
    for (int kc = 0; kc < 4; ++kc) {
        const short8 ac0 = *(const short8*)&csh_c[r0][kc * 32 + kg * 8];
        const short8 ac1 = *(const short8*)&csh_c[r1][kc * 32 + kg * 8];
        const short8 ae0 = *(const short8*)&csh_e[r0][kc * 32 + kg * 8];
        const short8 ae1 = *(const short8*)&csh_e[r1][kc * 32 + kg * 8];
        #pragma unroll
        for (int n = 0; n < 4; ++n) {
            const int ng = nh * 4 + n;
            const short8 bc = *(const short8*)&Wc2p[(ng * 4 + kc) << 9];
            ac[0][n] = __builtin_amdgcn_mfma_f32_16x16x32_bf16(ac0, bc, ac[0][n], 0, 0, 0);
            ac[1][n] = __builtin_amdgcn_mfma_f32_16x16x32_bf16(ac1, bc, ac[1][n], 0, 0, 0);
            const short8 be = *(const short8*)&We2p[(ng * 4 + kc) << 9];
            ae[0][n] = __builtin_amdgcn_mfma_f32_16x16x32_bf16(ae0, be, ae[0][n], 0, 0, 0);
            ae[1][n] = __builtin_amdgcn_mfma_f32_16x16x32_bf16(ae1, be, ae[1][n], 0, 0, 0);
        }
    }
    {   // scale = silu(c2).Wc3 reduce -> sc_part
        float part[2][4] = {{0.f,0.f,0.f,0.f},{0.f,0.f,0.f,0.f}};
        #pragma unroll
        for (int n = 0; n < 4; ++n) {
            const int ng = nh * 4 + n;
            const float b  = bc2[ng*16 + col];
            const float w3 = Wc3[ng*16 + col];
            #pragma unroll
            for (int fr = 0; fr < 2; ++fr)
                #pragma unroll
                for (int i = 0; i < 4; ++i) part[fr][i] += silu_f(ac[fr][n][i] + b) * w3;
        }
        #pragma unroll
        for (int m = 1; m < 16; m <<= 1)
            #pragma unroll
            for (int fr = 0; fr < 2; ++fr)
                #pragma unroll
                for (int i = 0; i < 4; ++i) part[fr][i] += __shfl_xor(part[fr][i], m);
        if (col == 0) {
            #pragma unroll
            for (int fr = 0; fr < 2; ++fr)
                #pragma unroll
                for (int i = 0; i < 4; ++i)
                    sc_part[nh][er0 + fr*16 + kg*4 + i] = part[fr][i];
        }
    }
    __syncthreads();                                     // B2: csh_e l2 reads done

    {   // msg epilogue: ungated msg -> csh_e ; att partial -> pa_part
        float pa[2][4] = {{0.f,0.f,0.f,0.f},{0.f,0.f,0.f,0.f}};
        #pragma unroll
        for (int n = 0; n < 4; ++n) {
            const int ng = nh * 4 + n;
            const float b  = be2[ng*16 + col];
            const float wa = Watt[ng*16 + col];
            #pragma unroll
            for (int fr = 0; fr < 2; ++fr)
                #pragma unroll
                for (int i = 0; i < 4; ++i) {
                    const float v = silu_f(ae[fr][n][i] + b);
                    csh_e[er0 + fr*16 + kg*4 + i][ng*16 + col] = f2bf(v);
                    pa[fr][i] += v * wa;
                }
        }
        #pragma unroll
        for (int m = 1; m < 16; m <<= 1)
            #pragma unroll
            for (int fr = 0; fr < 2; ++fr)
                #pragma unroll
                for (int i = 0; i < 4; ++i) pa[fr][i] += __shfl_xor(pa[fr][i], m);
        if (col == 0) {
            #pragma unroll
            for (int fr = 0; fr < 2; ++fr)
                #pragma unroll
                for (int i = 0; i < 4; ++i)
                    pa_part[nh][er0 + fr*16 + kg*4 + i] = pa[fr][i];
        }
    }
    __syncthreads();                                     // B3: msg + pa visible

    if (tid < MT)
        att_s[tid] = sigm_f(pa_part[0][tid] + pa_part[1][tid] + batt[0]);
    __syncthreads();                                     // B4

    // ---- segmented sum over same-dst runs: 1 atomic per (run, col) ----
    {
        const int nr   = nruns_s;
        const int colx = tid & 127;
        for (int r = tid >> 7; r < nr; r += 2) {
            const int s0 = run_start[r], s1 = run_start[r + 1];
            float sum = 0.f;
            for (int e = s0; e < s1; ++e) sum += bf2f(csh_e[e][colx]) * att_s[e];
            const int drow = dst_s[s0];
            atomicAdd(&out_h[(size_t)drow * HD + colx], sum);
            if (colx < 3) {
                float sx = 0.f;
                for (int e = s0; e < s1; ++e)
                    sx += (sc_part[0][e] + sc_part[1][e]) * diff_s[e][colx] * rinv_s[e];
                atomicAdd(&out_x[(size_t)drow * 3 + colx], sx);
            }
        }
    }
}

// ---------------------------------------------------------------------------
// Node kernel (MFMA, fragment-ordered B) — unchanged
// ---------------------------------------------------------------------------
__global__ __launch_bounds__(256) void node_kernel(
    const float* __restrict__ h, const float* __restrict__ coords,
    const float* __restrict__ bn1, const float* __restrict__ bn2,
    const unsigned short* __restrict__ wpan,
    float* __restrict__ out_h, float* __restrict__ out_x)
{
    __shared__ __align__(16) unsigned short ash[MT][LPA];
    __shared__ __align__(16) unsigned short csh[MT][LPC];

    const int tid = threadIdx.x;
    const int n0  = blockIdx.x * MT;

    #pragma unroll
    for (int it = 0; it < 16; ++it) {
        const int idx = it * 256 + tid;
        const int e = idx >> 6, q = idx & 63;
        const float* base = (q < 32)
            ? h     + (size_t)(n0 + e) * HD + q * 4
            : out_h + (size_t)(n0 + e) * HD + (q - 32) * 4;
        const float4 v = *(const float4*)base;
        union { unsigned short us[4]; uint2 u2; } p;
        p.us[0] = f2bf(v.x); p.us[1] = f2bf(v.y);
        p.us[2] = f2bf(v.z); p.us[3] = f2bf(v.w);
        *(uint2*)&ash[e][q * 4] = p.u2;
    }
    __syncthreads();

    if (tid < MT * 3) {
        const int n = tid / 3, d = tid % 3;
        const size_t gi = (size_t)(n0 + n) * 3 + d;
        out_x[gi] += coords[gi];
    }

    const int lane = tid & 63;
    const int w    = tid >> 6;
    const int er0  = w * 16;
    const int col  = lane & 15;
    const int kg   = lane >> 4;

    const unsigned short* Wn1p = wpan + O_WN1 + lane * 8;
    const unsigned short* Wn2p = wpan + O_WN2 + lane * 8;

    const f32x4 zero = {0.f, 0.f, 0.f, 0.f};
    f32x4 acc[8];

    #pragma unroll
    for (int n = 0; n < 8; ++n) acc[n] = zero;
    #pragma unroll
    for (int kc = 0; kc < 8; ++kc) {
        const short8 af = *(const short8*)&ash[er0 + col][kc * 32 + kg * 8];
        #pragma unroll
        for (int n = 0; n < 8; ++n) {
            const short8 bf = *(const short8*)&Wn1p[(n * 8 + kc) << 9];
            acc[n] = __builtin_amdgcn_mfma_f32_16x16x32_bf16(af, bf, acc[n], 0, 0, 0);
        }
    }
    #pragma unroll
    for (int n = 0; n < 8; ++n) {
        const float b = bn1[n*16 + col];
        #pragma unroll
        for (int i = 0; i < 4; ++i)
            csh[er0 + kg*4 + i][n*16 + col] = f2bf(silu_f(acc[n][i] + b));
    }
    __syncthreads();
    #pragma unroll
    for (int n = 0; n < 8; ++n) acc[n] = zero;
    #pragma unroll
    for (int kc = 0; kc < 4; ++kc) {
        const short8 af = *(const short8*)&csh[er0 + col][kc * 32 + kg * 8];
        #pragma unroll
        for (int n = 0; n < 8; ++n) {
            const short8 bf = *(const short8*)&Wn2p[(n * 4 + kc) << 9];
            acc[n] = __builtin_amdgcn_mfma_f32_16x16x32_bf16(af, bf, acc[n], 0, 0, 0);
        }
    }
    #pragma unroll
    for (int i = 0; i < 4; ++i) {
        const int node = n0 + er0 + kg*4 + i;
        const float* hr   = h     + (size_t)node * HD;
        float*       orow = out_h + (size_t)node * HD;
        #pragma unroll
        for (int n = 0; n < 8; ++n) {
            const int f = n*16 + col;
            orow[f] = hr[f] + acc[n][i] + bn2[f];
        }
    }
}

extern "C" void kernel_launch(void* const* d_in, const int* in_sizes, int n_in,
                              void* d_out, int out_size, void* d_ws, size_t ws_size,
                              hipStream_t stream)
{
    const int*   src    = (const int*)  d_in[0];
    const int*   dst    = (const int*)  d_in[1];
    const float* h      = (const float*)d_in[2];
    const float* coords = (const float*)d_in[3];
    const float* a      = (const float*)d_in[4];
    const float* Wc1    = (const float*)d_in[5];
    const float* bc1    = (const float*)d_in[6];
    const float* Wc2    = (const float*)d_in[7];
    const float* bc2    = (const float*)d_in[8];
    const float* Wc3    = (const float*)d_in[9];
    const float* We1    = (const float*)d_in[10];
    const float* be1    = (const float*)d_in[11];
    const float* We2    = (const float*)d_in[12];
    const float* be2    = (const float*)d_in[13];
    const float* Watt   = (const float*)d_in[14];
    const float* batt   = (const float*)d_in[15];
    const float* Wn1    = (const float*)d_in[16];
    const float* bn1    = (const float*)d_in[17];
    const float* Wn2    = (const float*)d_in[18];
    const float* bn2    = (const float*)d_in[19];

    const int E = in_sizes[0];
    const int N = in_sizes[2] / HD;

    float* out_h = (float*)d_out;
    float* out_x = out_h + (size_t)N * HD;

    char* wsb = (char*)d_ws;
    unsigned short* h16  = (unsigned short*)(wsb + B_H16);
    unsigned short* wpan = (unsigned short*)(wsb + B_WPAN);
    unsigned*       cnt  = (unsigned*)      (wsb + B_CNT);
    unsigned*       ofs  = (unsigned*)      (wsb + B_OFS);
    int*            srcp = (int*)           (wsb + B_SRCP);
    int*            dstp = (int*)           (wsb + B_DSTP);
    unsigned short* a16p = (unsigned short*)(wsb + B_A16);

    hipMemsetAsync(d_out, 0, (size_t)out_size * sizeof(float), stream);
    hipMemsetAsync(cnt, 0, (size_t)N * sizeof(unsigned), stream);

    conv_h<<<dim3((N * HD / 4) / 256), dim3(256), 0, stream>>>(h, h16);
    prep_weights<<<dim3(WS_ELEMS / 256), dim3(256), 0, stream>>>(
        Wc1, We1, Wc2, We2, Wn1, Wn2, wpan);

    hist_kernel<<<dim3((E + 255) / 256), dim3(256), 0, stream>>>(dst, cnt, E);
    scan32k<<<dim3(1), dim3(1024), 0, stream>>>(cnt, ofs);
    scatter_perm<<<dim3((E + 255) / 256), dim3(256), 0, stream>>>(
        src, dst, a, ofs, srcp, dstp, a16p, E);

    edge_kernel<<<dim3(E / MT), dim3(256), 0, stream>>>(
        srcp, dstp, a16p, coords, h16,
        bc1, bc2, Wc3, be1, be2, Watt, batt,
        wpan, out_h, out_x);

    node_kernel<<<dim3(N / MT), dim3(256), 0, stream>>>(
        h, coords, bn1, bn2, wpan, out_h, out_x);
}

// Round 8
// 337.803 us; speedup vs baseline: 2.2424x; 1.1921x over previous
//
#include <hip/hip_runtime.h>
#include <math.h>

#define HD   128
#define EFD  16
#define MT   64      // edges / nodes per block
#define LPA  264
#define LPC  136     // LDS pitch (ushort): rows=edges, cols=hidden(128)+pad

#define W1SZ (128 * 288)
#define W2SZ (128 * 128)
#define O_WE1 (W1SZ)
#define O_WC2 (2 * W1SZ)
#define O_WE2 (2 * W1SZ + W2SZ)
#define O_WN1 (2 * W1SZ + 2 * W2SZ)
#define O_WN2 (2 * W1SZ + 2 * W2SZ + 128 * 256)
#define WS_ELEMS (O_WN2 + W2SZ)

// ws byte layout
#define B_H16   ((size_t)0)
#define B_WPAN  ((size_t)8388608)
#define B_CNT   ((size_t)8699904)
#define B_OFS   ((size_t)8830976)
#define B_SRCP  ((size_t)8962048)
#define B_DSTP  ((size_t)11059200)
#define B_A16   ((size_t)13156352)

typedef __attribute__((ext_vector_type(8))) short short8;
typedef __attribute__((ext_vector_type(4))) float f32x4;

// native bf16 conversion (compiler pairs into v_cvt_pk_bf16_f32)
__device__ __forceinline__ unsigned short f2bf(float x) {
    __bf16 b = (__bf16)x;
    unsigned short u;
    __builtin_memcpy(&u, &b, 2);
    return u;
}
__device__ __forceinline__ float bf2f(unsigned short u) {
    union { unsigned u; float f; } v; v.u = ((unsigned)u) << 16;
    return v.f;
}
__device__ __forceinline__ float sigm_f(float x) {
    return __builtin_amdgcn_rcpf(1.f + __expf(-x));
}
__device__ __forceinline__ float silu_f(float x) { return x * sigm_f(x); }
__device__ __forceinline__ unsigned pack2(float a, float b) {
    return (unsigned)f2bf(a) | ((unsigned)f2bf(b) << 16);
}

// ---------------------------------------------------------------------------
__global__ __launch_bounds__(256) void conv_h(const float* __restrict__ h,
                                              unsigned short* __restrict__ h16)
{
    const int i = blockIdx.x * 256 + threadIdx.x;
    const float4 v = ((const float4*)h)[i];
    union { unsigned short us[4]; uint2 u2; } p;
    p.us[0] = f2bf(v.x); p.us[1] = f2bf(v.y);
    p.us[2] = f2bf(v.z); p.us[3] = f2bf(v.w);
    ((uint2*)h16)[i] = p.u2;
}

// ---------------------------------------------------------------------------
// Fragment-ordered bf16 weight panels (same layout; used as MFMA *A* operand
// now — A and B frag lane layouts are identical on 16x16x32).
// l1 K remap: k<256 -> k ; 256..271 -> a rows (orig 257..272);
// 272 -> radial (orig 256); 273 -> BIAS (folded, data supplies 1.0); else 0
// ---------------------------------------------------------------------------
__device__ __forceinline__ void frag_l1(int idx, const float* __restrict__ W,
                                        const float* __restrict__ bias,
                                        unsigned short* __restrict__ out)
{
    const int j = idx & 7, lane = (idx >> 3) & 63, blk = idx >> 9;
    const int kc = blk % 9, n = blk / 9;
    const int k = kc * 32 + (lane >> 4) * 8 + j;
    const int c = n * 16 + (lane & 15);
    float v = 0.f;
    if (k < 256) v = W[k * HD + c];
    else if (k < 272) v = W[(k + 1) * HD + c];
    else if (k == 272) v = W[256 * HD + c];
    else if (k == 273) v = bias[c];
    out[idx] = f2bf(v);
}
__device__ __forceinline__ void frag_sq(int idx, const float* __restrict__ W,
                                        int nkc, unsigned short* __restrict__ out)
{
    const int j = idx & 7, lane = (idx >> 3) & 63, blk = idx >> 9;
    const int kc = blk % nkc, n = blk / nkc;
    const int k = kc * 32 + (lane >> 4) * 8 + j;
    const int c = n * 16 + (lane & 15);
    out[idx] = f2bf(W[k * HD + c]);
}

__global__ __launch_bounds__(256) void prep_weights(
    const float* __restrict__ Wc1, const float* __restrict__ bc1,
    const float* __restrict__ We1, const float* __restrict__ be1,
    const float* __restrict__ Wc2, const float* __restrict__ We2,
    const float* __restrict__ Wn1, const float* __restrict__ Wn2,
    unsigned short* __restrict__ ws)
{
    int idx = blockIdx.x * 256 + threadIdx.x;
    if (idx < W1SZ)            { frag_l1(idx, Wc1, bc1, ws);            return; }
    idx -= W1SZ;
    if (idx < W1SZ)            { frag_l1(idx, We1, be1, ws + O_WE1);    return; }
    idx -= W1SZ;
    if (idx < W2SZ)            { frag_sq(idx, Wc2, 4, ws + O_WC2);      return; }
    idx -= W2SZ;
    if (idx < W2SZ)            { frag_sq(idx, We2, 4, ws + O_WE2);      return; }
    idx -= W2SZ;
    if (idx < 128 * 256)       { frag_sq(idx, Wn1, 8, ws + O_WN1);      return; }
    idx -= 128 * 256;
    if (idx < W2SZ)            { frag_sq(idx, Wn2, 4, ws + O_WN2); }
}

// ---------------------------------------------------------------------------
// Counting sort by dst
// ---------------------------------------------------------------------------
__global__ __launch_bounds__(256) void hist_kernel(const int* __restrict__ dst,
                                                   unsigned* __restrict__ cnt, int E)
{
    const int i = blockIdx.x * 256 + threadIdx.x;
    if (i < E) atomicAdd(&cnt[dst[i]], 1u);
}

__global__ __launch_bounds__(1024) void scan32k(const unsigned* __restrict__ cnt,
                                                unsigned* __restrict__ ofs)
{
    __shared__ unsigned wsum[16];
    __shared__ unsigned carry_s;
    const int tid = threadIdx.x, lane = tid & 63, w = tid >> 6;
    if (tid == 0) carry_s = 0;
    __syncthreads();
    for (int c = 0; c < 32; ++c) {
        const unsigned x = cnt[c * 1024 + tid];
        unsigned v = x;
        #pragma unroll
        for (int off = 1; off < 64; off <<= 1) {
            unsigned t = __shfl_up(v, off);
            if (lane >= off) v += t;
        }
        if (lane == 63) wsum[w] = v;
        __syncthreads();
        if (tid < 16) {
            unsigned s = wsum[tid];
            #pragma unroll
            for (int off = 1; off < 16; off <<= 1) {
                unsigned t = __shfl_up(s, off);
                if (tid >= off) s += t;
            }
            wsum[tid] = s;
        }
        __syncthreads();
        const unsigned carry = carry_s;
        const unsigned woff = (w == 0) ? 0u : wsum[w - 1];
        ofs[c * 1024 + tid] = carry + woff + v - x;
        __syncthreads();
        if (tid == 0) carry_s = carry + wsum[15];
        __syncthreads();
    }
}

__global__ __launch_bounds__(256) void scatter_perm(
    const int* __restrict__ src, const int* __restrict__ dst,
    const float* __restrict__ a, unsigned* __restrict__ ofs,
    int* __restrict__ srcp, int* __restrict__ dstp,
    unsigned short* __restrict__ a16p, int E)
{
    const int i = blockIdx.x * 256 + threadIdx.x;
    if (i >= E) return;
    const int d = dst[i];
    const unsigned pos = atomicAdd(&ofs[d], 1u);
    srcp[pos] = src[i];
    dstp[pos] = d;
    const float* ar = a + (size_t)i * EFD;
    union { unsigned short us[8]; short8 v; } p0, p1;
    #pragma unroll
    for (int t = 0; t < 8; ++t) { p0.us[t] = f2bf(ar[t]); p1.us[t] = f2bf(ar[8 + t]); }
    short8* dstv = (short8*)(a16p + (size_t)pos * EFD);
    dstv[0] = p0.v; dstv[1] = p1.v;
}

// ---------------------------------------------------------------------------
// Edge kernel — SWAPPED operands: C[out x edge] = mfma(A=Wt frag, B=data frag)
// Wave w owns out-cols w*32..w*32+31 for ALL 64 edges; both MLPs fused.
// Weight panels stream through the block exactly once (208 KB/block).
// ---------------------------------------------------------------------------
__global__ __launch_bounds__(256, 4) void edge_kernel(
    const int* __restrict__ srcp, const int* __restrict__ dstp,
    const unsigned short* __restrict__ a16p,
    const float* __restrict__ coords, const unsigned short* __restrict__ h16,
    const float* __restrict__ bc2, const float* __restrict__ Wc3,
    const float* __restrict__ be2,
    const float* __restrict__ Watt, const float* __restrict__ batt,
    const unsigned short* __restrict__ wpan,
    float* __restrict__ out_h, float* __restrict__ out_x)
{
    __shared__ __align__(16) unsigned short csh_c[MT][LPC];  // c1act [edge][hidden]
    __shared__ __align__(16) unsigned short csh_e[MT][LPC];  // e1act, then msg
    __shared__ float diff_s[MT][3];
    __shared__ float rinv_s[MT];
    __shared__ float rad_s[MT];
    __shared__ float sc_part[4][MT];
    __shared__ float pa_part[4][MT];
    __shared__ float att_s[MT];
    __shared__ float sc_s[MT];
    __shared__ int   src_s[MT], dst_s[MT];
    __shared__ short run_start[MT + 1];
    __shared__ int   nruns_s;

    const int tid = threadIdx.x;
    const int e0  = blockIdx.x * MT;

    if (tid < MT) {
        const int s = srcp[e0 + tid], d = dstp[e0 + tid];
        src_s[tid] = s; dst_s[tid] = d;
        const float dx = coords[(size_t)s*3+0] - coords[(size_t)d*3+0];
        const float dy = coords[(size_t)s*3+1] - coords[(size_t)d*3+1];
        const float dz = coords[(size_t)s*3+2] - coords[(size_t)d*3+2];
        diff_s[tid][0] = dx; diff_s[tid][1] = dy; diff_s[tid][2] = dz;
        const float rad = dx*dx + dy*dy + dz*dz;
        rad_s[tid]  = rad;
        rinv_s[tid] = __builtin_amdgcn_rcpf(sqrtf(rad + 1e-5f) + 1.f);
    }
    __syncthreads();                                     // Ba

    if (tid < 64) {
        const bool st = (tid == 0) || (dst_s[tid] != dst_s[tid - 1]);
        unsigned long long m = __ballot(st);
        if (tid == 0) {
            int nr = 0;
            while (m) { run_start[nr++] = (short)__builtin_ctzll(m); m &= m - 1; }
            run_start[nr] = MT;
            nruns_s = nr;
        }
    }

    const int lane = tid & 63;
    const int w    = tid >> 6;        // out-col quarter: cols w*32..+31
    const int w2   = w * 2;           // first 16-wide out tile index
    const int col  = lane & 15;       // edge within 16-tile (B/C col)
    const int kg   = lane >> 4;

    const unsigned short* Wc1p = wpan            + lane * 8;
    const unsigned short* We1p = wpan + O_WE1    + lane * 8;
    const unsigned short* Wc2p = wpan + O_WC2    + lane * 8;
    const unsigned short* We2p = wpan + O_WE2    + lane * 8;

    // per-lane data (B) gather bases: edge rows et*16+col
    const unsigned short* hs[4];
    const unsigned short* hd[4];
    #pragma unroll
    for (int et = 0; et < 4; ++et) {
        const int r = et * 16 + col;
        hs[et] = h16 + (size_t)src_s[r] * HD;
        hd[et] = h16 + (size_t)dst_s[r] * HD;
    }

    const f32x4 zero = {0.f, 0.f, 0.f, 0.f};
    const short8 zf  = {0,0,0,0,0,0,0,0};
    f32x4 ac[2][4], ae[2][4];

    // ================= layer 1 (coord + edge fused; bias folded at k=273) ====
    #pragma unroll
    for (int m = 0; m < 2; ++m)
        #pragma unroll
        for (int et = 0; et < 4; ++et) { ac[m][et] = zero; ae[m][et] = zero; }

    #pragma unroll
    for (int kc = 0; kc < 9; ++kc) {
        short8 df[4];
        #pragma unroll
        for (int et = 0; et < 4; ++et) {
            if (kc < 4)       df[et] = *(const short8*)(hs[et] + kc * 32 + kg * 8);
            else if (kc < 8)  df[et] = *(const short8*)(hd[et] + (kc - 4) * 32 + kg * 8);
            else if (kg < 2)  df[et] = *(const short8*)(a16p + (size_t)(e0 + et*16 + col) * EFD + kg * 8);
            else if (kg == 2) {
                df[et] = zf;
                df[et][0] = (short)f2bf(rad_s[et*16 + col]);  // k=272: radial
                df[et][1] = (short)0x3F80;                    // k=273: 1.0 (bias row)
            } else df[et] = zf;
        }
        #pragma unroll
        for (int m = 0; m < 2; ++m) {
            const short8 wc = *(const short8*)&Wc1p[((w2 + m) * 9 + kc) << 9];
            const short8 we = *(const short8*)&We1p[((w2 + m) * 9 + kc) << 9];
            #pragma unroll
            for (int et = 0; et < 4; ++et) {
                ac[m][et] = __builtin_amdgcn_mfma_f32_16x16x32_bf16(wc, df[et], ac[m][et], 0, 0, 0);
                ae[m][et] = __builtin_amdgcn_mfma_f32_16x16x32_bf16(we, df[et], ae[m][et], 0, 0, 0);
            }
        }
    }
    // epilogue: silu; (i,i+1) pairs are LDS-adjacent -> packed b32 stores
    #pragma unroll
    for (int m = 0; m < 2; ++m)
        #pragma unroll
        for (int et = 0; et < 4; ++et) {
            const int row = et * 16 + col;
            #pragma unroll
            for (int i = 0; i < 4; i += 2) {
                const int hw = w * 32 + m * 16 + kg * 4 + i;
                *(unsigned*)&csh_c[row][hw] =
                    pack2(silu_f(ac[m][et][i]), silu_f(ac[m][et][i+1]));
                *(unsigned*)&csh_e[row][hw] =
                    pack2(silu_f(ae[m][et][i]), silu_f(ae[m][et][i+1]));
            }
        }
    __syncthreads();                                     // B1: l1 acts visible

    // ================= layer 2 (coord + edge fused) =================
    #pragma unroll
    for (int m = 0; m < 2; ++m)
        #pragma unroll
        for (int et = 0; et < 4; ++et) { ac[m][et] = zero; ae[m][et] = zero; }

    #pragma unroll
    for (int kc = 0; kc < 4; ++kc) {
        short8 dc[4], de[4];
        #pragma unroll
        for (int et = 0; et < 4; ++et) {
            const int row = et * 16 + col;
            dc[et] = *(const short8*)&csh_c[row][kc * 32 + kg * 8];
            de[et] = *(const short8*)&csh_e[row][kc * 32 + kg * 8];
        }
        #pragma unroll
        for (int m = 0; m < 2; ++m) {
            const short8 wc = *(const short8*)&Wc2p[((w2 + m) * 4 + kc) << 9];
            const short8 we = *(const short8*)&We2p[((w2 + m) * 4 + kc) << 9];
            #pragma unroll
            for (int et = 0; et < 4; ++et) {
                ac[m][et] = __builtin_amdgcn_mfma_f32_16x16x32_bf16(wc, dc[et], ac[m][et], 0, 0, 0);
                ae[m][et] = __builtin_amdgcn_mfma_f32_16x16x32_bf16(we, de[et], ae[m][et], 0, 0, 0);
            }
        }
    }

    {   // scale partial: lane-local over this wave's 32 out-cols + kg-reduce
        float sc[4] = {0.f, 0.f, 0.f, 0.f};
        #pragma unroll
        for (int m = 0; m < 2; ++m)
            #pragma unroll
            for (int i = 0; i < 4; ++i) {
                const int hw = w * 32 + m * 16 + kg * 4 + i;
                const float b = bc2[hw], w3 = Wc3[hw];
                #pragma unroll
                for (int et = 0; et < 4; ++et)
                    sc[et] += silu_f(ac[m][et][i] + b) * w3;
            }
        #pragma unroll
        for (int et = 0; et < 4; ++et) {
            sc[et] += __shfl_xor(sc[et], 16);
            sc[et] += __shfl_xor(sc[et], 32);
        }
        if (kg == 0) {
            #pragma unroll
            for (int et = 0; et < 4; ++et)
                sc_part[w][et * 16 + col] = sc[et];
        }
    }
    __syncthreads();                                     // B2: csh_e l2 reads done

    {   // msg: silu(e2+b) -> packed store to csh_e ; att partial
        float pa[4] = {0.f, 0.f, 0.f, 0.f};
        #pragma unroll
        for (int m = 0; m < 2; ++m)
            #pragma unroll
            for (int et = 0; et < 4; ++et) {
                const int row = et * 16 + col;
                #pragma unroll
                for (int i = 0; i < 4; i += 2) {
                    const int hw = w * 32 + m * 16 + kg * 4 + i;
                    const float v0 = silu_f(ae[m][et][i]   + be2[hw]);
                    const float v1 = silu_f(ae[m][et][i+1] + be2[hw+1]);
                    pa[et] += v0 * Watt[hw] + v1 * Watt[hw+1];
                    *(unsigned*)&csh_e[row][hw] = pack2(v0, v1);
                }
            }
        #pragma unroll
        for (int et = 0; et < 4; ++et) {
            pa[et] += __shfl_xor(pa[et], 16);
            pa[et] += __shfl_xor(pa[et], 32);
        }
        if (kg == 0) {
            #pragma unroll
            for (int et = 0; et < 4; ++et)
                pa_part[w][et * 16 + col] = pa[et];
        }
    }
    __syncthreads();                                     // B3: msg + partials

    if (tid < MT) {
        att_s[tid] = sigm_f(pa_part[0][tid] + pa_part[1][tid] +
                            pa_part[2][tid] + pa_part[3][tid] + batt[0]);
        sc_s[tid]  = (sc_part[0][tid] + sc_part[1][tid] +
                      sc_part[2][tid] + sc_part[3][tid]) * rinv_s[tid];
    }
    __syncthreads();                                     // B4

    // ---- segmented sum over same-dst runs: 1 atomic per (run, col) ----
    {
        const int nr   = nruns_s;
        const int colx = tid & 127;
        for (int r = tid >> 7; r < nr; r += 2) {
            const int s0 = run_start[r], s1 = run_start[r + 1];
            float sum = 0.f;
            for (int e = s0; e < s1; ++e) sum += bf2f(csh_e[e][colx]) * att_s[e];
            const int drow = dst_s[s0];
            atomicAdd(&out_h[(size_t)drow * HD + colx], sum);
            if (colx < 3) {
                float sx = 0.f;
                for (int e = s0; e < s1; ++e)
                    sx += sc_s[e] * diff_s[e][colx];
                atomicAdd(&out_x[(size_t)drow * 3 + colx], sx);
            }
        }
    }
}

// ---------------------------------------------------------------------------
// Node kernel (unchanged structure; native casts)
// ---------------------------------------------------------------------------
__global__ __launch_bounds__(256) void node_kernel(
    const float* __restrict__ h, const float* __restrict__ coords,
    const float* __restrict__ bn1, const float* __restrict__ bn2,
    const unsigned short* __restrict__ wpan,
    float* __restrict__ out_h, float* __restrict__ out_x)
{
    __shared__ __align__(16) unsigned short ash[MT][LPA];
    __shared__ __align__(16) unsigned short csh[MT][LPC];

    const int tid = threadIdx.x;
    const int n0  = blockIdx.x * MT;

    #pragma unroll
    for (int it = 0; it < 16; ++it) {
        const int idx = it * 256 + tid;
        const int e = idx >> 6, q = idx & 63;
        const float* base = (q < 32)
            ? h     + (size_t)(n0 + e) * HD + q * 4
            : out_h + (size_t)(n0 + e) * HD + (q - 32) * 4;
        const float4 v = *(const float4*)base;
        union { unsigned short us[4]; uint2 u2; } p;
        p.us[0] = f2bf(v.x); p.us[1] = f2bf(v.y);
        p.us[2] = f2bf(v.z); p.us[3] = f2bf(v.w);
        *(uint2*)&ash[e][q * 4] = p.u2;
    }
    __syncthreads();

    if (tid < MT * 3) {
        const int n = tid / 3, d = tid % 3;
        const size_t gi = (size_t)(n0 + n) * 3 + d;
        out_x[gi] += coords[gi];
    }

    const int lane = tid & 63;
    const int w    = tid >> 6;
    const int er0  = w * 16;
    const int col  = lane & 15;
    const int kg   = lane >> 4;

    const unsigned short* Wn1p = wpan + O_WN1 + lane * 8;
    const unsigned short* Wn2p = wpan + O_WN2 + lane * 8;

    const f32x4 zero = {0.f, 0.f, 0.f, 0.f};
    f32x4 acc[8];

    #pragma unroll
    for (int n = 0; n < 8; ++n) acc[n] = zero;
    #pragma unroll
    for (int kc = 0; kc < 8; ++kc) {
        const short8 af = *(const short8*)&ash[er0 + col][kc * 32 + kg * 8];
        #pragma unroll
        for (int n = 0; n < 8; ++n) {
            const short8 bf = *(const short8*)&Wn1p[(n * 8 + kc) << 9];
            acc[n] = __builtin_amdgcn_mfma_f32_16x16x32_bf16(af, bf, acc[n], 0, 0, 0);
        }
    }
    #pragma unroll
    for (int n = 0; n < 8; ++n) {
        const float b = bn1[n*16 + col];
        #pragma unroll
        for (int i = 0; i < 4; ++i)
            csh[er0 + kg*4 + i][n*16 + col] = f2bf(silu_f(acc[n][i] + b));
    }
    __syncthreads();
    #pragma unroll
    for (int n = 0; n < 8; ++n) acc[n] = zero;
    #pragma unroll
    for (int kc = 0; kc < 4; ++kc) {
        const short8 af = *(const short8*)&csh[er0 + col][kc * 32 + kg * 8];
        #pragma unroll
        for (int n = 0; n < 8; ++n) {
            const short8 bf = *(const short8*)&Wn2p[(n * 4 + kc) << 9];
            acc[n] = __builtin_amdgcn_mfma_f32_16x16x32_bf16(af, bf, acc[n], 0, 0, 0);
        }
    }
    #pragma unroll
    for (int i = 0; i < 4; ++i) {
        const int node = n0 + er0 + kg*4 + i;
        const float* hr   = h     + (size_t)node * HD;
        float*       orow = out_h + (size_t)node * HD;
        #pragma unroll
        for (int n = 0; n < 8; ++n) {
            const int f = n*16 + col;
            orow[f] = hr[f] + acc[n][i] + bn2[f];
        }
    }
}

extern "C" void kernel_launch(void* const* d_in, const int* in_sizes, int n_in,
                              void* d_out, int out_size, void* d_ws, size_t ws_size,
                              hipStream_t stream)
{
    const int*   src    = (const int*)  d_in[0];
    const int*   dst    = (const int*)  d_in[1];
    const float* h      = (const float*)d_in[2];
    const float* coords = (const float*)d_in[3];
    const float* a      = (const float*)d_in[4];
    const float* Wc1    = (const float*)d_in[5];
    const float* bc1    = (const float*)d_in[6];
    const float* Wc2    = (const float*)d_in[7];
    const float* bc2    = (const float*)d_in[8];
    const float* Wc3    = (const float*)d_in[9];
    const float* We1    = (const float*)d_in[10];
    const float* be1    = (const float*)d_in[11];
    const float* We2    = (const float*)d_in[12];
    const float* be2    = (const float*)d_in[13];
    const float* Watt   = (const float*)d_in[14];
    const float* batt   = (const float*)d_in[15];
    const float* Wn1    = (const float*)d_in[16];
    const float* bn1    = (const float*)d_in[17];
    const float* Wn2    = (const float*)d_in[18];
    const float* bn2    = (const float*)d_in[19];

    const int E = in_sizes[0];
    const int N = in_sizes[2] / HD;

    float* out_h = (float*)d_out;
    float* out_x = out_h + (size_t)N * HD;

    char* wsb = (char*)d_ws;
    unsigned short* h16  = (unsigned short*)(wsb + B_H16);
    unsigned short* wpan = (unsigned short*)(wsb + B_WPAN);
    unsigned*       cnt  = (unsigned*)      (wsb + B_CNT);
    unsigned*       ofs  = (unsigned*)      (wsb + B_OFS);
    int*            srcp = (int*)           (wsb + B_SRCP);
    int*            dstp = (int*)           (wsb + B_DSTP);
    unsigned short* a16p = (unsigned short*)(wsb + B_A16);

    hipMemsetAsync(d_out, 0, (size_t)out_size * sizeof(float), stream);
    hipMemsetAsync(cnt, 0, (size_t)N * sizeof(unsigned), stream);

    conv_h<<<dim3((N * HD / 4) / 256), dim3(256), 0, stream>>>(h, h16);
    prep_weights<<<dim3(WS_ELEMS / 256), dim3(256), 0, stream>>>(
        Wc1, bc1, We1, be1, Wc2, We2, Wn1, Wn2, wpan);

    hist_kernel<<<dim3((E + 255) / 256), dim3(256), 0, stream>>>(dst, cnt, E);
    scan32k<<<dim3(1), dim3(1024), 0, stream>>>(cnt, ofs);
    scatter_perm<<<dim3((E + 255) / 256), dim3(256), 0, stream>>>(
        src, dst, a, ofs, srcp, dstp, a16p, E);

    edge_kernel<<<dim3(E / MT), dim3(256), 0, stream>>>(
        srcp, dstp, a16p, coords, h16,
        bc2, Wc3, be2, Watt, batt,
        wpan, out_h, out_x);

    node_kernel<<<dim3(N / MT), dim3(256), 0, stream>>>(
        h, coords, bn1, bn2, wpan, out_h, out_x);
}

// Round 9
// 324.263 us; speedup vs baseline: 2.3360x; 1.0418x over previous
//
#include <hip/hip_runtime.h>
#include <math.h>

#define HD   128
#define EFD  16
#define MT   64      // edges / nodes per block
#define LPA  264
#define LPC  136     // LDS pitch (ushort): rows=edges, cols=hidden(128)+pad

#define W1SZ (128 * 288)
#define W2SZ (128 * 128)
#define O_WE1 (W1SZ)
#define O_WC2 (2 * W1SZ)
#define O_WE2 (2 * W1SZ + W2SZ)
#define O_WN1 (2 * W1SZ + 2 * W2SZ)
#define O_WN2 (2 * W1SZ + 2 * W2SZ + 128 * 256)
#define WS_ELEMS (O_WN2 + W2SZ)          // 155648

// ws byte layout
#define B_H16   ((size_t)0)
#define B_WPAN  ((size_t)8388608)
#define B_CNT   ((size_t)8699904)
#define B_OFS   ((size_t)8830976)
#define B_SRCP  ((size_t)8962048)
#define B_DSTP  ((size_t)11059200)
#define B_A16   ((size_t)13156352)

typedef __attribute__((ext_vector_type(8))) short short8;
typedef __attribute__((ext_vector_type(4))) float f32x4;

__device__ __forceinline__ unsigned short f2bf(float x) {
    __bf16 b = (__bf16)x;
    unsigned short u;
    __builtin_memcpy(&u, &b, 2);
    return u;
}
__device__ __forceinline__ float bf2f(unsigned short u) {
    union { unsigned u; float f; } v; v.u = ((unsigned)u) << 16;
    return v.f;
}
__device__ __forceinline__ float sigm_f(float x) {
    return __builtin_amdgcn_rcpf(1.f + __expf(-x));
}
__device__ __forceinline__ float silu_f(float x) { return x * sigm_f(x); }
__device__ __forceinline__ unsigned pack2(float a, float b) {
    return (unsigned)f2bf(a) | ((unsigned)f2bf(b) << 16);
}

// ---------------------------------------------------------------------------
// Fragment-ordered bf16 weight panels (A-operand layout).
// l1 K remap: k<256 -> k ; 256..271 -> a rows (orig 257..272);
// 272 -> radial (orig 256); 273 -> BIAS (data supplies 1.0); else 0
// ---------------------------------------------------------------------------
__device__ __forceinline__ void frag_l1(int idx, const float* __restrict__ W,
                                        const float* __restrict__ bias,
                                        unsigned short* __restrict__ out)
{
    const int j = idx & 7, lane = (idx >> 3) & 63, blk = idx >> 9;
    const int kc = blk % 9, n = blk / 9;
    const int k = kc * 32 + (lane >> 4) * 8 + j;
    const int c = n * 16 + (lane & 15);
    float v = 0.f;
    if (k < 256) v = W[k * HD + c];
    else if (k < 272) v = W[(k + 1) * HD + c];
    else if (k == 272) v = W[256 * HD + c];
    else if (k == 273) v = bias[c];
    out[idx] = f2bf(v);
}
__device__ __forceinline__ void frag_sq(int idx, const float* __restrict__ W,
                                        int nkc, unsigned short* __restrict__ out)
{
    const int j = idx & 7, lane = (idx >> 3) & 63, blk = idx >> 9;
    const int kc = blk % nkc, n = blk / nkc;
    const int k = kc * 32 + (lane >> 4) * 8 + j;
    const int c = n * 16 + (lane & 15);
    out[idx] = f2bf(W[k * HD + c]);
}

// ---------------------------------------------------------------------------
// Fused prep: [0,nConv) conv_h | [nConv,nConv+608) weights | rest: dst hist
// ---------------------------------------------------------------------------
__global__ __launch_bounds__(256) void fused_prep(
    const float* __restrict__ h, unsigned short* __restrict__ h16,
    const float* __restrict__ Wc1, const float* __restrict__ bc1,
    const float* __restrict__ We1, const float* __restrict__ be1,
    const float* __restrict__ Wc2, const float* __restrict__ We2,
    const float* __restrict__ Wn1, const float* __restrict__ Wn2,
    unsigned short* __restrict__ ws,
    const int* __restrict__ dst, unsigned* __restrict__ cnt,
    int nConv, int nPrep, int E)
{
    const int bid = blockIdx.x, tid = threadIdx.x;
    if (bid < nConv) {
        const int i = bid * 256 + tid;
        const float4 v = ((const float4*)h)[i];
        union { unsigned short us[4]; uint2 u2; } p;
        p.us[0] = f2bf(v.x); p.us[1] = f2bf(v.y);
        p.us[2] = f2bf(v.z); p.us[3] = f2bf(v.w);
        ((uint2*)h16)[i] = p.u2;
        return;
    }
    if (bid < nConv + nPrep) {
        int idx = (bid - nConv) * 256 + tid;
        if (idx < W1SZ)            { frag_l1(idx, Wc1, bc1, ws);            return; }
        idx -= W1SZ;
        if (idx < W1SZ)            { frag_l1(idx, We1, be1, ws + O_WE1);    return; }
        idx -= W1SZ;
        if (idx < W2SZ)            { frag_sq(idx, Wc2, 4, ws + O_WC2);      return; }
        idx -= W2SZ;
        if (idx < W2SZ)            { frag_sq(idx, We2, 4, ws + O_WE2);      return; }
        idx -= W2SZ;
        if (idx < 128 * 256)       { frag_sq(idx, Wn1, 8, ws + O_WN1);      return; }
        idx -= 128 * 256;
        if (idx < W2SZ)            { frag_sq(idx, Wn2, 4, ws + O_WN2); }
        return;
    }
    const int i = (bid - nConv - nPrep) * 256 + tid;
    if (i < E) atomicAdd(&cnt[dst[i]], 1u);
}

// ---------------------------------------------------------------------------
__global__ __launch_bounds__(1024) void scan32k(const unsigned* __restrict__ cnt,
                                                unsigned* __restrict__ ofs)
{
    __shared__ unsigned wsum[16];
    __shared__ unsigned carry_s;
    const int tid = threadIdx.x, lane = tid & 63, w = tid >> 6;
    if (tid == 0) carry_s = 0;
    __syncthreads();
    for (int c = 0; c < 32; ++c) {
        const unsigned x = cnt[c * 1024 + tid];
        unsigned v = x;
        #pragma unroll
        for (int off = 1; off < 64; off <<= 1) {
            unsigned t = __shfl_up(v, off);
            if (lane >= off) v += t;
        }
        if (lane == 63) wsum[w] = v;
        __syncthreads();
        if (tid < 16) {
            unsigned s = wsum[tid];
            #pragma unroll
            for (int off = 1; off < 16; off <<= 1) {
                unsigned t = __shfl_up(s, off);
                if (tid >= off) s += t;
            }
            wsum[tid] = s;
        }
        __syncthreads();
        const unsigned carry = carry_s;
        const unsigned woff = (w == 0) ? 0u : wsum[w - 1];
        ofs[c * 1024 + tid] = carry + woff + v - x;
        __syncthreads();
        if (tid == 0) carry_s = carry + wsum[15];
        __syncthreads();
    }
}

__global__ __launch_bounds__(256) void scatter_perm(
    const int* __restrict__ src, const int* __restrict__ dst,
    const float* __restrict__ a, unsigned* __restrict__ ofs,
    int* __restrict__ srcp, int* __restrict__ dstp,
    unsigned short* __restrict__ a16p, int E)
{
    const int i = blockIdx.x * 256 + threadIdx.x;
    if (i >= E) return;
    const int d = dst[i];
    const unsigned pos = atomicAdd(&ofs[d], 1u);
    srcp[pos] = src[i];
    dstp[pos] = d;
    const float* ar = a + (size_t)i * EFD;
    union { unsigned short us[8]; short8 v; } p0, p1;
    #pragma unroll
    for (int t = 0; t < 8; ++t) { p0.us[t] = f2bf(ar[t]); p1.us[t] = f2bf(ar[8 + t]); }
    short8* dstv = (short8*)(a16p + (size_t)pos * EFD);
    dstv[0] = p0.v; dstv[1] = p1.v;
}

// ---------------------------------------------------------------------------
// Edge kernel — swapped operands: C[out x edge] = mfma(A=W frag, B=data frag)
// b64 LDS stores (conflict-free) + dword segsum.
// ---------------------------------------------------------------------------
__global__ __launch_bounds__(256, 4) void edge_kernel(
    const int* __restrict__ srcp, const int* __restrict__ dstp,
    const unsigned short* __restrict__ a16p,
    const float* __restrict__ coords, const unsigned short* __restrict__ h16,
    const float* __restrict__ bc2, const float* __restrict__ Wc3,
    const float* __restrict__ be2,
    const float* __restrict__ Watt, const float* __restrict__ batt,
    const unsigned short* __restrict__ wpan,
    float* __restrict__ out_h, float* __restrict__ out_x)
{
    __shared__ __align__(16) unsigned short csh_c[MT][LPC];
    __shared__ __align__(16) unsigned short csh_e[MT][LPC];
    __shared__ float diff_s[MT][3];
    __shared__ float rinv_s[MT];
    __shared__ float rad_s[MT];
    __shared__ float sc_part[4][MT];
    __shared__ float pa_part[4][MT];
    __shared__ float att_s[MT];
    __shared__ float sc_s[MT];
    __shared__ int   src_s[MT], dst_s[MT];
    __shared__ short run_start[MT + 1];
    __shared__ int   nruns_s;

    const int tid = threadIdx.x;
    const int e0  = blockIdx.x * MT;

    if (tid < MT) {
        const int s = srcp[e0 + tid], d = dstp[e0 + tid];
        src_s[tid] = s; dst_s[tid] = d;
        const float dx = coords[(size_t)s*3+0] - coords[(size_t)d*3+0];
        const float dy = coords[(size_t)s*3+1] - coords[(size_t)d*3+1];
        const float dz = coords[(size_t)s*3+2] - coords[(size_t)d*3+2];
        diff_s[tid][0] = dx; diff_s[tid][1] = dy; diff_s[tid][2] = dz;
        const float rad = dx*dx + dy*dy + dz*dz;
        rad_s[tid]  = rad;
        rinv_s[tid] = __builtin_amdgcn_rcpf(sqrtf(rad + 1e-5f) + 1.f);
    }
    __syncthreads();                                     // Ba

    if (tid < 64) {
        const bool st = (tid == 0) || (dst_s[tid] != dst_s[tid - 1]);
        unsigned long long m = __ballot(st);
        if (tid == 0) {
            int nr = 0;
            while (m) { run_start[nr++] = (short)__builtin_ctzll(m); m &= m - 1; }
            run_start[nr] = MT;
            nruns_s = nr;
        }
    }

    const int lane = tid & 63;
    const int w    = tid >> 6;        // out-col quarter
    const int w2   = w * 2;
    const int col  = lane & 15;       // edge within 16-tile
    const int kg   = lane >> 4;

    const unsigned short* Wc1p = wpan            + lane * 8;
    const unsigned short* We1p = wpan + O_WE1    + lane * 8;
    const unsigned short* Wc2p = wpan + O_WC2    + lane * 8;
    const unsigned short* We2p = wpan + O_WE2    + lane * 8;

    const unsigned short* hs[4];
    const unsigned short* hd[4];
    #pragma unroll
    for (int et = 0; et < 4; ++et) {
        const int r = et * 16 + col;
        hs[et] = h16 + (size_t)src_s[r] * HD;
        hd[et] = h16 + (size_t)dst_s[r] * HD;
    }

    const f32x4 zero = {0.f, 0.f, 0.f, 0.f};
    const short8 zf  = {0,0,0,0,0,0,0,0};
    f32x4 ac[2][4], ae[2][4];

    // ================= layer 1 (coord + edge fused; bias folded) ============
    #pragma unroll
    for (int m = 0; m < 2; ++m)
        #pragma unroll
        for (int et = 0; et < 4; ++et) { ac[m][et] = zero; ae[m][et] = zero; }

    #pragma unroll
    for (int kc = 0; kc < 9; ++kc) {
        short8 df[4];
        #pragma unroll
        for (int et = 0; et < 4; ++et) {
            if (kc < 4)       df[et] = *(const short8*)(hs[et] + kc * 32 + kg * 8);
            else if (kc < 8)  df[et] = *(const short8*)(hd[et] + (kc - 4) * 32 + kg * 8);
            else if (kg < 2)  df[et] = *(const short8*)(a16p + (size_t)(e0 + et*16 + col) * EFD + kg * 8);
            else if (kg == 2) {
                df[et] = zf;
                df[et][0] = (short)f2bf(rad_s[et*16 + col]);
                df[et][1] = (short)0x3F80;
            } else df[et] = zf;
        }
        #pragma unroll
        for (int m = 0; m < 2; ++m) {
            const short8 wc = *(const short8*)&Wc1p[((w2 + m) * 9 + kc) << 9];
            const short8 we = *(const short8*)&We1p[((w2 + m) * 9 + kc) << 9];
            #pragma unroll
            for (int et = 0; et < 4; ++et) {
                ac[m][et] = __builtin_amdgcn_mfma_f32_16x16x32_bf16(wc, df[et], ac[m][et], 0, 0, 0);
                ae[m][et] = __builtin_amdgcn_mfma_f32_16x16x32_bf16(we, df[et], ae[m][et], 0, 0, 0);
            }
        }
    }
    // epilogue: silu -> packed uint2 (b64 store, conflict-free: 4 dw/bank)
    #pragma unroll
    for (int m = 0; m < 2; ++m)
        #pragma unroll
        for (int et = 0; et < 4; ++et) {
            const int row = et * 16 + col;
            const int hw  = w * 32 + m * 16 + kg * 4;
            uint2 vc, ve;
            vc.x = pack2(silu_f(ac[m][et][0]), silu_f(ac[m][et][1]));
            vc.y = pack2(silu_f(ac[m][et][2]), silu_f(ac[m][et][3]));
            ve.x = pack2(silu_f(ae[m][et][0]), silu_f(ae[m][et][1]));
            ve.y = pack2(silu_f(ae[m][et][2]), silu_f(ae[m][et][3]));
            *(uint2*)&csh_c[row][hw] = vc;
            *(uint2*)&csh_e[row][hw] = ve;
        }
    __syncthreads();                                     // B1

    // ================= layer 2 (coord + edge fused) =================
    #pragma unroll
    for (int m = 0; m < 2; ++m)
        #pragma unroll
        for (int et = 0; et < 4; ++et) { ac[m][et] = zero; ae[m][et] = zero; }

    #pragma unroll
    for (int kc = 0; kc < 4; ++kc) {
        short8 dc[4], de[4];
        #pragma unroll
        for (int et = 0; et < 4; ++et) {
            const int row = et * 16 + col;
            dc[et] = *(const short8*)&csh_c[row][kc * 32 + kg * 8];
            de[et] = *(const short8*)&csh_e[row][kc * 32 + kg * 8];
        }
        #pragma unroll
        for (int m = 0; m < 2; ++m) {
            const short8 wc = *(const short8*)&Wc2p[((w2 + m) * 4 + kc) << 9];
            const short8 we = *(const short8*)&We2p[((w2 + m) * 4 + kc) << 9];
            #pragma unroll
            for (int et = 0; et < 4; ++et) {
                ac[m][et] = __builtin_amdgcn_mfma_f32_16x16x32_bf16(wc, dc[et], ac[m][et], 0, 0, 0);
                ae[m][et] = __builtin_amdgcn_mfma_f32_16x16x32_bf16(we, de[et], ae[m][et], 0, 0, 0);
            }
        }
    }

    {   // scale partial: lane-local + kg reduce
        float sc[4] = {0.f, 0.f, 0.f, 0.f};
        #pragma unroll
        for (int m = 0; m < 2; ++m)
            #pragma unroll
            for (int i = 0; i < 4; ++i) {
                const int hw = w * 32 + m * 16 + kg * 4 + i;
                const float b = bc2[hw], w3 = Wc3[hw];
                #pragma unroll
                for (int et = 0; et < 4; ++et)
                    sc[et] += silu_f(ac[m][et][i] + b) * w3;
            }
        #pragma unroll
        for (int et = 0; et < 4; ++et) {
            sc[et] += __shfl_xor(sc[et], 16);
            sc[et] += __shfl_xor(sc[et], 32);
        }
        if (kg == 0) {
            #pragma unroll
            for (int et = 0; et < 4; ++et)
                sc_part[w][et * 16 + col] = sc[et];
        }
    }
    __syncthreads();                                     // B2

    {   // msg epilogue: b64 store + att partial
        float pa[4] = {0.f, 0.f, 0.f, 0.f};
        #pragma unroll
        for (int m = 0; m < 2; ++m)
            #pragma unroll
            for (int et = 0; et < 4; ++et) {
                const int row = et * 16 + col;
                const int hw  = w * 32 + m * 16 + kg * 4;
                const float v0 = silu_f(ae[m][et][0] + be2[hw]);
                const float v1 = silu_f(ae[m][et][1] + be2[hw+1]);
                const float v2 = silu_f(ae[m][et][2] + be2[hw+2]);
                const float v3 = silu_f(ae[m][et][3] + be2[hw+3]);
                pa[et] += v0 * Watt[hw] + v1 * Watt[hw+1]
                        + v2 * Watt[hw+2] + v3 * Watt[hw+3];
                uint2 ve;
                ve.x = pack2(v0, v1);
                ve.y = pack2(v2, v3);
                *(uint2*)&csh_e[row][hw] = ve;
            }
        #pragma unroll
        for (int et = 0; et < 4; ++et) {
            pa[et] += __shfl_xor(pa[et], 16);
            pa[et] += __shfl_xor(pa[et], 32);
        }
        if (kg == 0) {
            #pragma unroll
            for (int et = 0; et < 4; ++et)
                pa_part[w][et * 16 + col] = pa[et];
        }
    }
    __syncthreads();                                     // B3

    if (tid < MT) {
        att_s[tid] = sigm_f(pa_part[0][tid] + pa_part[1][tid] +
                            pa_part[2][tid] + pa_part[3][tid] + batt[0]);
        sc_s[tid]  = (sc_part[0][tid] + sc_part[1][tid] +
                      sc_part[2][tid] + sc_part[3][tid]) * rinv_s[tid];
    }
    __syncthreads();                                     // B4

    // ---- segmented sum: dword reads (2 cols/thread), 4 run-groups ----
    {
        const int nr    = nruns_s;
        const int colx2 = tid & 63;          // dword col: ushort cols 2c,2c+1
        for (int r = tid >> 6; r < nr; r += 4) {
            const int s0 = run_start[r], s1 = run_start[r + 1];
            float sum0 = 0.f, sum1 = 0.f;
            for (int e = s0; e < s1; ++e) {
                const unsigned uv = *(const unsigned*)&csh_e[e][colx2 * 2];
                const float at = att_s[e];
                sum0 += bf2f((unsigned short)uv) * at;
                sum1 += bf2f((unsigned short)(uv >> 16)) * at;
            }
            const int drow = dst_s[s0];
            float* op = out_h + (size_t)drow * HD + colx2 * 2;
            atomicAdd(op,     sum0);
            atomicAdd(op + 1, sum1);
            if (colx2 < 2) {
                float sx0 = 0.f, sx1 = 0.f;
                for (int e = s0; e < s1; ++e) {
                    const float s = sc_s[e];
                    sx0 += s * diff_s[e][colx2 * 2];
                    if (colx2 == 0) sx1 += s * diff_s[e][1];
                }
                atomicAdd(&out_x[(size_t)drow * 3 + colx2 * 2], sx0);
                if (colx2 == 0) atomicAdd(&out_x[(size_t)drow * 3 + 1], sx1);
            }
        }
    }
}

// ---------------------------------------------------------------------------
// Node kernel (unchanged)
// ---------------------------------------------------------------------------
__global__ __launch_bounds__(256) void node_kernel(
    const float* __restrict__ h, const float* __restrict__ coords,
    const float* __restrict__ bn1, const float* __restrict__ bn2,
    const unsigned short* __restrict__ wpan,
    float* __restrict__ out_h, float* __restrict__ out_x)
{
    __shared__ __align__(16) unsigned short ash[MT][LPA];
    __shared__ __align__(16) unsigned short csh[MT][LPC];

    const int tid = threadIdx.x;
    const int n0  = blockIdx.x * MT;

    #pragma unroll
    for (int it = 0; it < 16; ++it) {
        const int idx = it * 256 + tid;
        const int e = idx >> 6, q = idx & 63;
        const float* base = (q < 32)
            ? h     + (size_t)(n0 + e) * HD + q * 4
            : out_h + (size_t)(n0 + e) * HD + (q - 32) * 4;
        const float4 v = *(const float4*)base;
        union { unsigned short us[4]; uint2 u2; } p;
        p.us[0] = f2bf(v.x); p.us[1] = f2bf(v.y);
        p.us[2] = f2bf(v.z); p.us[3] = f2bf(v.w);
        *(uint2*)&ash[e][q * 4] = p.u2;
    }
    __syncthreads();

    if (tid < MT * 3) {
        const int n = tid / 3, d = tid % 3;
        const size_t gi = (size_t)(n0 + n) * 3 + d;
        out_x[gi] += coords[gi];
    }

    const int lane = tid & 63;
    const int w    = tid >> 6;
    const int er0  = w * 16;
    const int col  = lane & 15;
    const int kg   = lane >> 4;

    const unsigned short* Wn1p = wpan + O_WN1 + lane * 8;
    const unsigned short* Wn2p = wpan + O_WN2 + lane * 8;

    const f32x4 zero = {0.f, 0.f, 0.f, 0.f};
    f32x4 acc[8];

    #pragma unroll
    for (int n = 0; n < 8; ++n) acc[n] = zero;
    #pragma unroll
    for (int kc = 0; kc < 8; ++kc) {
        const short8 af = *(const short8*)&ash[er0 + col][kc * 32 + kg * 8];
        #pragma unroll
        for (int n = 0; n < 8; ++n) {
            const short8 bf = *(const short8*)&Wn1p[(n * 8 + kc) << 9];
            acc[n] = __builtin_amdgcn_mfma_f32_16x16x32_bf16(af, bf, acc[n], 0, 0, 0);
        }
    }
    #pragma unroll
    for (int n = 0; n < 8; ++n) {
        const float b = bn1[n*16 + col];
        #pragma unroll
        for (int i = 0; i < 4; ++i)
            csh[er0 + kg*4 + i][n*16 + col] = f2bf(silu_f(acc[n][i] + b));
    }
    __syncthreads();
    #pragma unroll
    for (int n = 0; n < 8; ++n) acc[n] = zero;
    #pragma unroll
    for (int kc = 0; kc < 4; ++kc) {
        const short8 af = *(const short8*)&csh[er0 + col][kc * 32 + kg * 8];
        #pragma unroll
        for (int n = 0; n < 8; ++n) {
            const short8 bf = *(const short8*)&Wn2p[(n * 4 + kc) << 9];
            acc[n] = __builtin_amdgcn_mfma_f32_16x16x32_bf16(af, bf, acc[n], 0, 0, 0);
        }
    }
    #pragma unroll
    for (int i = 0; i < 4; ++i) {
        const int node = n0 + er0 + kg*4 + i;
        const float* hr   = h     + (size_t)node * HD;
        float*       orow = out_h + (size_t)node * HD;
        #pragma unroll
        for (int n = 0; n < 8; ++n) {
            const int f = n*16 + col;
            orow[f] = hr[f] + acc[n][i] + bn2[f];
        }
    }
}

extern "C" void kernel_launch(void* const* d_in, const int* in_sizes, int n_in,
                              void* d_out, int out_size, void* d_ws, size_t ws_size,
                              hipStream_t stream)
{
    const int*   src    = (const int*)  d_in[0];
    const int*   dst    = (const int*)  d_in[1];
    const float* h      = (const float*)d_in[2];
    const float* coords = (const float*)d_in[3];
    const float* a      = (const float*)d_in[4];
    const float* Wc1    = (const float*)d_in[5];
    const float* bc1    = (const float*)d_in[6];
    const float* Wc2    = (const float*)d_in[7];
    const float* bc2    = (const float*)d_in[8];
    const float* Wc3    = (const float*)d_in[9];
    const float* We1    = (const float*)d_in[10];
    const float* be1    = (const float*)d_in[11];
    const float* We2    = (const float*)d_in[12];
    const float* be2    = (const float*)d_in[13];
    const float* Watt   = (const float*)d_in[14];
    const float* batt   = (const float*)d_in[15];
    const float* Wn1    = (const float*)d_in[16];
    const float* bn1    = (const float*)d_in[17];
    const float* Wn2    = (const float*)d_in[18];
    const float* bn2    = (const float*)d_in[19];

    const int E = in_sizes[0];
    const int N = in_sizes[2] / HD;

    float* out_h = (float*)d_out;
    float* out_x = out_h + (size_t)N * HD;

    char* wsb = (char*)d_ws;
    unsigned short* h16  = (unsigned short*)(wsb + B_H16);
    unsigned short* wpan = (unsigned short*)(wsb + B_WPAN);
    unsigned*       cnt  = (unsigned*)      (wsb + B_CNT);
    unsigned*       ofs  = (unsigned*)      (wsb + B_OFS);
    int*            srcp = (int*)           (wsb + B_SRCP);
    int*            dstp = (int*)           (wsb + B_DSTP);
    unsigned short* a16p = (unsigned short*)(wsb + B_A16);

    hipMemsetAsync(d_out, 0, (size_t)out_size * sizeof(float), stream);
    hipMemsetAsync(cnt, 0, (size_t)N * sizeof(unsigned), stream);

    const int nConv = (N * HD / 4) / 256;          // 4096
    const int nPrep = WS_ELEMS / 256;              // 608
    const int nHist = (E + 255) / 256;             // 2048

    fused_prep<<<dim3(nConv + nPrep + nHist), dim3(256), 0, stream>>>(
        h, h16, Wc1, bc1, We1, be1, Wc2, We2, Wn1, Wn2, wpan,
        dst, cnt, nConv, nPrep, E);

    scan32k<<<dim3(1), dim3(1024), 0, stream>>>(cnt, ofs);
    scatter_perm<<<dim3((E + 255) / 256), dim3(256), 0, stream>>>(
        src, dst, a, ofs, srcp, dstp, a16p, E);

    edge_kernel<<<dim3(E / MT), dim3(256), 0, stream>>>(
        srcp, dstp, a16p, coords, h16,
        bc2, Wc3, be2, Watt, batt,
        wpan, out_h, out_x);

    node_kernel<<<dim3(N / MT), dim3(256), 0, stream>>>(
        h, coords, bn1, bn2, wpan, out_h, out_x);
}

// Round 10
// 318.330 us; speedup vs baseline: 2.3795x; 1.0186x over previous
//
#include <hip/hip_runtime.h>
#include <math.h>

#define HD   128
#define EFD  16
#define MT   64      // edges / nodes per block
#define LPA  264
#define LPC  136     // LDS pitch (ushort): rows, cols=128+pad

#define W1SZ (128 * 288)
#define W2SZ (128 * 128)
#define O_WE1 (W1SZ)
#define O_WC2 (2 * W1SZ)
#define O_WE2 (2 * W1SZ + W2SZ)
#define O_WN1 (2 * W1SZ + 2 * W2SZ)
#define O_WN2 (2 * W1SZ + 2 * W2SZ + 128 * 256)
#define WS_ELEMS (O_WN2 + W2SZ)          // 155648

// ws byte layout (~38.5 MB)
#define B_PSC   ((size_t)0)              // N*128 bf16 = 8 MB
#define B_PDC   ((size_t)8388608)
#define B_PSE   ((size_t)16777216)
#define B_PDE   ((size_t)25165824)
#define B_WPAN  ((size_t)33554432)       // 311296
#define B_CNT   ((size_t)33865728)       // 131072
#define B_OFS   ((size_t)33996800)       // 131072
#define B_SRCP  ((size_t)34127872)       // 2 MB
#define B_DSTP  ((size_t)36225024)       // 2 MB
#define B_EIDX  ((size_t)38322176)       // 2 MB

typedef __attribute__((ext_vector_type(8))) short short8;
typedef __attribute__((ext_vector_type(4))) float f32x4;

__device__ __forceinline__ unsigned short f2bf(float x) {
    __bf16 b = (__bf16)x;
    unsigned short u;
    __builtin_memcpy(&u, &b, 2);
    return u;
}
__device__ __forceinline__ float bf2f(unsigned short u) {
    union { unsigned u; float f; } v; v.u = ((unsigned)u) << 16;
    return v.f;
}
__device__ __forceinline__ float bfl(unsigned u) {   // low bf16 of dword
    union { unsigned u; float f; } v; v.u = u << 16; return v.f;
}
__device__ __forceinline__ float bfh(unsigned u) {   // high bf16 of dword
    union { unsigned u; float f; } v; v.u = u & 0xffff0000u; return v.f;
}
__device__ __forceinline__ float sigm_f(float x) {
    return __builtin_amdgcn_rcpf(1.f + __expf(-x));
}
__device__ __forceinline__ float silu_f(float x) { return x * sigm_f(x); }
__device__ __forceinline__ unsigned pack2(float a, float b) {
    return (unsigned)f2bf(a) | ((unsigned)f2bf(b) << 16);
}

// ---------------------------------------------------------------------------
// Fragment-ordered bf16 weight panels (A-operand layout).
// l1 K remap: k<256 -> k ; 256..271 -> a rows (orig 257..272);
// 272 -> radial (orig 256); 273 -> BIAS (data supplies 1.0); else 0
// ---------------------------------------------------------------------------
__device__ __forceinline__ void frag_l1(int idx, const float* __restrict__ W,
                                        const float* __restrict__ bias,
                                        unsigned short* __restrict__ out)
{
    const int j = idx & 7, lane = (idx >> 3) & 63, blk = idx >> 9;
    const int kc = blk % 9, n = blk / 9;
    const int k = kc * 32 + (lane >> 4) * 8 + j;
    const int c = n * 16 + (lane & 15);
    float v = 0.f;
    if (k < 256) v = W[k * HD + c];
    else if (k < 272) v = W[(k + 1) * HD + c];
    else if (k == 272) v = W[256 * HD + c];
    else if (k == 273) v = bias[c];
    out[idx] = f2bf(v);
}
__device__ __forceinline__ void frag_sq(int idx, const float* __restrict__ W,
                                        int nkc, unsigned short* __restrict__ out)
{
    const int j = idx & 7, lane = (idx >> 3) & 63, blk = idx >> 9;
    const int kc = blk % nkc, n = blk / nkc;
    const int k = kc * 32 + (lane >> 4) * 8 + j;
    const int c = n * 16 + (lane & 15);
    out[idx] = f2bf(W[k * HD + c]);
}

// ---------------------------------------------------------------------------
// Fused prep: [0,nPrep) weight panels | [nPrep, nPrep+nHist) dst histogram
// ---------------------------------------------------------------------------
__global__ __launch_bounds__(256) void fused_prep(
    const float* __restrict__ Wc1, const float* __restrict__ bc1,
    const float* __restrict__ We1, const float* __restrict__ be1,
    const float* __restrict__ Wc2, const float* __restrict__ We2,
    const float* __restrict__ Wn1, const float* __restrict__ Wn2,
    unsigned short* __restrict__ ws,
    const int* __restrict__ dst, unsigned* __restrict__ cnt,
    int nPrep, int E)
{
    const int bid = blockIdx.x, tid = threadIdx.x;
    if (bid < nPrep) {
        int idx = bid * 256 + tid;
        if (idx < W1SZ)            { frag_l1(idx, Wc1, bc1, ws);            return; }
        idx -= W1SZ;
        if (idx < W1SZ)            { frag_l1(idx, We1, be1, ws + O_WE1);    return; }
        idx -= W1SZ;
        if (idx < W2SZ)            { frag_sq(idx, Wc2, 4, ws + O_WC2);      return; }
        idx -= W2SZ;
        if (idx < W2SZ)            { frag_sq(idx, We2, 4, ws + O_WE2);      return; }
        idx -= W2SZ;
        if (idx < 128 * 256)       { frag_sq(idx, Wn1, 8, ws + O_WN1);      return; }
        idx -= 128 * 256;
        if (idx < W2SZ)            { frag_sq(idx, Wn2, 4, ws + O_WN2); }
        return;
    }
    const int i = (bid - nPrep) * 256 + tid;
    if (i < E) atomicAdd(&cnt[dst[i]], 1u);
}

// ---------------------------------------------------------------------------
// node_pre: P tables = h @ W1-halves (per-node precompute of edge layer 1)
//   Ps_c = h @ Wc1[0:128], Pd_c = h @ Wc1[128:256]; same for We1.
// Reuses l1 panels: kc 0..3 = src half, kc 4..7 = dst half.
// ---------------------------------------------------------------------------
__device__ __forceinline__ void pre_pass(
    const unsigned short* __restrict__ panelp,   // panel + lane*8
    const unsigned short* __restrict__ hsh,      // LDS [64][136]
    unsigned short* __restrict__ Ps, unsigned short* __restrict__ Pd,
    int n0, int w2, int w, int col, int kg)
{
    const f32x4 zero = {0.f, 0.f, 0.f, 0.f};
    f32x4 as_[2][4], ad_[2][4];
    #pragma unroll
    for (int m = 0; m < 2; ++m)
        #pragma unroll
        for (int et = 0; et < 4; ++et) { as_[m][et] = zero; ad_[m][et] = zero; }
    #pragma unroll
    for (int kc = 0; kc < 4; ++kc) {
        short8 bf[4];
        #pragma unroll
        for (int et = 0; et < 4; ++et)
            bf[et] = *(const short8*)&hsh[(et*16 + col) * LPC + kc * 32 + kg * 8];
        #pragma unroll
        for (int m = 0; m < 2; ++m) {
            const short8 As = *(const short8*)&panelp[((w2 + m) * 9 + kc) << 9];
            const short8 Ad = *(const short8*)&panelp[((w2 + m) * 9 + kc + 4) << 9];
            #pragma unroll
            for (int et = 0; et < 4; ++et) {
                as_[m][et] = __builtin_amdgcn_mfma_f32_16x16x32_bf16(As, bf[et], as_[m][et], 0, 0, 0);
                ad_[m][et] = __builtin_amdgcn_mfma_f32_16x16x32_bf16(Ad, bf[et], ad_[m][et], 0, 0, 0);
            }
        }
    }
    #pragma unroll
    for (int m = 0; m < 2; ++m)
        #pragma unroll
        for (int et = 0; et < 4; ++et) {
            const size_t row = (size_t)(n0 + et * 16 + col) * HD;
            const int hw = w * 32 + m * 16 + kg * 4;
            uint2 vs, vd;
            vs.x = pack2(as_[m][et][0], as_[m][et][1]);
            vs.y = pack2(as_[m][et][2], as_[m][et][3]);
            vd.x = pack2(ad_[m][et][0], ad_[m][et][1]);
            vd.y = pack2(ad_[m][et][2], ad_[m][et][3]);
            *(uint2*)(Ps + row + hw) = vs;
            *(uint2*)(Pd + row + hw) = vd;
        }
}

__global__ __launch_bounds__(256) void node_pre(
    const float* __restrict__ h, const unsigned short* __restrict__ wpan,
    unsigned short* __restrict__ Psc, unsigned short* __restrict__ Pdc,
    unsigned short* __restrict__ Pse, unsigned short* __restrict__ Pde)
{
    __shared__ __align__(16) unsigned short hsh[MT][LPC];
    const int tid = threadIdx.x;
    const int n0  = blockIdx.x * MT;

    #pragma unroll
    for (int it = 0; it < 8; ++it) {
        const int idx = it * 256 + tid;          // 2048 float4 slots
        const int r = idx >> 5, q = idx & 31;
        const float4 v = *(const float4*)(h + (size_t)(n0 + r) * HD + q * 4);
        uint2 p; p.x = pack2(v.x, v.y); p.y = pack2(v.z, v.w);
        *(uint2*)&hsh[r][q * 4] = p;
    }
    __syncthreads();

    const int lane = tid & 63;
    const int w    = tid >> 6;
    const int w2   = w * 2;
    const int col  = lane & 15;
    const int kg   = lane >> 4;

    pre_pass(wpan + lane * 8,         &hsh[0][0], Psc, Pdc, n0, w2, w, col, kg);
    pre_pass(wpan + O_WE1 + lane * 8, &hsh[0][0], Pse, Pde, n0, w2, w, col, kg);
}

// ---------------------------------------------------------------------------
__global__ __launch_bounds__(1024) void scan32k(const unsigned* __restrict__ cnt,
                                                unsigned* __restrict__ ofs)
{
    __shared__ unsigned wsum[16];
    __shared__ unsigned carry_s;
    const int tid = threadIdx.x, lane = tid & 63, w = tid >> 6;
    if (tid == 0) carry_s = 0;
    __syncthreads();
    for (int c = 0; c < 32; ++c) {
        const unsigned x = cnt[c * 1024 + tid];
        unsigned v = x;
        #pragma unroll
        for (int off = 1; off < 64; off <<= 1) {
            unsigned t = __shfl_up(v, off);
            if (lane >= off) v += t;
        }
        if (lane == 63) wsum[w] = v;
        __syncthreads();
        if (tid < 16) {
            unsigned s = wsum[tid];
            #pragma unroll
            for (int off = 1; off < 16; off <<= 1) {
                unsigned t = __shfl_up(s, off);
                if (tid >= off) s += t;
            }
            wsum[tid] = s;
        }
        __syncthreads();
        const unsigned carry = carry_s;
        const unsigned woff = (w == 0) ? 0u : wsum[w - 1];
        ofs[c * 1024 + tid] = carry + woff + v - x;
        __syncthreads();
        if (tid == 0) carry_s = carry + wsum[15];
        __syncthreads();
    }
}

__global__ __launch_bounds__(256) void scatter_perm(
    const int* __restrict__ src, const int* __restrict__ dst,
    unsigned* __restrict__ ofs,
    int* __restrict__ srcp, int* __restrict__ dstp,
    int* __restrict__ eidx, int E)
{
    const int i = blockIdx.x * 256 + threadIdx.x;
    if (i >= E) return;
    const int d = dst[i];
    const unsigned pos = atomicAdd(&ofs[d], 1u);
    srcp[pos] = src[i];
    dstp[pos] = d;
    eidx[pos] = i;
}

// ---------------------------------------------------------------------------
// Edge kernel: layer-1 = P-gather acc-init + single (a,rad,bias) MFMA chunk.
// C[out x edge] = mfma(A=W frag, B=data frag). Layer-2 unchanged.
// ---------------------------------------------------------------------------
__global__ __launch_bounds__(256, 4) void edge_kernel(
    const int* __restrict__ srcp, const int* __restrict__ dstp,
    const int* __restrict__ eidx, const float* __restrict__ a,
    const float* __restrict__ coords,
    const unsigned short* __restrict__ Psc, const unsigned short* __restrict__ Pdc,
    const unsigned short* __restrict__ Pse, const unsigned short* __restrict__ Pde,
    const float* __restrict__ bc2, const float* __restrict__ Wc3,
    const float* __restrict__ be2,
    const float* __restrict__ Watt, const float* __restrict__ batt,
    const unsigned short* __restrict__ wpan,
    float* __restrict__ out_h, float* __restrict__ out_x)
{
    __shared__ __align__(16) unsigned short csh_c[MT][LPC];
    __shared__ __align__(16) unsigned short csh_e[MT][LPC];
    __shared__ float diff_s[MT][3];
    __shared__ float rad_s[MT];
    __shared__ float rinv_s[MT];
    __shared__ float sc_part[4][MT];
    __shared__ float pa_part[4][MT];
    __shared__ float att_s[MT];
    __shared__ float sc_s[MT];
    __shared__ int   src_s[MT], dst_s[MT], eid_s[MT];
    __shared__ short run_start[MT + 1];
    __shared__ int   nruns_s;

    const int tid = threadIdx.x;
    const int e0  = blockIdx.x * MT;

    if (tid < MT) {
        const int s = srcp[e0 + tid], d = dstp[e0 + tid];
        src_s[tid] = s; dst_s[tid] = d;
        eid_s[tid] = eidx[e0 + tid];
        const float dx = coords[(size_t)s*3+0] - coords[(size_t)d*3+0];
        const float dy = coords[(size_t)s*3+1] - coords[(size_t)d*3+1];
        const float dz = coords[(size_t)s*3+2] - coords[(size_t)d*3+2];
        diff_s[tid][0] = dx; diff_s[tid][1] = dy; diff_s[tid][2] = dz;
        const float rad = dx*dx + dy*dy + dz*dz;
        rad_s[tid]  = rad;
        rinv_s[tid] = __builtin_amdgcn_rcpf(sqrtf(rad + 1e-5f) + 1.f);
    }
    __syncthreads();                                     // Ba

    if (tid < 64) {
        const bool st = (tid == 0) || (dst_s[tid] != dst_s[tid - 1]);
        unsigned long long m = __ballot(st);
        if (tid == 0) {
            int nr = 0;
            while (m) { run_start[nr++] = (short)__builtin_ctzll(m); m &= m - 1; }
            run_start[nr] = MT;
            nruns_s = nr;
        }
    }

    const int lane = tid & 63;
    const int w    = tid >> 6;        // out-col quarter
    const int w2   = w * 2;
    const int col  = lane & 15;       // edge within 16-tile
    const int kg   = lane >> 4;

    const unsigned short* Wc1p = wpan            + lane * 8;
    const unsigned short* We1p = wpan + O_WE1    + lane * 8;
    const unsigned short* Wc2p = wpan + O_WC2    + lane * 8;
    const unsigned short* We2p = wpan + O_WE2    + lane * 8;

    // P-gather byte offsets (per et): row*256 + (w*64 + kg*8); +m*32 via imm
    unsigned po_s[4], po_d[4];
    #pragma unroll
    for (int et = 0; et < 4; ++et) {
        const int r = et * 16 + col;
        const unsigned wk = (unsigned)(w * 64 + kg * 8);
        po_s[et] = (unsigned)src_s[r] * 256u + wk;
        po_d[et] = (unsigned)dst_s[r] * 256u + wk;
    }

    const short8 zf = {0,0,0,0,0,0,0,0};
    f32x4 ac[2][4], ae[2][4];

    // ============ layer 1: acc-init from P, then (a,rad,bias) MFMA ==========
    #pragma unroll
    for (int m = 0; m < 2; ++m)
        #pragma unroll
        for (int et = 0; et < 4; ++et) {
            const uint2 sc_ = *(const uint2*)((const char*)Psc + po_s[et] + m * 32);
            const uint2 dc_ = *(const uint2*)((const char*)Pdc + po_d[et] + m * 32);
            const uint2 se_ = *(const uint2*)((const char*)Pse + po_s[et] + m * 32);
            const uint2 de_ = *(const uint2*)((const char*)Pde + po_d[et] + m * 32);
            ac[m][et][0] = bfl(sc_.x) + bfl(dc_.x);
            ac[m][et][1] = bfh(sc_.x) + bfh(dc_.x);
            ac[m][et][2] = bfl(sc_.y) + bfl(dc_.y);
            ac[m][et][3] = bfh(sc_.y) + bfh(dc_.y);
            ae[m][et][0] = bfl(se_.x) + bfl(de_.x);
            ae[m][et][1] = bfh(se_.x) + bfh(de_.x);
            ae[m][et][2] = bfl(se_.y) + bfl(de_.y);
            ae[m][et][3] = bfh(se_.y) + bfh(de_.y);
        }
    {   // kc=8 chunk: a(16) | rad | 1.0(bias) | pad
        short8 df[4];
        #pragma unroll
        for (int et = 0; et < 4; ++et) {
            if (kg < 2) {
                const int oe = eid_s[et * 16 + col];
                const float4 a0 = *(const float4*)(a + (size_t)oe * EFD + kg * 8);
                const float4 a1 = *(const float4*)(a + (size_t)oe * EFD + kg * 8 + 4);
                short8 v;
                v[0] = (short)f2bf(a0.x); v[1] = (short)f2bf(a0.y);
                v[2] = (short)f2bf(a0.z); v[3] = (short)f2bf(a0.w);
                v[4] = (short)f2bf(a1.x); v[5] = (short)f2bf(a1.y);
                v[6] = (short)f2bf(a1.z); v[7] = (short)f2bf(a1.w);
                df[et] = v;
            } else if (kg == 2) {
                short8 v = zf;
                v[0] = (short)f2bf(rad_s[et * 16 + col]);
                v[1] = (short)0x3F80;
                df[et] = v;
            } else df[et] = zf;
        }
        #pragma unroll
        for (int m = 0; m < 2; ++m) {
            const short8 wc = *(const short8*)&Wc1p[((w2 + m) * 9 + 8) << 9];
            const short8 we = *(const short8*)&We1p[((w2 + m) * 9 + 8) << 9];
            #pragma unroll
            for (int et = 0; et < 4; ++et) {
                ac[m][et] = __builtin_amdgcn_mfma_f32_16x16x32_bf16(wc, df[et], ac[m][et], 0, 0, 0);
                ae[m][et] = __builtin_amdgcn_mfma_f32_16x16x32_bf16(we, df[et], ae[m][et], 0, 0, 0);
            }
        }
    }
    // epilogue: silu -> packed b64 stores
    #pragma unroll
    for (int m = 0; m < 2; ++m)
        #pragma unroll
        for (int et = 0; et < 4; ++et) {
            const int row = et * 16 + col;
            const int hw  = w * 32 + m * 16 + kg * 4;
            uint2 vc, ve;
            vc.x = pack2(silu_f(ac[m][et][0]), silu_f(ac[m][et][1]));
            vc.y = pack2(silu_f(ac[m][et][2]), silu_f(ac[m][et][3]));
            ve.x = pack2(silu_f(ae[m][et][0]), silu_f(ae[m][et][1]));
            ve.y = pack2(silu_f(ae[m][et][2]), silu_f(ae[m][et][3]));
            *(uint2*)&csh_c[row][hw] = vc;
            *(uint2*)&csh_e[row][hw] = ve;
        }
    __syncthreads();                                     // B1

    // ================= layer 2 (coord + edge fused) =================
    const f32x4 zero = {0.f, 0.f, 0.f, 0.f};
    #pragma unroll
    for (int m = 0; m < 2; ++m)
        #pragma unroll
        for (int et = 0; et < 4; ++et) { ac[m][et] = zero; ae[m][et] = zero; }

    #pragma unroll
    for (int kc = 0; kc < 4; ++kc) {
        short8 dc[4], de[4];
        #pragma unroll
        for (int et = 0; et < 4; ++et) {
            const int row = et * 16 + col;
            dc[et] = *(const short8*)&csh_c[row][kc * 32 + kg * 8];
            de[et] = *(const short8*)&csh_e[row][kc * 32 + kg * 8];
        }
        #pragma unroll
        for (int m = 0; m < 2; ++m) {
            const short8 wc = *(const short8*)&Wc2p[((w2 + m) * 4 + kc) << 9];
            const short8 we = *(const short8*)&We2p[((w2 + m) * 4 + kc) << 9];
            #pragma unroll
            for (int et = 0; et < 4; ++et) {
                ac[m][et] = __builtin_amdgcn_mfma_f32_16x16x32_bf16(wc, dc[et], ac[m][et], 0, 0, 0);
                ae[m][et] = __builtin_amdgcn_mfma_f32_16x16x32_bf16(we, de[et], ae[m][et], 0, 0, 0);
            }
        }
    }

    {   // scale partial: lane-local + kg reduce
        float sc[4] = {0.f, 0.f, 0.f, 0.f};
        #pragma unroll
        for (int m = 0; m < 2; ++m)
            #pragma unroll
            for (int i = 0; i < 4; ++i) {
                const int hw = w * 32 + m * 16 + kg * 4 + i;
                const float b = bc2[hw], w3 = Wc3[hw];
                #pragma unroll
                for (int et = 0; et < 4; ++et)
                    sc[et] += silu_f(ac[m][et][i] + b) * w3;
            }
        #pragma unroll
        for (int et = 0; et < 4; ++et) {
            sc[et] += __shfl_xor(sc[et], 16);
            sc[et] += __shfl_xor(sc[et], 32);
        }
        if (kg == 0) {
            #pragma unroll
            for (int et = 0; et < 4; ++et)
                sc_part[w][et * 16 + col] = sc[et];
        }
    }
    __syncthreads();                                     // B2

    {   // msg epilogue: b64 store + att partial
        float pa[4] = {0.f, 0.f, 0.f, 0.f};
        #pragma unroll
        for (int m = 0; m < 2; ++m)
            #pragma unroll
            for (int et = 0; et < 4; ++et) {
                const int row = et * 16 + col;
                const int hw  = w * 32 + m * 16 + kg * 4;
                const float v0 = silu_f(ae[m][et][0] + be2[hw]);
                const float v1 = silu_f(ae[m][et][1] + be2[hw+1]);
                const float v2 = silu_f(ae[m][et][2] + be2[hw+2]);
                const float v3 = silu_f(ae[m][et][3] + be2[hw+3]);
                pa[et] += v0 * Watt[hw] + v1 * Watt[hw+1]
                        + v2 * Watt[hw+2] + v3 * Watt[hw+3];
                uint2 ve;
                ve.x = pack2(v0, v1);
                ve.y = pack2(v2, v3);
                *(uint2*)&csh_e[row][hw] = ve;
            }
        #pragma unroll
        for (int et = 0; et < 4; ++et) {
            pa[et] += __shfl_xor(pa[et], 16);
            pa[et] += __shfl_xor(pa[et], 32);
        }
        if (kg == 0) {
            #pragma unroll
            for (int et = 0; et < 4; ++et)
                pa_part[w][et * 16 + col] = pa[et];
        }
    }
    __syncthreads();                                     // B3

    if (tid < MT) {
        att_s[tid] = sigm_f(pa_part[0][tid] + pa_part[1][tid] +
                            pa_part[2][tid] + pa_part[3][tid] + batt[0]);
        sc_s[tid]  = (sc_part[0][tid] + sc_part[1][tid] +
                      sc_part[2][tid] + sc_part[3][tid]) * rinv_s[tid];
    }
    __syncthreads();                                     // B4

    // ---- segmented sum: dword reads (2 cols/thread), 4 run-groups ----
    {
        const int nr    = nruns_s;
        const int colx2 = tid & 63;
        for (int r = tid >> 6; r < nr; r += 4) {
            const int s0 = run_start[r], s1 = run_start[r + 1];
            float sum0 = 0.f, sum1 = 0.f;
            for (int e = s0; e < s1; ++e) {
                const unsigned uv = *(const unsigned*)&csh_e[e][colx2 * 2];
                const float at = att_s[e];
                sum0 += bfl(uv) * at;
                sum1 += bfh(uv) * at;
            }
            const int drow = dst_s[s0];
            float* op = out_h + (size_t)drow * HD + colx2 * 2;
            atomicAdd(op,     sum0);
            atomicAdd(op + 1, sum1);
            if (colx2 < 2) {
                float sx0 = 0.f, sx1 = 0.f;
                for (int e = s0; e < s1; ++e) {
                    const float s = sc_s[e];
                    sx0 += s * diff_s[e][colx2 * 2];
                    if (colx2 == 0) sx1 += s * diff_s[e][1];
                }
                atomicAdd(&out_x[(size_t)drow * 3 + colx2 * 2], sx0);
                if (colx2 == 0) atomicAdd(&out_x[(size_t)drow * 3 + 1], sx1);
            }
        }
    }
}

// ---------------------------------------------------------------------------
// Node kernel (unchanged)
// ---------------------------------------------------------------------------
__global__ __launch_bounds__(256) void node_kernel(
    const float* __restrict__ h, const float* __restrict__ coords,
    const float* __restrict__ bn1, const float* __restrict__ bn2,
    const unsigned short* __restrict__ wpan,
    float* __restrict__ out_h, float* __restrict__ out_x)
{
    __shared__ __align__(16) unsigned short ash[MT][LPA];
    __shared__ __align__(16) unsigned short csh[MT][LPC];

    const int tid = threadIdx.x;
    const int n0  = blockIdx.x * MT;

    #pragma unroll
    for (int it = 0; it < 16; ++it) {
        const int idx = it * 256 + tid;
        const int e = idx >> 6, q = idx & 63;
        const float* base = (q < 32)
            ? h     + (size_t)(n0 + e) * HD + q * 4
            : out_h + (size_t)(n0 + e) * HD + (q - 32) * 4;
        const float4 v = *(const float4*)base;
        union { unsigned short us[4]; uint2 u2; } p;
        p.us[0] = f2bf(v.x); p.us[1] = f2bf(v.y);
        p.us[2] = f2bf(v.z); p.us[3] = f2bf(v.w);
        *(uint2*)&ash[e][q * 4] = p.u2;
    }
    __syncthreads();

    if (tid < MT * 3) {
        const int n = tid / 3, d = tid % 3;
        const size_t gi = (size_t)(n0 + n) * 3 + d;
        out_x[gi] += coords[gi];
    }

    const int lane = tid & 63;
    const int w    = tid >> 6;
    const int er0  = w * 16;
    const int col  = lane & 15;
    const int kg   = lane >> 4;

    const unsigned short* Wn1p = wpan + O_WN1 + lane * 8;
    const unsigned short* Wn2p = wpan + O_WN2 + lane * 8;

    const f32x4 zero = {0.f, 0.f, 0.f, 0.f};
    f32x4 acc[8];

    #pragma unroll
    for (int n = 0; n < 8; ++n) acc[n] = zero;
    #pragma unroll
    for (int kc = 0; kc < 8; ++kc) {
        const short8 af = *(const short8*)&ash[er0 + col][kc * 32 + kg * 8];
        #pragma unroll
        for (int n = 0; n < 8; ++n) {
            const short8 bf = *(const short8*)&Wn1p[(n * 8 + kc) << 9];
            acc[n] = __builtin_amdgcn_mfma_f32_16x16x32_bf16(af, bf, acc[n], 0, 0, 0);
        }
    }
    #pragma unroll
    for (int n = 0; n < 8; ++n) {
        const float b = bn1[n*16 + col];
        #pragma unroll
        for (int i = 0; i < 4; ++i)
            csh[er0 + kg*4 + i][n*16 + col] = f2bf(silu_f(acc[n][i] + b));
    }
    __syncthreads();
    #pragma unroll
    for (int n = 0; n < 8; ++n) acc[n] = zero;
    #pragma unroll
    for (int kc = 0; kc < 4; ++kc) {
        const short8 af = *(const short8*)&csh[er0 + col][kc * 32 + kg * 8];
        #pragma unroll
        for (int n = 0; n < 8; ++n) {
            const short8 bf = *(const short8*)&Wn2p[(n * 4 + kc) << 9];
            acc[n] = __builtin_amdgcn_mfma_f32_16x16x32_bf16(af, bf, acc[n], 0, 0, 0);
        }
    }
    #pragma unroll
    for (int i = 0; i < 4; ++i) {
        const int node = n0 + er0 + kg*4 + i;
        const float* hr   = h     + (size_t)node * HD;
        float*       orow = out_h + (size_t)node * HD;
        #pragma unroll
        for (int n = 0; n < 8; ++n) {
            const int f = n*16 + col;
            orow[f] = hr[f] + acc[n][i] + bn2[f];
        }
    }
}

extern "C" void kernel_launch(void* const* d_in, const int* in_sizes, int n_in,
                              void* d_out, int out_size, void* d_ws, size_t ws_size,
                              hipStream_t stream)
{
    const int*   src    = (const int*)  d_in[0];
    const int*   dst    = (const int*)  d_in[1];
    const float* h      = (const float*)d_in[2];
    const float* coords = (const float*)d_in[3];
    const float* a      = (const float*)d_in[4];
    const float* Wc1    = (const float*)d_in[5];
    const float* bc1    = (const float*)d_in[6];
    const float* Wc2    = (const float*)d_in[7];
    const float* bc2    = (const float*)d_in[8];
    const float* Wc3    = (const float*)d_in[9];
    const float* We1    = (const float*)d_in[10];
    const float* be1    = (const float*)d_in[11];
    const float* We2    = (const float*)d_in[12];
    const float* be2    = (const float*)d_in[13];
    const float* Watt   = (const float*)d_in[14];
    const float* batt   = (const float*)d_in[15];
    const float* Wn1    = (const float*)d_in[16];
    const float* bn1    = (const float*)d_in[17];
    const float* Wn2    = (const float*)d_in[18];
    const float* bn2    = (const float*)d_in[19];

    const int E = in_sizes[0];
    const int N = in_sizes[2] / HD;

    float* out_h = (float*)d_out;
    float* out_x = out_h + (size_t)N * HD;

    char* wsb = (char*)d_ws;
    unsigned short* Psc  = (unsigned short*)(wsb + B_PSC);
    unsigned short* Pdc  = (unsigned short*)(wsb + B_PDC);
    unsigned short* Pse  = (unsigned short*)(wsb + B_PSE);
    unsigned short* Pde  = (unsigned short*)(wsb + B_PDE);
    unsigned short* wpan = (unsigned short*)(wsb + B_WPAN);
    unsigned*       cnt  = (unsigned*)      (wsb + B_CNT);
    unsigned*       ofs  = (unsigned*)      (wsb + B_OFS);
    int*            srcp = (int*)           (wsb + B_SRCP);
    int*            dstp = (int*)           (wsb + B_DSTP);
    int*            eidx = (int*)           (wsb + B_EIDX);

    hipMemsetAsync(d_out, 0, (size_t)out_size * sizeof(float), stream);
    hipMemsetAsync(cnt, 0, (size_t)N * sizeof(unsigned), stream);

    const int nPrep = WS_ELEMS / 256;              // 608
    const int nHist = (E + 255) / 256;             // 2048

    fused_prep<<<dim3(nPrep + nHist), dim3(256), 0, stream>>>(
        Wc1, bc1, We1, be1, Wc2, We2, Wn1, Wn2, wpan,
        dst, cnt, nPrep, E);

    node_pre<<<dim3(N / MT), dim3(256), 0, stream>>>(
        h, wpan, Psc, Pdc, Pse, Pde);

    scan32k<<<dim3(1), dim3(1024), 0, stream>>>(cnt, ofs);
    scatter_perm<<<dim3((E + 255) / 256), dim3(256), 0, stream>>>(
        src, dst, ofs, srcp, dstp, eidx, E);

    edge_kernel<<<dim3(E / MT), dim3(256), 0, stream>>>(
        srcp, dstp, eidx, a, coords,
        Psc, Pdc, Pse, Pde,
        bc2, Wc3, be2, Watt, batt,
        wpan, out_h, out_x);

    node_kernel<<<dim3(N / MT), dim3(256), 0, stream>>>(
        h, coords, bn1, bn2, wpan, out_h, out_x);
}

// Round 11
// 311.999 us; speedup vs baseline: 2.4278x; 1.0203x over previous
//
#include <hip/hip_runtime.h>
#include <math.h>

#define HD   128
#define EFD  16
#define MT   64      // edges / nodes per block
#define LPA  264
#define LPC  136     // LDS pitch (ushort): rows, cols=128+pad

#define W1SZ (128 * 288)
#define W2SZ (128 * 128)
#define O_WE1 (W1SZ)
#define O_WC2 (2 * W1SZ)
#define O_WE2 (2 * W1SZ + W2SZ)
#define O_WN1 (2 * W1SZ + 2 * W2SZ)
#define O_WN2 (2 * W1SZ + 2 * W2SZ + 128 * 256)
#define WS_ELEMS (O_WN2 + W2SZ)          // 155648

// ws byte layout (~40.4 MB)
#define B_PSC   ((size_t)0)              // N*128 bf16 = 8 MB
#define B_PDC   ((size_t)8388608)
#define B_PSE   ((size_t)16777216)
#define B_PDE   ((size_t)25165824)
#define B_WPAN  ((size_t)33554432)       // 311296
#define B_CNT   ((size_t)33865728)       // 131072
#define B_OFS   ((size_t)33996800)       // 131072
#define B_SRCP  ((size_t)34127872)       // 2 MB
#define B_DSTP  ((size_t)36225024)       // 2 MB
#define B_EIDX  ((size_t)38322176)       // 2 MB

typedef __attribute__((ext_vector_type(8))) short short8;
typedef __attribute__((ext_vector_type(4))) float f32x4;

__device__ __forceinline__ unsigned short f2bf(float x) {
    __bf16 b = (__bf16)x;
    unsigned short u;
    __builtin_memcpy(&u, &b, 2);
    return u;
}
__device__ __forceinline__ float bfl(unsigned u) {   // low bf16 of dword
    union { unsigned u; float f; } v; v.u = u << 16; return v.f;
}
__device__ __forceinline__ float bfh(unsigned u) {   // high bf16 of dword
    union { unsigned u; float f; } v; v.u = u & 0xffff0000u; return v.f;
}
__device__ __forceinline__ float sigm_f(float x) {
    return __builtin_amdgcn_rcpf(1.f + __expf(-x));
}
__device__ __forceinline__ float silu_f(float x) { return x * sigm_f(x); }
__device__ __forceinline__ unsigned pack2(float a, float b) {
    return (unsigned)f2bf(a) | ((unsigned)f2bf(b) << 16);
}

// ---------------------------------------------------------------------------
// Fragment-ordered bf16 weight panels (A-operand layout).
// l1 K remap: k<256 -> k ; 256..271 -> a rows (orig 257..272);
// 272 -> radial (orig 256); 273 -> BIAS (data supplies 1.0); else 0
// ---------------------------------------------------------------------------
__device__ __forceinline__ void frag_l1(int idx, const float* __restrict__ W,
                                        const float* __restrict__ bias,
                                        unsigned short* __restrict__ out)
{
    const int j = idx & 7, lane = (idx >> 3) & 63, blk = idx >> 9;
    const int kc = blk % 9, n = blk / 9;
    const int k = kc * 32 + (lane >> 4) * 8 + j;
    const int c = n * 16 + (lane & 15);
    float v = 0.f;
    if (k < 256) v = W[k * HD + c];
    else if (k < 272) v = W[(k + 1) * HD + c];
    else if (k == 272) v = W[256 * HD + c];
    else if (k == 273) v = bias[c];
    out[idx] = f2bf(v);
}
__device__ __forceinline__ void frag_sq(int idx, const float* __restrict__ W,
                                        int nkc, unsigned short* __restrict__ out)
{
    const int j = idx & 7, lane = (idx >> 3) & 63, blk = idx >> 9;
    const int kc = blk % nkc, n = blk / nkc;
    const int k = kc * 32 + (lane >> 4) * 8 + j;
    const int c = n * 16 + (lane & 15);
    out[idx] = f2bf(W[k * HD + c]);
}

// ---------------------------------------------------------------------------
// Fused prep: [0,nPrep) weight panels | [nPrep, nPrep+nHist) dst histogram
// ---------------------------------------------------------------------------
__global__ __launch_bounds__(256) void fused_prep(
    const float* __restrict__ Wc1, const float* __restrict__ bc1,
    const float* __restrict__ We1, const float* __restrict__ be1,
    const float* __restrict__ Wc2, const float* __restrict__ We2,
    const float* __restrict__ Wn1, const float* __restrict__ Wn2,
    unsigned short* __restrict__ ws,
    const int* __restrict__ dst, unsigned* __restrict__ cnt,
    int nPrep, int E)
{
    const int bid = blockIdx.x, tid = threadIdx.x;
    if (bid < nPrep) {
        int idx = bid * 256 + tid;
        if (idx < W1SZ)            { frag_l1(idx, Wc1, bc1, ws);            return; }
        idx -= W1SZ;
        if (idx < W1SZ)            { frag_l1(idx, We1, be1, ws + O_WE1);    return; }
        idx -= W1SZ;
        if (idx < W2SZ)            { frag_sq(idx, Wc2, 4, ws + O_WC2);      return; }
        idx -= W2SZ;
        if (idx < W2SZ)            { frag_sq(idx, We2, 4, ws + O_WE2);      return; }
        idx -= W2SZ;
        if (idx < 128 * 256)       { frag_sq(idx, Wn1, 8, ws + O_WN1);      return; }
        idx -= 128 * 256;
        if (idx < W2SZ)            { frag_sq(idx, Wn2, 4, ws + O_WN2); }
        return;
    }
    const int i = (bid - nPrep) * 256 + tid;
    if (i < E) atomicAdd(&cnt[dst[i]], 1u);
}

// ---------------------------------------------------------------------------
// node_pre: P tables = h @ W1-halves (per-node precompute of edge layer 1)
// ---------------------------------------------------------------------------
__device__ __forceinline__ void pre_pass(
    const unsigned short* __restrict__ panelp,   // panel + lane*8
    const unsigned short* __restrict__ hsh,      // LDS [64][136]
    unsigned short* __restrict__ Ps, unsigned short* __restrict__ Pd,
    int n0, int w2, int w, int col, int kg)
{
    const f32x4 zero = {0.f, 0.f, 0.f, 0.f};
    f32x4 as_[2][4], ad_[2][4];
    #pragma unroll
    for (int m = 0; m < 2; ++m)
        #pragma unroll
        for (int et = 0; et < 4; ++et) { as_[m][et] = zero; ad_[m][et] = zero; }
    #pragma unroll
    for (int kc = 0; kc < 4; ++kc) {
        short8 bf[4];
        #pragma unroll
        for (int et = 0; et < 4; ++et)
            bf[et] = *(const short8*)&hsh[(et*16 + col) * LPC + kc * 32 + kg * 8];
        #pragma unroll
        for (int m = 0; m < 2; ++m) {
            const short8 As = *(const short8*)&panelp[((w2 + m) * 9 + kc) << 9];
            const short8 Ad = *(const short8*)&panelp[((w2 + m) * 9 + kc + 4) << 9];
            #pragma unroll
            for (int et = 0; et < 4; ++et) {
                as_[m][et] = __builtin_amdgcn_mfma_f32_16x16x32_bf16(As, bf[et], as_[m][et], 0, 0, 0);
                ad_[m][et] = __builtin_amdgcn_mfma_f32_16x16x32_bf16(Ad, bf[et], ad_[m][et], 0, 0, 0);
            }
        }
    }
    #pragma unroll
    for (int m = 0; m < 2; ++m)
        #pragma unroll
        for (int et = 0; et < 4; ++et) {
            const size_t row = (size_t)(n0 + et * 16 + col) * HD;
            const int hw = w * 32 + m * 16 + kg * 4;
            uint2 vs, vd;
            vs.x = pack2(as_[m][et][0], as_[m][et][1]);
            vs.y = pack2(as_[m][et][2], as_[m][et][3]);
            vd.x = pack2(ad_[m][et][0], ad_[m][et][1]);
            vd.y = pack2(ad_[m][et][2], ad_[m][et][3]);
            *(uint2*)(Ps + row + hw) = vs;
            *(uint2*)(Pd + row + hw) = vd;
        }
}

__global__ __launch_bounds__(256) void node_pre(
    const float* __restrict__ h, const unsigned short* __restrict__ wpan,
    unsigned short* __restrict__ Psc, unsigned short* __restrict__ Pdc,
    unsigned short* __restrict__ Pse, unsigned short* __restrict__ Pde)
{
    __shared__ __align__(16) unsigned short hsh[MT][LPC];
    const int tid = threadIdx.x;
    const int n0  = blockIdx.x * MT;

    #pragma unroll
    for (int it = 0; it < 8; ++it) {
        const int idx = it * 256 + tid;          // 2048 float4 slots
        const int r = idx >> 5, q = idx & 31;
        const float4 v = *(const float4*)(h + (size_t)(n0 + r) * HD + q * 4);
        uint2 p; p.x = pack2(v.x, v.y); p.y = pack2(v.z, v.w);
        *(uint2*)&hsh[r][q * 4] = p;
    }
    __syncthreads();

    const int lane = tid & 63;
    const int w    = tid >> 6;
    const int w2   = w * 2;
    const int col  = lane & 15;
    const int kg   = lane >> 4;

    pre_pass(wpan + lane * 8,         &hsh[0][0], Psc, Pdc, n0, w2, w, col, kg);
    pre_pass(wpan + O_WE1 + lane * 8, &hsh[0][0], Pse, Pde, n0, w2, w, col, kg);
}

// ---------------------------------------------------------------------------
__global__ __launch_bounds__(1024) void scan32k(const unsigned* __restrict__ cnt,
                                                unsigned* __restrict__ ofs)
{
    __shared__ unsigned wsum[16];
    __shared__ unsigned carry_s;
    const int tid = threadIdx.x, lane = tid & 63, w = tid >> 6;
    if (tid == 0) carry_s = 0;
    __syncthreads();
    for (int c = 0; c < 32; ++c) {
        const unsigned x = cnt[c * 1024 + tid];
        unsigned v = x;
        #pragma unroll
        for (int off = 1; off < 64; off <<= 1) {
            unsigned t = __shfl_up(v, off);
            if (lane >= off) v += t;
        }
        if (lane == 63) wsum[w] = v;
        __syncthreads();
        if (tid < 16) {
            unsigned s = wsum[tid];
            #pragma unroll
            for (int off = 1; off < 16; off <<= 1) {
                unsigned t = __shfl_up(s, off);
                if (tid >= off) s += t;
            }
            wsum[tid] = s;
        }
        __syncthreads();
        const unsigned carry = carry_s;
        const unsigned woff = (w == 0) ? 0u : wsum[w - 1];
        ofs[c * 1024 + tid] = carry + woff + v - x;
        __syncthreads();
        if (tid == 0) carry_s = carry + wsum[15];
        __syncthreads();
    }
}

__global__ __launch_bounds__(256) void scatter_perm(
    const int* __restrict__ src, const int* __restrict__ dst,
    unsigned* __restrict__ ofs,
    int* __restrict__ srcp, int* __restrict__ dstp,
    int* __restrict__ eidx, int E)
{
    const int i = blockIdx.x * 256 + threadIdx.x;
    if (i >= E) return;
    const int d = dst[i];
    const unsigned pos = atomicAdd(&ofs[d], 1u);
    srcp[pos] = src[i];
    dstp[pos] = d;
    eidx[pos] = i;
}

// ---------------------------------------------------------------------------
// Edge kernel: layer-1 acc-init via IDENTITY MFMA over P fragments
// (kg<2 lanes carry Ps cols, kg>=2 carry Pd cols; A = delta((k&15),o)),
// then one (a,rad,bias) MFMA chunk. Layer-2 unchanged.
// ---------------------------------------------------------------------------
__global__ __launch_bounds__(256, 4) void edge_kernel(
    const int* __restrict__ srcp, const int* __restrict__ dstp,
    const int* __restrict__ eidx, const float* __restrict__ a,
    const float* __restrict__ coords,
    const unsigned short* __restrict__ Psc, const unsigned short* __restrict__ Pdc,
    const unsigned short* __restrict__ Pse, const unsigned short* __restrict__ Pde,
    const float* __restrict__ bc2, const float* __restrict__ Wc3,
    const float* __restrict__ be2,
    const float* __restrict__ Watt, const float* __restrict__ batt,
    const unsigned short* __restrict__ wpan,
    float* __restrict__ out_h, float* __restrict__ out_x)
{
    __shared__ __align__(16) unsigned short csh_c[MT][LPC];
    __shared__ __align__(16) unsigned short csh_e[MT][LPC];
    __shared__ float diff_s[MT][3];
    __shared__ float rad_s[MT];
    __shared__ float rinv_s[MT];
    __shared__ float sc_part[4][MT];
    __shared__ float pa_part[4][MT];
    __shared__ float att_s[MT];
    __shared__ float sc_s[MT];
    __shared__ int   src_s[MT], dst_s[MT], eid_s[MT];
    __shared__ short run_start[MT + 1];
    __shared__ int   nruns_s;

    const int tid = threadIdx.x;
    const int e0  = blockIdx.x * MT;

    if (tid < MT) {
        const int s = srcp[e0 + tid], d = dstp[e0 + tid];
        src_s[tid] = s; dst_s[tid] = d;
        eid_s[tid] = eidx[e0 + tid];
        const float dx = coords[(size_t)s*3+0] - coords[(size_t)d*3+0];
        const float dy = coords[(size_t)s*3+1] - coords[(size_t)d*3+1];
        const float dz = coords[(size_t)s*3+2] - coords[(size_t)d*3+2];
        diff_s[tid][0] = dx; diff_s[tid][1] = dy; diff_s[tid][2] = dz;
        const float rad = dx*dx + dy*dy + dz*dz;
        rad_s[tid]  = rad;
        rinv_s[tid] = __builtin_amdgcn_rcpf(sqrtf(rad + 1e-5f) + 1.f);
    }
    __syncthreads();                                     // Ba

    if (tid < 64) {
        const bool st = (tid == 0) || (dst_s[tid] != dst_s[tid - 1]);
        unsigned long long m = __ballot(st);
        if (tid == 0) {
            int nr = 0;
            while (m) { run_start[nr++] = (short)__builtin_ctzll(m); m &= m - 1; }
            run_start[nr] = MT;
            nruns_s = nr;
        }
    }

    const int lane = tid & 63;
    const int w    = tid >> 6;        // out-col quarter
    const int w2   = w * 2;
    const int col  = lane & 15;       // edge within 16-tile (B/C col; A out-row)
    const int kg   = lane >> 4;

    const unsigned short* Wc1p = wpan            + lane * 8;
    const unsigned short* We1p = wpan + O_WE1    + lane * 8;
    const unsigned short* Wc2p = wpan + O_WC2    + lane * 8;
    const unsigned short* We2p = wpan + O_WE2    + lane * 8;

    // identity A-fragment: A[o][k] = delta(k&15, o)  (sums Ps + Pd halves)
    short8 idf;
    #pragma unroll
    for (int j = 0; j < 8; ++j)
        idf[j] = (short)((((kg * 8 + j) & 15) == col) ? 0x3F80 : 0);

    // per-(et) B-fragment bases: kg<2 lanes read Ps (src), kg>=2 read Pd (dst)
    const unsigned short* bas_c[4];
    const unsigned short* bas_e[4];
    #pragma unroll
    for (int et = 0; et < 4; ++et) {
        const int r = et * 16 + col;
        const size_t so = (size_t)src_s[r] * HD;
        const size_t dofs = (size_t)dst_s[r] * HD;
        const int slot = (kg & 1) * 8;
        bas_c[et] = ((kg < 2) ? Psc + so : Pdc + dofs) + slot;
        bas_e[et] = ((kg < 2) ? Pse + so : Pde + dofs) + slot;
    }

    const short8 zf = {0,0,0,0,0,0,0,0};
    const f32x4 zero = {0.f, 0.f, 0.f, 0.f};
    f32x4 ac[2][4], ae[2][4];

    // ============ layer 1: identity-MFMA P-sum + (a,rad,bias) chunk =========
    #pragma unroll
    for (int m = 0; m < 2; ++m)
        #pragma unroll
        for (int et = 0; et < 4; ++et) { ac[m][et] = zero; ae[m][et] = zero; }

    #pragma unroll
    for (int m = 0; m < 2; ++m) {
        const int co = (w2 + m) * 16;            // col offset within P row
        #pragma unroll
        for (int et = 0; et < 4; ++et) {
            const short8 bc_ = *(const short8*)(bas_c[et] + co);
            const short8 be_ = *(const short8*)(bas_e[et] + co);
            ac[m][et] = __builtin_amdgcn_mfma_f32_16x16x32_bf16(idf, bc_, ac[m][et], 0, 0, 0);
            ae[m][et] = __builtin_amdgcn_mfma_f32_16x16x32_bf16(idf, be_, ae[m][et], 0, 0, 0);
        }
    }
    {   // kc=8 chunk: a(16) | rad | 1.0(bias) | pad
        short8 df[4];
        #pragma unroll
        for (int et = 0; et < 4; ++et) {
            if (kg < 2) {
                const int oe = eid_s[et * 16 + col];
                const float4 a0 = *(const float4*)(a + (size_t)oe * EFD + kg * 8);
                const float4 a1 = *(const float4*)(a + (size_t)oe * EFD + kg * 8 + 4);
                short8 v;
                v[0] = (short)f2bf(a0.x); v[1] = (short)f2bf(a0.y);
                v[2] = (short)f2bf(a0.z); v[3] = (short)f2bf(a0.w);
                v[4] = (short)f2bf(a1.x); v[5] = (short)f2bf(a1.y);
                v[6] = (short)f2bf(a1.z); v[7] = (short)f2bf(a1.w);
                df[et] = v;
            } else if (kg == 2) {
                short8 v = zf;
                v[0] = (short)f2bf(rad_s[et * 16 + col]);
                v[1] = (short)0x3F80;
                df[et] = v;
            } else df[et] = zf;
        }
        #pragma unroll
        for (int m = 0; m < 2; ++m) {
            const short8 wc = *(const short8*)&Wc1p[((w2 + m) * 9 + 8) << 9];
            const short8 we = *(const short8*)&We1p[((w2 + m) * 9 + 8) << 9];
            #pragma unroll
            for (int et = 0; et < 4; ++et) {
                ac[m][et] = __builtin_amdgcn_mfma_f32_16x16x32_bf16(wc, df[et], ac[m][et], 0, 0, 0);
                ae[m][et] = __builtin_amdgcn_mfma_f32_16x16x32_bf16(we, df[et], ae[m][et], 0, 0, 0);
            }
        }
    }
    // epilogue: silu -> packed b64 stores
    #pragma unroll
    for (int m = 0; m < 2; ++m)
        #pragma unroll
        for (int et = 0; et < 4; ++et) {
            const int row = et * 16 + col;
            const int hw  = w * 32 + m * 16 + kg * 4;
            uint2 vc, ve;
            vc.x = pack2(silu_f(ac[m][et][0]), silu_f(ac[m][et][1]));
            vc.y = pack2(silu_f(ac[m][et][2]), silu_f(ac[m][et][3]));
            ve.x = pack2(silu_f(ae[m][et][0]), silu_f(ae[m][et][1]));
            ve.y = pack2(silu_f(ae[m][et][2]), silu_f(ae[m][et][3]));
            *(uint2*)&csh_c[row][hw] = vc;
            *(uint2*)&csh_e[row][hw] = ve;
        }
    __syncthreads();                                     // B1

    // ================= layer 2 (coord + edge fused) =================
    #pragma unroll
    for (int m = 0; m < 2; ++m)
        #pragma unroll
        for (int et = 0; et < 4; ++et) { ac[m][et] = zero; ae[m][et] = zero; }

    #pragma unroll
    for (int kc = 0; kc < 4; ++kc) {
        short8 dc[4], de[4];
        #pragma unroll
        for (int et = 0; et < 4; ++et) {
            const int row = et * 16 + col;
            dc[et] = *(const short8*)&csh_c[row][kc * 32 + kg * 8];
            de[et] = *(const short8*)&csh_e[row][kc * 32 + kg * 8];
        }
        #pragma unroll
        for (int m = 0; m < 2; ++m) {
            const short8 wc = *(const short8*)&Wc2p[((w2 + m) * 4 + kc) << 9];
            const short8 we = *(const short8*)&We2p[((w2 + m) * 4 + kc) << 9];
            #pragma unroll
            for (int et = 0; et < 4; ++et) {
                ac[m][et] = __builtin_amdgcn_mfma_f32_16x16x32_bf16(wc, dc[et], ac[m][et], 0, 0, 0);
                ae[m][et] = __builtin_amdgcn_mfma_f32_16x16x32_bf16(we, de[et], ae[m][et], 0, 0, 0);
            }
        }
    }

    {   // scale partial: lane-local + kg reduce
        float sc[4] = {0.f, 0.f, 0.f, 0.f};
        #pragma unroll
        for (int m = 0; m < 2; ++m)
            #pragma unroll
            for (int i = 0; i < 4; ++i) {
                const int hw = w * 32 + m * 16 + kg * 4 + i;
                const float b = bc2[hw], w3 = Wc3[hw];
                #pragma unroll
                for (int et = 0; et < 4; ++et)
                    sc[et] += silu_f(ac[m][et][i] + b) * w3;
            }
        #pragma unroll
        for (int et = 0; et < 4; ++et) {
            sc[et] += __shfl_xor(sc[et], 16);
            sc[et] += __shfl_xor(sc[et], 32);
        }
        if (kg == 0) {
            #pragma unroll
            for (int et = 0; et < 4; ++et)
                sc_part[w][et * 16 + col] = sc[et];
        }
    }
    __syncthreads();                                     // B2

    {   // msg epilogue: b64 store + att partial
        float pa[4] = {0.f, 0.f, 0.f, 0.f};
        #pragma unroll
        for (int m = 0; m < 2; ++m)
            #pragma unroll
            for (int et = 0; et < 4; ++et) {
                const int row = et * 16 + col;
                const int hw  = w * 32 + m * 16 + kg * 4;
                const float v0 = silu_f(ae[m][et][0] + be2[hw]);
                const float v1 = silu_f(ae[m][et][1] + be2[hw+1]);
                const float v2 = silu_f(ae[m][et][2] + be2[hw+2]);
                const float v3 = silu_f(ae[m][et][3] + be2[hw+3]);
                pa[et] += v0 * Watt[hw] + v1 * Watt[hw+1]
                        + v2 * Watt[hw+2] + v3 * Watt[hw+3];
                uint2 ve;
                ve.x = pack2(v0, v1);
                ve.y = pack2(v2, v3);
                *(uint2*)&csh_e[row][hw] = ve;
            }
        #pragma unroll
        for (int et = 0; et < 4; ++et) {
            pa[et] += __shfl_xor(pa[et], 16);
            pa[et] += __shfl_xor(pa[et], 32);
        }
        if (kg == 0) {
            #pragma unroll
            for (int et = 0; et < 4; ++et)
                pa_part[w][et * 16 + col] = pa[et];
        }
    }
    __syncthreads();                                     // B3

    if (tid < MT) {
        att_s[tid] = sigm_f(pa_part[0][tid] + pa_part[1][tid] +
                            pa_part[2][tid] + pa_part[3][tid] + batt[0]);
        sc_s[tid]  = (sc_part[0][tid] + sc_part[1][tid] +
                      sc_part[2][tid] + sc_part[3][tid]) * rinv_s[tid];
    }
    __syncthreads();                                     // B4

    // ---- segmented sum: dword reads (2 cols/thread), 4 run-groups ----
    {
        const int nr    = nruns_s;
        const int colx2 = tid & 63;
        for (int r = tid >> 6; r < nr; r += 4) {
            const int s0 = run_start[r], s1 = run_start[r + 1];
            float sum0 = 0.f, sum1 = 0.f;
            for (int e = s0; e < s1; ++e) {
                const unsigned uv = *(const unsigned*)&csh_e[e][colx2 * 2];
                const float at = att_s[e];
                sum0 += bfl(uv) * at;
                sum1 += bfh(uv) * at;
            }
            const int drow = dst_s[s0];
            float* op = out_h + (size_t)drow * HD + colx2 * 2;
            atomicAdd(op,     sum0);
            atomicAdd(op + 1, sum1);
            if (colx2 < 2) {
                float sx0 = 0.f, sx1 = 0.f;
                for (int e = s0; e < s1; ++e) {
                    const float s = sc_s[e];
                    sx0 += s * diff_s[e][colx2 * 2];
                    if (colx2 == 0) sx1 += s * diff_s[e][1];
                }
                atomicAdd(&out_x[(size_t)drow * 3 + colx2 * 2], sx0);
                if (colx2 == 0) atomicAdd(&out_x[(size_t)drow * 3 + 1], sx1);
            }
        }
    }
}

// ---------------------------------------------------------------------------
// Node kernel (unchanged)
// ---------------------------------------------------------------------------
__global__ __launch_bounds__(256) void node_kernel(
    const float* __restrict__ h, const float* __restrict__ coords,
    const float* __restrict__ bn1, const float* __restrict__ bn2,
    const unsigned short* __restrict__ wpan,
    float* __restrict__ out_h, float* __restrict__ out_x)
{
    __shared__ __align__(16) unsigned short ash[MT][LPA];
    __shared__ __align__(16) unsigned short csh[MT][LPC];

    const int tid = threadIdx.x;
    const int n0  = blockIdx.x * MT;

    #pragma unroll
    for (int it = 0; it < 16; ++it) {
        const int idx = it * 256 + tid;
        const int e = idx >> 6, q = idx & 63;
        const float* base = (q < 32)
            ? h     + (size_t)(n0 + e) * HD + q * 4
            : out_h + (size_t)(n0 + e) * HD + (q - 32) * 4;
        const float4 v = *(const float4*)base;
        uint2 p; p.x = pack2(v.x, v.y); p.y = pack2(v.z, v.w);
        *(uint2*)&ash[e][q * 4] = p;
    }
    __syncthreads();

    if (tid < MT * 3) {
        const int n = tid / 3, d = tid % 3;
        const size_t gi = (size_t)(n0 + n) * 3 + d;
        out_x[gi] += coords[gi];
    }

    const int lane = tid & 63;
    const int w    = tid >> 6;
    const int er0  = w * 16;
    const int col  = lane & 15;
    const int kg   = lane >> 4;

    const unsigned short* Wn1p = wpan + O_WN1 + lane * 8;
    const unsigned short* Wn2p = wpan + O_WN2 + lane * 8;

    const f32x4 zero = {0.f, 0.f, 0.f, 0.f};
    f32x4 acc[8];

    #pragma unroll
    for (int n = 0; n < 8; ++n) acc[n] = zero;
    #pragma unroll
    for (int kc = 0; kc < 8; ++kc) {
        const short8 af = *(const short8*)&ash[er0 + col][kc * 32 + kg * 8];
        #pragma unroll
        for (int n = 0; n < 8; ++n) {
            const short8 bf = *(const short8*)&Wn1p[(n * 8 + kc) << 9];
            acc[n] = __builtin_amdgcn_mfma_f32_16x16x32_bf16(af, bf, acc[n], 0, 0, 0);
        }
    }
    #pragma unroll
    for (int n = 0; n < 8; ++n) {
        const float b = bn1[n*16 + col];
        #pragma unroll
        for (int i = 0; i < 4; ++i)
            csh[er0 + kg*4 + i][n*16 + col] = f2bf(silu_f(acc[n][i] + b));
    }
    __syncthreads();
    #pragma unroll
    for (int n = 0; n < 8; ++n) acc[n] = zero;
    #pragma unroll
    for (int kc = 0; kc < 4; ++kc) {
        const short8 af = *(const short8*)&csh[er0 + col][kc * 32 + kg * 8];
        #pragma unroll
        for (int n = 0; n < 8; ++n) {
            const short8 bf = *(const short8*)&Wn2p[(n * 4 + kc) << 9];
            acc[n] = __builtin_amdgcn_mfma_f32_16x16x32_bf16(af, bf, acc[n], 0, 0, 0);
        }
    }
    #pragma unroll
    for (int i = 0; i < 4; ++i) {
        const int node = n0 + er0 + kg*4 + i;
        const float* hr   = h     + (size_t)node * HD;
        float*       orow = out_h + (size_t)node * HD;
        #pragma unroll
        for (int n = 0; n < 8; ++n) {
            const int f = n*16 + col;
            orow[f] = hr[f] + acc[n][i] + bn2[f];
        }
    }
}

extern "C" void kernel_launch(void* const* d_in, const int* in_sizes, int n_in,
                              void* d_out, int out_size, void* d_ws, size_t ws_size,
                              hipStream_t stream)
{
    const int*   src    = (const int*)  d_in[0];
    const int*   dst    = (const int*)  d_in[1];
    const float* h      = (const float*)d_in[2];
    const float* coords = (const float*)d_in[3];
    const float* a      = (const float*)d_in[4];
    const float* Wc1    = (const float*)d_in[5];
    const float* bc1    = (const float*)d_in[6];
    const float* Wc2    = (const float*)d_in[7];
    const float* bc2    = (const float*)d_in[8];
    const float* Wc3    = (const float*)d_in[9];
    const float* We1    = (const float*)d_in[10];
    const float* be1    = (const float*)d_in[11];
    const float* We2    = (const float*)d_in[12];
    const float* be2    = (const float*)d_in[13];
    const float* Watt   = (const float*)d_in[14];
    const float* batt   = (const float*)d_in[15];
    const float* Wn1    = (const float*)d_in[16];
    const float* bn1    = (const float*)d_in[17];
    const float* Wn2    = (const float*)d_in[18];
    const float* bn2    = (const float*)d_in[19];

    const int E = in_sizes[0];
    const int N = in_sizes[2] / HD;

    float* out_h = (float*)d_out;
    float* out_x = out_h + (size_t)N * HD;

    char* wsb = (char*)d_ws;
    unsigned short* Psc  = (unsigned short*)(wsb + B_PSC);
    unsigned short* Pdc  = (unsigned short*)(wsb + B_PDC);
    unsigned short* Pse  = (unsigned short*)(wsb + B_PSE);
    unsigned short* Pde  = (unsigned short*)(wsb + B_PDE);
    unsigned short* wpan = (unsigned short*)(wsb + B_WPAN);
    unsigned*       cnt  = (unsigned*)      (wsb + B_CNT);
    unsigned*       ofs  = (unsigned*)      (wsb + B_OFS);
    int*            srcp = (int*)           (wsb + B_SRCP);
    int*            dstp = (int*)           (wsb + B_DSTP);
    int*            eidx = (int*)           (wsb + B_EIDX);

    hipMemsetAsync(d_out, 0, (size_t)out_size * sizeof(float), stream);
    hipMemsetAsync(cnt, 0, (size_t)N * sizeof(unsigned), stream);

    const int nPrep = WS_ELEMS / 256;              // 608
    const int nHist = (E + 255) / 256;             // 2048

    fused_prep<<<dim3(nPrep + nHist), dim3(256), 0, stream>>>(
        Wc1, bc1, We1, be1, Wc2, We2, Wn1, Wn2, wpan,
        dst, cnt, nPrep, E);

    node_pre<<<dim3(N / MT), dim3(256), 0, stream>>>(
        h, wpan, Psc, Pdc, Pse, Pde);

    scan32k<<<dim3(1), dim3(1024), 0, stream>>>(cnt, ofs);
    scatter_perm<<<dim3((E + 255) / 256), dim3(256), 0, stream>>>(
        src, dst, ofs, srcp, dstp, eidx, E);

    edge_kernel<<<dim3(E / MT), dim3(256), 0, stream>>>(
        srcp, dstp, eidx, a, coords,
        Psc, Pdc, Pse, Pde,
        bc2, Wc3, be2, Watt, batt,
        wpan, out_h, out_x);

    node_kernel<<<dim3(N / MT), dim3(256), 0, stream>>>(
        h, coords, bn1, bn2, wpan, out_h, out_x);
}